// Round 1
// baseline (1834.342 us; speedup 1.0000x reference)
//
#include <hip/hip_runtime.h>

#define N_NODES 50000
#define N_EDGES 800000
#define N_TOT   850000   // edges + self-loops
#define SD 128
#define HD 256
#define OD 41
#define ODP 48
#define NG 512

__global__ __launch_bounds__(256) void fill4_kernel(float4* __restrict__ p, float v, int n4) {
  int i = blockIdx.x * 256 + threadIdx.x;
  if (i < n4) p[i] = make_float4(v, v, v, v);
}

__global__ __launch_bounds__(256) void deg_kernel(const int* __restrict__ ei, int* __restrict__ ideg) {
  int e = blockIdx.x * 256 + threadIdx.x;
  if (e < N_EDGES) atomicAdd(&ideg[ei[N_EDGES + e]], 1);
}

__global__ __launch_bounds__(256) void dinv_kernel(const int* __restrict__ ideg, float* __restrict__ dinv) {
  int i = blockIdx.x * 256 + threadIdx.x;
  if (i < N_NODES) dinv[i] = rsqrtf((float)(ideg[i] + 1));  // +1 = self-loop; always > 0
}

// agg1[d] += norm * emb[x_ids[s]]  -- one thread per (edge, float4-chunk of 128 feats)
__global__ __launch_bounds__(256) void agg1_kernel(const int* __restrict__ ei,
    const int* __restrict__ x_ids, const float* __restrict__ dinv,
    const float4* __restrict__ emb4, float* __restrict__ agg1) {
  long idx = (long)blockIdx.x * 256 + threadIdx.x;   // < N_TOT * 32
  int e = (int)(idx >> 5);
  int c = (int)(idx & 31);
  int s, d; float nrm;
  if (e < N_EDGES) {
    s = ei[e]; d = ei[N_EDGES + e];
    nrm = dinv[s] * dinv[d];
  } else {
    s = d = e - N_EDGES;
    float di = dinv[s]; nrm = di * di;
  }
  float4 v = emb4[x_ids[s] * 32 + c];
  float* out = agg1 + (size_t)d * SD + (c << 2);
  unsafeAtomicAdd(out + 0, v.x * nrm);
  unsafeAtomicAdd(out + 1, v.y * nrm);
  unsafeAtomicAdd(out + 2, v.z * nrm);
  unsafeAtomicAdd(out + 3, v.w * nrm);
}

// y1 = relu(agg1 @ W1 + b1)   [50000,128]@[128,256]
__global__ __launch_bounds__(256) void gemm1_kernel(const float* __restrict__ agg1,
    const float* __restrict__ W1, const float* __restrict__ b1, float* __restrict__ y1) {
  __shared__ float w_lds[32 * 256];   // k-chunk of 32, natural [k][col] layout
  __shared__ float a_lds[16 * 128];   // 16-row A tile
  int t = threadIdx.x;
  int row0 = blockIdx.x * 16;
  const float4* ag4 = (const float4*)(agg1 + (size_t)row0 * SD);
  float4* al4 = (float4*)a_lds;
  al4[t]       = ag4[t];
  al4[t + 256] = ag4[t + 256];
  float acc[16];
  #pragma unroll
  for (int r = 0; r < 16; ++r) acc[r] = 0.f;
  const float4* W14 = (const float4*)W1;
  float4* wl4 = (float4*)w_lds;
  const float4* a4l = (const float4*)a_lds;
  for (int kc = 0; kc < 4; ++kc) {
    __syncthreads();
    #pragma unroll
    for (int i = 0; i < 8; ++i) wl4[t + i * 256] = W14[kc * 2048 + t + i * 256];
    __syncthreads();
    #pragma unroll
    for (int kq = 0; kq < 8; ++kq) {
      int kb = kq * 4;
      float w0  = w_lds[(kb + 0) * 256 + t];
      float w1v = w_lds[(kb + 1) * 256 + t];
      float w2v = w_lds[(kb + 2) * 256 + t];
      float w3v = w_lds[(kb + 3) * 256 + t];
      #pragma unroll
      for (int r = 0; r < 16; ++r) {
        float4 a = a4l[r * 32 + kc * 8 + kq];
        acc[r] += a.x * w0 + a.y * w1v + a.z * w2v + a.w * w3v;
      }
    }
  }
  float bias = b1[t];
  #pragma unroll
  for (int r = 0; r < 16; ++r) {
    float v = acc[r] + bias;
    y1[(size_t)(row0 + r) * HD + t] = fmaxf(v, 0.f);
  }
}

// h2 = y1 @ W2   [50000,256]@[256,41] -> stride-48 padded rows (no bias here)
__global__ __launch_bounds__(256) void gemm2_kernel(const float* __restrict__ y1,
    const float* __restrict__ W2, float* __restrict__ h2) {
  __shared__ float w_lds[HD * OD];    // 10496 floats, natural [j][oc]
  __shared__ float y_lds[16 * HD];    // 4096 floats
  int t = threadIdx.x;
  int row0 = blockIdx.x * 16;
  const float4* W24 = (const float4*)W2;
  float4* wl4 = (float4*)w_lds;
  #pragma unroll
  for (int i = 0; i < 11; ++i) {
    int idx = t + i * 256;
    if (idx < (HD * OD) / 4) wl4[idx] = W24[idx];
  }
  const float4* yg4 = (const float4*)(y1 + (size_t)row0 * HD);
  float4* yl4 = (float4*)y_lds;
  #pragma unroll
  for (int i = 0; i < 4; ++i) yl4[t + i * 256] = yg4[t + i * 256];
  __syncthreads();
  if (t >= 246) return;
  int rg = t / 41;
  int oc = t - rg * 41;
  float acc0 = 0.f, acc1 = 0.f, acc2 = 0.f;
  const float4* y4 = (const float4*)y_lds;
  for (int jq = 0; jq < 64; ++jq) {
    int j = jq * 4;
    float w0  = w_lds[(j + 0) * OD + oc];
    float w1v = w_lds[(j + 1) * OD + oc];
    float w2v = w_lds[(j + 2) * OD + oc];
    float w3v = w_lds[(j + 3) * OD + oc];
    float4 ya = y4[rg * 64 + jq];
    acc0 += ya.x * w0 + ya.y * w1v + ya.z * w2v + ya.w * w3v;
    float4 yb = y4[(rg + 6) * 64 + jq];
    acc1 += yb.x * w0 + yb.y * w1v + yb.z * w2v + yb.w * w3v;
    if (rg < 4) {
      float4 yc = y4[(rg + 12) * 64 + jq];
      acc2 += yc.x * w0 + yc.y * w1v + yc.z * w2v + yc.w * w3v;
    }
  }
  h2[(size_t)(row0 + rg) * ODP + oc] = acc0;
  h2[(size_t)(row0 + rg + 6) * ODP + oc] = acc1;
  if (rg < 4) h2[(size_t)(row0 + rg + 12) * ODP + oc] = acc2;
}

// agg2[d] += norm * h2[s]  -- 41 feats, 6 edges per 256-thread block
__global__ __launch_bounds__(256) void agg2_kernel(const int* __restrict__ ei,
    const float* __restrict__ dinv, const float* __restrict__ h2, float* __restrict__ agg2) {
  int t = threadIdx.x;
  int le = t / 41;
  if (le >= 6) return;
  int f = t - le * 41;
  int e = blockIdx.x * 6 + le;
  if (e >= N_TOT) return;
  int s, d; float nrm;
  if (e < N_EDGES) {
    s = ei[e]; d = ei[N_EDGES + e];
    nrm = dinv[s] * dinv[d];
  } else {
    s = d = e - N_EDGES;
    nrm = dinv[s]; nrm *= nrm;
  }
  unsafeAtomicAdd(&agg2[(size_t)d * ODP + f], h2[(size_t)s * ODP + f] * nrm);
}

// out[batch[n]] += agg2[n] + b2   (b2 applied per node, matching ref)
__global__ __launch_bounds__(256) void pool_kernel(const int* __restrict__ batch,
    const float* __restrict__ agg2, const float* __restrict__ b2, float* __restrict__ out) {
  int t = threadIdx.x;
  int ln = t / 41;
  if (ln >= 6) return;
  int f = t - ln * 41;
  int node = blockIdx.x * 6 + ln;
  if (node >= N_NODES) return;
  int g = batch[node];
  unsafeAtomicAdd(&out[g * OD + f], agg2[(size_t)node * ODP + f] + b2[f]);
}

extern "C" void kernel_launch(void* const* d_in, const int* in_sizes, int n_in,
                              void* d_out, int out_size, void* d_ws, size_t ws_size,
                              hipStream_t stream) {
  const int*   x_ids = (const int*)d_in[0];
  const int*   ei    = (const int*)d_in[1];
  const int*   batch = (const int*)d_in[2];
  const float* emb   = (const float*)d_in[3];
  const float* W1    = (const float*)d_in[4];
  const float* b1    = (const float*)d_in[5];
  const float* W2    = (const float*)d_in[6];
  const float* b2    = (const float*)d_in[7];
  float* out = (float*)d_out;
  char* ws = (char*)d_ws;

  // workspace layout (bytes); h2/agg2 reuse the agg1 region after gemm1
  int*   ideg = (int*)  (ws + 0);                       // 200,000 B
  float* dinv = (float*)(ws + 262144);                  // 200,000 B
  float* agg1 = (float*)(ws + 524288);                  // 25.6 MB
  float* y1   = (float*)(ws + 26124288);                // 51.2 MB  (total ~77.3 MB)
  float* h2   = (float*)(ws + 524288);                  // 9.6 MB (reuse agg1)
  float* agg2 = (float*)(ws + 524288 + 12582912);       // 9.6 MB (reuse agg1 tail)

  fill4_kernel<<<49,    256, 0, stream>>>((float4*)ideg, 0.f, 12500);
  fill4_kernel<<<6250,  256, 0, stream>>>((float4*)agg1, 0.f, 1600000);
  fill4_kernel<<<21,    256, 0, stream>>>((float4*)out,  0.f, 5248);

  deg_kernel <<<3125, 256, 0, stream>>>(ei, ideg);
  dinv_kernel<<<196,  256, 0, stream>>>(ideg, dinv);

  agg1_kernel<<<106250, 256, 0, stream>>>(ei, x_ids, dinv, (const float4*)emb, agg1);
  gemm1_kernel<<<3125,  256, 0, stream>>>(agg1, W1, b1, y1);

  fill4_kernel<<<2344, 256, 0, stream>>>((float4*)agg2, 0.f, 600000);
  gemm2_kernel<<<3125, 256, 0, stream>>>(y1, W2, h2);
  agg2_kernel<<<141667, 256, 0, stream>>>(ei, dinv, h2, agg2);
  pool_kernel<<<8334,  256, 0, stream>>>(batch, agg2, b2, out);
}

// Round 2
// 375.480 us; speedup vs baseline: 4.8853x; 4.8853x over previous
//
#include <hip/hip_runtime.h>

#define N_NODES 50000
#define N_EDGES 800000
#define N_TOT   850000   // edges + self-loops
#define SD 128
#define HD 256
#define OD 41
#define ODP 48
#define NG 512

__global__ __launch_bounds__(256) void fill4_kernel(float4* __restrict__ p, float v, int n4) {
  int i = blockIdx.x * 256 + threadIdx.x;
  if (i < n4) p[i] = make_float4(v, v, v, v);
}

__global__ __launch_bounds__(256) void deg_kernel(const int* __restrict__ ei, int* __restrict__ ideg) {
  int e = blockIdx.x * 256 + threadIdx.x;
  if (e < N_EDGES) atomicAdd(&ideg[ei[N_EDGES + e]], 1);
}

__global__ __launch_bounds__(256) void dinv_kernel(const int* __restrict__ ideg, float* __restrict__ dinv) {
  int i = blockIdx.x * 256 + threadIdx.x;
  if (i < N_NODES) dinv[i] = rsqrtf((float)(ideg[i] + 1));  // +1 = self-loop
}

// ---- block scan (exclusive) over cnt[i] = ideg[i]+1 ----
__global__ __launch_bounds__(256) void scan1_kernel(const int* __restrict__ ideg,
    int* __restrict__ off, int* __restrict__ bsum) {
  __shared__ int lds[256];
  int t = threadIdx.x;
  int i = blockIdx.x * 256 + t;
  int v = (i < N_NODES) ? ideg[i] + 1 : 0;
  lds[t] = v;
  __syncthreads();
  for (int s = 1; s < 256; s <<= 1) {
    int add = (t >= s) ? lds[t - s] : 0;
    __syncthreads();
    lds[t] += add;
    __syncthreads();
  }
  int inc = lds[t];
  if (i < N_NODES) off[i] = inc - v;
  if (t == 255) bsum[blockIdx.x] = inc;
}

__global__ __launch_bounds__(256) void scan2_kernel(int* __restrict__ bsum, int* __restrict__ bso, int nb) {
  __shared__ int lds[256];
  int t = threadIdx.x;
  int v = (t < nb) ? bsum[t] : 0;
  lds[t] = v;
  __syncthreads();
  for (int s = 1; s < 256; s <<= 1) {
    int add = (t >= s) ? lds[t - s] : 0;
    __syncthreads();
    lds[t] += add;
    __syncthreads();
  }
  if (t < nb) bso[t] = lds[t] - v;
}

__global__ __launch_bounds__(256) void scan3_kernel(int* __restrict__ off, const int* __restrict__ bso) {
  int i = blockIdx.x * 256 + threadIdx.x;
  if (i < N_NODES) off[i] += bso[blockIdx.x];
  if (i == 0) off[N_NODES] = N_TOT;
}

// graph start boundaries from sorted batch
__global__ __launch_bounds__(256) void gstart_kernel(const int* __restrict__ batch, int* __restrict__ gstart) {
  int n = blockIdx.x * 256 + threadIdx.x;
  if (n >= N_NODES) return;
  if (n == 0) {
    for (int g = 0; g <= batch[0]; ++g) gstart[g] = 0;
  } else {
    int bp = batch[n - 1], bn = batch[n];
    for (int g = bp + 1; g <= bn; ++g) gstart[g] = n;
  }
  if (n == N_NODES - 1) {
    for (int g = batch[n] + 1; g <= NG; ++g) gstart[g] = N_NODES;
  }
}

// bucket edges by dst; record (xid, norm) and src
__global__ __launch_bounds__(256) void scatter_kernel(const int* __restrict__ ei,
    const int* __restrict__ x_ids, const float* __restrict__ dinv,
    const int* __restrict__ off, int* __restrict__ cur,
    int2* __restrict__ xn, int* __restrict__ ssrc) {
  int e = blockIdx.x * 256 + threadIdx.x;
  if (e >= N_TOT) return;
  int s, d; float nrm;
  if (e < N_EDGES) {
    s = ei[e]; d = ei[N_EDGES + e];
    nrm = dinv[s] * dinv[d];
  } else {
    s = d = e - N_EDGES;
    float di = dinv[s]; nrm = di * di;
  }
  int pos = off[d] + atomicAdd(&cur[d], 1);
  xn[pos] = make_int2(x_ids[s], __float_as_int(nrm));
  ssrc[pos] = s;
}

// agg1[d][f] = sum over CSR[d] of norm * emb[xid][f]   (gather, no atomics)
__global__ __launch_bounds__(256) void agg1g_kernel(const int* __restrict__ off,
    const int2* __restrict__ xn, const float* __restrict__ emb, float* __restrict__ agg1) {
  int t = threadIdx.x;
  int node = blockIdx.x * 2 + (t >> 7);
  int f = t & 127;
  int beg = off[node], end = off[node + 1];
  float acc = 0.f;
  #pragma unroll 2
  for (int i = beg; i < end; ++i) {
    int2 r = xn[i];
    acc += __int_as_float(r.y) * emb[r.x * SD + f];
  }
  agg1[(size_t)node * SD + f] = acc;
}

// y1 = relu(agg1 @ W1 + b1)   [50000,128]@[128,256]
__global__ __launch_bounds__(256) void gemm1_kernel(const float* __restrict__ agg1,
    const float* __restrict__ W1, const float* __restrict__ b1, float* __restrict__ y1) {
  __shared__ float w_lds[32 * 256];
  __shared__ float a_lds[16 * 128];
  int t = threadIdx.x;
  int row0 = blockIdx.x * 16;
  const float4* ag4 = (const float4*)(agg1 + (size_t)row0 * SD);
  float4* al4 = (float4*)a_lds;
  al4[t]       = ag4[t];
  al4[t + 256] = ag4[t + 256];
  float acc[16];
  #pragma unroll
  for (int r = 0; r < 16; ++r) acc[r] = 0.f;
  const float4* W14 = (const float4*)W1;
  float4* wl4 = (float4*)w_lds;
  const float4* a4l = (const float4*)a_lds;
  for (int kc = 0; kc < 4; ++kc) {
    __syncthreads();
    #pragma unroll
    for (int i = 0; i < 8; ++i) wl4[t + i * 256] = W14[kc * 2048 + t + i * 256];
    __syncthreads();
    #pragma unroll
    for (int kq = 0; kq < 8; ++kq) {
      int kb = kq * 4;
      float w0  = w_lds[(kb + 0) * 256 + t];
      float w1v = w_lds[(kb + 1) * 256 + t];
      float w2v = w_lds[(kb + 2) * 256 + t];
      float w3v = w_lds[(kb + 3) * 256 + t];
      #pragma unroll
      for (int r = 0; r < 16; ++r) {
        float4 a = a4l[r * 32 + kc * 8 + kq];
        acc[r] += a.x * w0 + a.y * w1v + a.z * w2v + a.w * w3v;
      }
    }
  }
  float bias = b1[t];
  #pragma unroll
  for (int r = 0; r < 16; ++r) {
    float v = acc[r] + bias;
    y1[(size_t)(row0 + r) * HD + t] = fmaxf(v, 0.f);
  }
}

// h2 = y1 @ W2   [50000,256]@[256,41] -> stride-48 padded rows
__global__ __launch_bounds__(256) void gemm2_kernel(const float* __restrict__ y1,
    const float* __restrict__ W2, float* __restrict__ h2) {
  __shared__ float w_lds[HD * OD];
  __shared__ float y_lds[16 * HD];
  int t = threadIdx.x;
  int row0 = blockIdx.x * 16;
  const float4* W24 = (const float4*)W2;
  float4* wl4 = (float4*)w_lds;
  #pragma unroll
  for (int i = 0; i < 11; ++i) {
    int idx = t + i * 256;
    if (idx < (HD * OD) / 4) wl4[idx] = W24[idx];
  }
  const float4* yg4 = (const float4*)(y1 + (size_t)row0 * HD);
  float4* yl4 = (float4*)y_lds;
  #pragma unroll
  for (int i = 0; i < 4; ++i) yl4[t + i * 256] = yg4[t + i * 256];
  __syncthreads();
  if (t >= 246) return;
  int rg = t / 41;
  int oc = t - rg * 41;
  float acc0 = 0.f, acc1 = 0.f, acc2 = 0.f;
  const float4* y4 = (const float4*)y_lds;
  for (int jq = 0; jq < 64; ++jq) {
    int j = jq * 4;
    float w0  = w_lds[(j + 0) * OD + oc];
    float w1v = w_lds[(j + 1) * OD + oc];
    float w2v = w_lds[(j + 2) * OD + oc];
    float w3v = w_lds[(j + 3) * OD + oc];
    float4 ya = y4[rg * 64 + jq];
    acc0 += ya.x * w0 + ya.y * w1v + ya.z * w2v + ya.w * w3v;
    float4 yb = y4[(rg + 6) * 64 + jq];
    acc1 += yb.x * w0 + yb.y * w1v + yb.z * w2v + yb.w * w3v;
    if (rg < 4) {
      float4 yc = y4[(rg + 12) * 64 + jq];
      acc2 += yc.x * w0 + yc.y * w1v + yc.z * w2v + yc.w * w3v;
    }
  }
  h2[(size_t)(row0 + rg) * ODP + oc] = acc0;
  h2[(size_t)(row0 + rg + 6) * ODP + oc] = acc1;
  if (rg < 4) h2[(size_t)(row0 + rg + 12) * ODP + oc] = acc2;
}

// fused layer-2 aggregation + graph pooling: out[g] += sum over graph-g edges
// of norm*h2[src] + cnt_g*b2.  4 chunk-blocks per graph, LDS reduce, tiny atomics.
__global__ __launch_bounds__(256) void pool2_kernel(const int* __restrict__ gstart,
    const int* __restrict__ off, const int* __restrict__ ssrc, const int2* __restrict__ xn,
    const float* __restrict__ h2, const float* __restrict__ b2, float* __restrict__ out) {
  __shared__ float red[6 * 41];
  int g = blockIdx.x >> 2, c = blockIdx.x & 3;
  int t = threadIdx.x;
  int r = t / 41, f = t - r * 41;   // r in [0,6) for t<246
  int n0 = gstart[g], n1 = gstart[g + 1];
  int e0 = off[n0], e1 = off[n1];
  int len = e1 - e0;
  int q0 = e0 + ((len * c) >> 2);
  int q1 = e0 + ((len * (c + 1)) >> 2);
  if (r < 6) {
    float acc = 0.f;
    for (int i = q0 + r; i < q1; i += 6)
      acc += __int_as_float(xn[i].y) * h2[(size_t)ssrc[i] * ODP + f];
    red[r * 41 + f] = acc;
  }
  __syncthreads();
  if (r == 0) {
    float s = red[f] + red[41 + f] + red[82 + f] + red[123 + f] + red[164 + f] + red[205 + f];
    if (c == 0) s += (float)(n1 - n0) * b2[f];
    unsafeAtomicAdd(&out[g * OD + f], s);
  }
}

extern "C" void kernel_launch(void* const* d_in, const int* in_sizes, int n_in,
                              void* d_out, int out_size, void* d_ws, size_t ws_size,
                              hipStream_t stream) {
  const int*   x_ids = (const int*)d_in[0];
  const int*   ei    = (const int*)d_in[1];
  const int*   batch = (const int*)d_in[2];
  const float* emb   = (const float*)d_in[3];
  const float* W1    = (const float*)d_in[4];
  const float* b1    = (const float*)d_in[5];
  const float* W2    = (const float*)d_in[6];
  const float* b2    = (const float*)d_in[7];
  float* out = (float*)d_out;
  char* ws = (char*)d_ws;

  // workspace layout (bytes)
  int*   ideg   = (int*)  (ws + 0);          // 200 KB
  float* dinv   = (float*)(ws + 204800);     // 200 KB
  int*   off    = (int*)  (ws + 409600);     // 200 KB (+4 for off[N])
  int*   cur    = (int*)  (ws + 614400);     // 200 KB
  int*   bsum   = (int*)  (ws + 819200);     // 784 B
  int*   bso    = (int*)  (ws + 820224);     // 784 B
  int*   gstart = (int*)  (ws + 821248);     // 2052 B
  int2*  xn     = (int2*) (ws + 1048576);    // 6.8 MB
  int*   ssrc   = (int*)  (ws + 8388608);    // 3.4 MB
  float* agg1   = (float*)(ws + 12582912);   // 25.6 MB
  float* h2     = (float*)(ws + 12582912);   // 9.6 MB (reuses agg1 after gemm1)
  float* y1     = (float*)(ws + 41943040);   // 51.2 MB  (total ~93.1 MB)

  fill4_kernel<<<49,   256, 0, stream>>>((float4*)ideg, 0.f, 12500);
  fill4_kernel<<<49,   256, 0, stream>>>((float4*)cur,  0.f, 12500);
  fill4_kernel<<<21,   256, 0, stream>>>((float4*)out,  0.f, 5248);

  deg_kernel  <<<3125, 256, 0, stream>>>(ei, ideg);
  dinv_kernel <<<196,  256, 0, stream>>>(ideg, dinv);

  scan1_kernel<<<196, 256, 0, stream>>>(ideg, off, bsum);
  scan2_kernel<<<1,   256, 0, stream>>>(bsum, bso, 196);
  scan3_kernel<<<196, 256, 0, stream>>>(off, bso);
  gstart_kernel<<<196, 256, 0, stream>>>(batch, gstart);

  scatter_kernel<<<3321, 256, 0, stream>>>(ei, x_ids, dinv, off, cur, xn, ssrc);

  agg1g_kernel<<<25000, 256, 0, stream>>>(off, xn, emb, agg1);
  gemm1_kernel<<<3125,  256, 0, stream>>>(agg1, W1, b1, y1);
  gemm2_kernel<<<3125,  256, 0, stream>>>(y1, W2, h2);
  pool2_kernel<<<2048,  256, 0, stream>>>(gstart, off, ssrc, xn, h2, b2, out);
}

// Round 3
// 264.675 us; speedup vs baseline: 6.9305x; 1.4186x over previous
//
#include <hip/hip_runtime.h>

#define N_NODES 50000
#define N_EDGES 800000
#define N_TOT   850000   // edges + self-loops
#define SD 128
#define HD 256
#define OD 41
#define ODP 48
#define NG 512

typedef __attribute__((ext_vector_type(8))) short bh8;   // 8 bf16 = 4 VGPR (MFMA A/B frag)
typedef __attribute__((ext_vector_type(4))) float f4;    // MFMA C/D frag

__device__ inline unsigned short f2bf(float x) {         // RNE float->bf16
  unsigned u = __float_as_uint(x);
  unsigned r = u + 0x7fff + ((u >> 16) & 1);
  return (unsigned short)(r >> 16);
}
__device__ inline float bf2f(unsigned short s) {
  return __uint_as_float(((unsigned)s) << 16);
}

__global__ __launch_bounds__(256) void fill4_kernel(float4* __restrict__ p, float v, int n4) {
  int i = blockIdx.x * 256 + threadIdx.x;
  if (i < n4) p[i] = make_float4(v, v, v, v);
}

__global__ __launch_bounds__(256) void deg_kernel(const int* __restrict__ ei, int* __restrict__ ideg) {
  int e = blockIdx.x * 256 + threadIdx.x;
  if (e < N_EDGES) atomicAdd(&ideg[ei[N_EDGES + e]], 1);
}

__global__ __launch_bounds__(256) void dinv_kernel(const int* __restrict__ ideg, float* __restrict__ dinv) {
  int i = blockIdx.x * 256 + threadIdx.x;
  if (i < N_NODES) dinv[i] = rsqrtf((float)(ideg[i] + 1));  // +1 = self-loop
}

// ---- dtype conversions / frag-linear weight layouts (tiny, once per launch) ----
__global__ __launch_bounds__(256) void cvt_emb_kernel(const float* __restrict__ emb,
    unsigned short* __restrict__ o) {
  int i = blockIdx.x * 256 + threadIdx.x;
  if (i < 1340 * SD) o[i] = f2bf(emb[i]);
}

// W1f[frag=ks*16+cf][lane][j] = bf16(W1[ks*32+(lane>>4)*8+j][cf*16+(lane&15)])
__global__ __launch_bounds__(256) void cvt_w1_kernel(const float* __restrict__ W1,
    unsigned short* __restrict__ o) {
  int tau = blockIdx.x * 256 + threadIdx.x;   // < 4096
  int lane = tau & 63, frag = tau >> 6;
  int ks = frag >> 4, cf = frag & 15;
  int col = cf * 16 + (lane & 15);
  #pragma unroll
  for (int j = 0; j < 8; ++j) {
    int k = ks * 32 + ((lane >> 4) << 3) + j;
    o[tau * 8 + j] = f2bf(W1[k * HD + col]);
  }
}

// W2f[frag=ks*3+cf][lane][j], zero-padded cols 41..47
__global__ __launch_bounds__(256) void cvt_w2_kernel(const float* __restrict__ W2,
    unsigned short* __restrict__ o) {
  int tau = blockIdx.x * 256 + threadIdx.x;   // < 1536
  if (tau >= 1536) return;
  int lane = tau & 63, frag = tau >> 6;
  int ks = frag / 3, cf = frag % 3;
  int col = cf * 16 + (lane & 15);
  #pragma unroll
  for (int j = 0; j < 8; ++j) {
    int k = ks * 32 + ((lane >> 4) << 3) + j;
    o[tau * 8 + j] = (col < OD) ? f2bf(W2[k * OD + col]) : (unsigned short)0;
  }
}

// ---- exclusive scan over cnt[i] = ideg[i]+1 ----
__global__ __launch_bounds__(256) void scan1_kernel(const int* __restrict__ ideg,
    int* __restrict__ off, int* __restrict__ bsum) {
  __shared__ int lds[256];
  int t = threadIdx.x;
  int i = blockIdx.x * 256 + t;
  int v = (i < N_NODES) ? ideg[i] + 1 : 0;
  lds[t] = v;
  __syncthreads();
  for (int s = 1; s < 256; s <<= 1) {
    int add = (t >= s) ? lds[t - s] : 0;
    __syncthreads();
    lds[t] += add;
    __syncthreads();
  }
  int inc = lds[t];
  if (i < N_NODES) off[i] = inc - v;
  if (t == 255) bsum[blockIdx.x] = inc;
}

__global__ __launch_bounds__(256) void scan2_kernel(int* __restrict__ bsum, int* __restrict__ bso, int nb) {
  __shared__ int lds[256];
  int t = threadIdx.x;
  int v = (t < nb) ? bsum[t] : 0;
  lds[t] = v;
  __syncthreads();
  for (int s = 1; s < 256; s <<= 1) {
    int add = (t >= s) ? lds[t - s] : 0;
    __syncthreads();
    lds[t] += add;
    __syncthreads();
  }
  if (t < nb) bso[t] = lds[t] - v;
}

__global__ __launch_bounds__(256) void scan3_kernel(int* __restrict__ off, const int* __restrict__ bso) {
  int i = blockIdx.x * 256 + threadIdx.x;
  if (i < N_NODES) off[i] += bso[blockIdx.x];
  if (i == 0) off[N_NODES] = N_TOT;
}

__global__ __launch_bounds__(256) void gstart_kernel(const int* __restrict__ batch, int* __restrict__ gstart) {
  int n = blockIdx.x * 256 + threadIdx.x;
  if (n >= N_NODES) return;
  if (n == 0) {
    for (int g = 0; g <= batch[0]; ++g) gstart[g] = 0;
  } else {
    int bp = batch[n - 1], bn = batch[n];
    for (int g = bp + 1; g <= bn; ++g) gstart[g] = n;
  }
  if (n == N_NODES - 1) {
    for (int g = batch[n] + 1; g <= NG; ++g) gstart[g] = N_NODES;
  }
}

// bucket edges by dst; record (xid, norm) and src
__global__ __launch_bounds__(256) void scatter_kernel(const int* __restrict__ ei,
    const int* __restrict__ x_ids, const float* __restrict__ dinv,
    const int* __restrict__ off, int* __restrict__ cur,
    int2* __restrict__ xn, int* __restrict__ ssrc) {
  int e = blockIdx.x * 256 + threadIdx.x;
  if (e >= N_TOT) return;
  int s, d; float nrm;
  if (e < N_EDGES) {
    s = ei[e]; d = ei[N_EDGES + e];
    nrm = dinv[s] * dinv[d];
  } else {
    s = d = e - N_EDGES;
    float di = dinv[s]; nrm = di * di;
  }
  int pos = off[d] + atomicAdd(&cur[d], 1);
  xn[pos] = make_int2(x_ids[s], __float_as_int(nrm));
  ssrc[pos] = s;
}

// agg1[d][f] = sum over CSR[d] of norm * embb[xid][f]   (bf16 emb, bf16 out, fp32 acc)
__global__ __launch_bounds__(256) void agg1g_kernel(const int* __restrict__ off,
    const int2* __restrict__ xn, const unsigned short* __restrict__ embb,
    unsigned short* __restrict__ agg1) {
  int t = threadIdx.x;
  int node = blockIdx.x * 2 + (t >> 7);
  int f = t & 127;
  int beg = off[node], end = off[node + 1];
  float acc = 0.f;
  #pragma unroll 2
  for (int i = beg; i < end; ++i) {
    int2 r = xn[i];
    acc += __int_as_float(r.y) * bf2f(embb[r.x * SD + f]);
  }
  agg1[(size_t)node * SD + f] = f2bf(acc);
}

// y1 = relu(agg1 @ W1 + b1)  via bf16 MFMA.  64x256 tile, 4 waves x (4 rf x 4 cf), K=128.
__global__ __launch_bounds__(256) void gemm1_mfma(const unsigned short* __restrict__ agg1,
    const bh8* __restrict__ w1f, const float* __restrict__ b1, float* __restrict__ y1) {
  __shared__ char raw[16384];   // 64 x 128 bf16, XOR-swizzled
  int t = threadIdx.x, lane = t & 63, wave = t >> 6;
  int row0 = blockIdx.x * 64;
  // stage A (coalesced global, swizzled LDS)
  #pragma unroll
  for (int k = 0; k < 4; ++k) {
    int idx = k * 256 + t;            // 16B chunk id, tile = 1024 chunks
    int r = idx >> 4, c = idx & 15;
    int4 v = make_int4(0, 0, 0, 0);
    if (row0 + r < N_NODES)
      v = *(const int4*)((const char*)agg1 + (size_t)(row0 + r) * 256 + c * 16);
    *(int4*)(raw + ((r * 256 + c * 16) ^ ((r & 15) << 4))) = v;
  }
  // B frags (frag-linear, coalesced)
  bh8 bf[4][4];
  #pragma unroll
  for (int cf = 0; cf < 4; ++cf)
    #pragma unroll
    for (int ks = 0; ks < 4; ++ks)
      bf[cf][ks] = w1f[(ks * 16 + wave * 4 + cf) * 64 + lane];
  f4 acc[4][4];
  #pragma unroll
  for (int rf = 0; rf < 4; ++rf)
    #pragma unroll
    for (int cf = 0; cf < 4; ++cf)
      acc[rf][cf] = (f4){0.f, 0.f, 0.f, 0.f};
  __syncthreads();
  #pragma unroll
  for (int ks = 0; ks < 4; ++ks) {
    bh8 a[4];
    #pragma unroll
    for (int rf = 0; rf < 4; ++rf) {
      int r = rf * 16 + (lane & 15);
      int byte = (r * 256 + ks * 64 + ((lane >> 4) << 4)) ^ ((r & 15) << 4);
      a[rf] = *(const bh8*)(raw + byte);
    }
    #pragma unroll
    for (int rf = 0; rf < 4; ++rf)
      #pragma unroll
      for (int cf = 0; cf < 4; ++cf)
        acc[rf][cf] = __builtin_amdgcn_mfma_f32_16x16x32_bf16(a[rf], bf[cf][ks], acc[rf][cf], 0, 0, 0);
  }
  // epilogue: + b1, relu, fp32 store (C-frag: col=lane&15, row=(lane>>4)*4+reg)
  #pragma unroll
  for (int cf = 0; cf < 4; ++cf) {
    int col = wave * 64 + cf * 16 + (lane & 15);
    float bias = b1[col];
    #pragma unroll
    for (int rf = 0; rf < 4; ++rf)
      #pragma unroll
      for (int j = 0; j < 4; ++j) {
        int rg = row0 + rf * 16 + ((lane >> 4) << 2) + j;
        if (rg < N_NODES)
          y1[(size_t)rg * HD + col] = fmaxf(acc[rf][cf][j] + bias, 0.f);
      }
  }
}

// h2 = y1 @ W2  via bf16 MFMA.  64-row tile, wave w owns rows w*16..w*16+15, 3 cf, K=256.
__global__ __launch_bounds__(256) void gemm2_mfma(const float* __restrict__ y1,
    const bh8* __restrict__ w2f, float* __restrict__ h2) {
  __shared__ char raw[32768];   // 64 x 256 bf16, XOR-swizzled
  int t = threadIdx.x, lane = t & 63, wave = t >> 6;
  int row0 = blockIdx.x * 64;
  // stage A: fp32 global (coalesced) -> bf16 LDS (swizzled)
  #pragma unroll
  for (int k = 0; k < 16; ++k) {
    int idx = k * 256 + t;            // 8B chunk id, tile = 4096 chunks
    int r = idx >> 6, c8 = idx & 63;
    float4 v = make_float4(0.f, 0.f, 0.f, 0.f);
    if (row0 + r < N_NODES)
      v = *(const float4*)(y1 + (size_t)(row0 + r) * HD + c8 * 4);
    short4 p;
    p.x = (short)f2bf(v.x); p.y = (short)f2bf(v.y);
    p.z = (short)f2bf(v.z); p.w = (short)f2bf(v.w);
    *(short4*)(raw + ((r * 512 + c8 * 8) ^ ((r & 15) << 4))) = p;
  }
  bh8 bf[3][8];
  #pragma unroll
  for (int cf = 0; cf < 3; ++cf)
    #pragma unroll
    for (int ks = 0; ks < 8; ++ks)
      bf[cf][ks] = w2f[(ks * 3 + cf) * 64 + lane];
  f4 acc[3];
  #pragma unroll
  for (int cf = 0; cf < 3; ++cf) acc[cf] = (f4){0.f, 0.f, 0.f, 0.f};
  __syncthreads();
  int r = wave * 16 + (lane & 15);
  #pragma unroll
  for (int ks = 0; ks < 8; ++ks) {
    int byte = (r * 512 + ks * 64 + ((lane >> 4) << 4)) ^ ((r & 15) << 4);
    bh8 a = *(const bh8*)(raw + byte);
    #pragma unroll
    for (int cf = 0; cf < 3; ++cf)
      acc[cf] = __builtin_amdgcn_mfma_f32_16x16x32_bf16(a, bf[cf][ks], acc[cf], 0, 0, 0);
  }
  #pragma unroll
  for (int cf = 0; cf < 3; ++cf) {
    int col = cf * 16 + (lane & 15);
    #pragma unroll
    for (int j = 0; j < 4; ++j) {
      int rg = row0 + wave * 16 + ((lane >> 4) << 2) + j;
      if (rg < N_NODES)
        h2[(size_t)rg * ODP + col] = acc[cf][j];
    }
  }
}

// fused layer-2 aggregation + graph pooling
__global__ __launch_bounds__(256) void pool2_kernel(const int* __restrict__ gstart,
    const int* __restrict__ off, const int* __restrict__ ssrc, const int2* __restrict__ xn,
    const float* __restrict__ h2, const float* __restrict__ b2, float* __restrict__ out) {
  __shared__ float red[6 * 41];
  int g = blockIdx.x >> 2, c = blockIdx.x & 3;
  int t = threadIdx.x;
  int r = t / 41, f = t - r * 41;
  int n0 = gstart[g], n1 = gstart[g + 1];
  int e0 = off[n0], e1 = off[n1];
  int len = e1 - e0;
  int q0 = e0 + ((len * c) >> 2);
  int q1 = e0 + ((len * (c + 1)) >> 2);
  if (r < 6) {
    float acc = 0.f;
    for (int i = q0 + r; i < q1; i += 6)
      acc += __int_as_float(xn[i].y) * h2[(size_t)ssrc[i] * ODP + f];
    red[r * 41 + f] = acc;
  }
  __syncthreads();
  if (r == 0) {
    float s = red[f] + red[41 + f] + red[82 + f] + red[123 + f] + red[164 + f] + red[205 + f];
    if (c == 0) s += (float)(n1 - n0) * b2[f];
    unsafeAtomicAdd(&out[g * OD + f], s);
  }
}

extern "C" void kernel_launch(void* const* d_in, const int* in_sizes, int n_in,
                              void* d_out, int out_size, void* d_ws, size_t ws_size,
                              hipStream_t stream) {
  const int*   x_ids = (const int*)d_in[0];
  const int*   ei    = (const int*)d_in[1];
  const int*   batch = (const int*)d_in[2];
  const float* emb   = (const float*)d_in[3];
  const float* W1    = (const float*)d_in[4];
  const float* b1    = (const float*)d_in[5];
  const float* W2    = (const float*)d_in[6];
  const float* b2    = (const float*)d_in[7];
  float* out = (float*)d_out;
  char* ws = (char*)d_ws;

  // workspace layout (bytes)
  int*            ideg   = (int*)           (ws + 0);          // 200 KB
  float*          dinv   = (float*)         (ws + 204800);     // 200 KB
  int*            off    = (int*)           (ws + 409600);     // 200 KB (+4)
  int*            cur    = (int*)           (ws + 614400);     // 200 KB
  int*            bsum   = (int*)           (ws + 819200);
  int*            bso    = (int*)           (ws + 820224);
  int*            gstart = (int*)           (ws + 821248);
  unsigned short* embb   = (unsigned short*)(ws + 1048576);    // 343 KB bf16 emb
  unsigned short* w1f    = (unsigned short*)(ws + 1441792);    // 64 KB frag-linear
  unsigned short* w2f    = (unsigned short*)(ws + 1507328);    // 24 KB frag-linear
  int2*           xn     = (int2*)          (ws + 2097152);    // 6.8 MB
  int*            ssrc   = (int*)           (ws + 9437184);    // 3.4 MB
  unsigned short* agg1   = (unsigned short*)(ws + 13631488);   // 12.8 MB bf16
  float*          h2     = (float*)         (ws + 13631488);   // 9.6 MB (reuses agg1 after gemm1)
  float*          y1     = (float*)         (ws + 27262976);   // 51.2 MB fp32 (end ~78.5 MB)

  fill4_kernel<<<49, 256, 0, stream>>>((float4*)ideg, 0.f, 12500);
  fill4_kernel<<<49, 256, 0, stream>>>((float4*)cur,  0.f, 12500);
  fill4_kernel<<<21, 256, 0, stream>>>((float4*)out,  0.f, 5248);

  cvt_emb_kernel<<<670, 256, 0, stream>>>(emb, embb);
  cvt_w1_kernel <<<16,  256, 0, stream>>>(W1, w1f);
  cvt_w2_kernel <<<6,   256, 0, stream>>>(W2, w2f);

  deg_kernel  <<<3125, 256, 0, stream>>>(ei, ideg);
  dinv_kernel <<<196,  256, 0, stream>>>(ideg, dinv);

  scan1_kernel <<<196, 256, 0, stream>>>(ideg, off, bsum);
  scan2_kernel <<<1,   256, 0, stream>>>(bsum, bso, 196);
  scan3_kernel <<<196, 256, 0, stream>>>(off, bso);
  gstart_kernel<<<196, 256, 0, stream>>>(batch, gstart);

  scatter_kernel<<<3321, 256, 0, stream>>>(ei, x_ids, dinv, off, cur, xn, ssrc);

  agg1g_kernel<<<25000, 256, 0, stream>>>(off, xn, embb, agg1);
  gemm1_mfma  <<<782,   256, 0, stream>>>(agg1, (const bh8*)w1f, b1, y1);
  gemm2_mfma  <<<782,   256, 0, stream>>>(y1, (const bh8*)w2f, h2);
  pool2_kernel<<<2048,  256, 0, stream>>>(gstart, off, ssrc, xn, h2, b2, out);
}

// Round 4
// 222.068 us; speedup vs baseline: 8.2603x; 1.1919x over previous
//
#include <hip/hip_runtime.h>

#define N_NODES 50000
#define N_EDGES 800000
#define N_TOT   850000   // edges + self-loops
#define SD 128
#define HD 256
#define OD 41
#define ODP 48
#define NG 512

typedef __attribute__((ext_vector_type(8))) short bh8;   // 8 bf16 = 4 VGPR (MFMA A/B frag)
typedef __attribute__((ext_vector_type(4))) float f4;    // MFMA C/D frag

__device__ inline unsigned short f2bf(float x) {         // RNE float->bf16
  unsigned u = __float_as_uint(x);
  unsigned r = u + 0x7fff + ((u >> 16) & 1);
  return (unsigned short)(r >> 16);
}
__device__ inline float bf2f(unsigned short s) {
  return __uint_as_float(((unsigned)s) << 16);
}
__device__ inline float bflo(unsigned e) { return __uint_as_float(e << 16); }
__device__ inline float bfhi(unsigned e) { return __uint_as_float(e & 0xffff0000u); }

__global__ __launch_bounds__(256) void fill4_kernel(float4* __restrict__ p, float v, int n4) {
  int i = blockIdx.x * 256 + threadIdx.x;
  if (i < n4) p[i] = make_float4(v, v, v, v);
}

__global__ __launch_bounds__(256) void deg_kernel(const int* __restrict__ ei, int* __restrict__ ideg) {
  int e = blockIdx.x * 256 + threadIdx.x;
  if (e < N_EDGES) atomicAdd(&ideg[ei[N_EDGES + e]], 1);
}

__global__ __launch_bounds__(256) void dinv_kernel(const int* __restrict__ ideg, float* __restrict__ dinv) {
  int i = blockIdx.x * 256 + threadIdx.x;
  if (i < N_NODES) dinv[i] = rsqrtf((float)(ideg[i] + 1));  // +1 = self-loop
}

// ---- dtype conversions / frag-linear weight layouts (tiny, once per launch) ----
__global__ __launch_bounds__(256) void cvt_emb_kernel(const float* __restrict__ emb,
    unsigned short* __restrict__ o) {
  int i = blockIdx.x * 256 + threadIdx.x;
  if (i < 1340 * SD) o[i] = f2bf(emb[i]);
}

// W1f[frag=ks*16+cf][lane][j] = bf16(W1[ks*32+(lane>>4)*8+j][cf*16+(lane&15)])
__global__ __launch_bounds__(256) void cvt_w1_kernel(const float* __restrict__ W1,
    unsigned short* __restrict__ o) {
  int tau = blockIdx.x * 256 + threadIdx.x;   // < 4096
  int lane = tau & 63, frag = tau >> 6;
  int ks = frag >> 4, cf = frag & 15;
  int col = cf * 16 + (lane & 15);
  #pragma unroll
  for (int j = 0; j < 8; ++j) {
    int k = ks * 32 + ((lane >> 4) << 3) + j;
    o[tau * 8 + j] = f2bf(W1[k * HD + col]);
  }
}

// W2f[frag=ks*3+cf][lane][j], zero-padded cols 41..47
__global__ __launch_bounds__(256) void cvt_w2_kernel(const float* __restrict__ W2,
    unsigned short* __restrict__ o) {
  int tau = blockIdx.x * 256 + threadIdx.x;   // < 1536
  if (tau >= 1536) return;
  int lane = tau & 63, frag = tau >> 6;
  int ks = frag / 3, cf = frag % 3;
  int col = cf * 16 + (lane & 15);
  #pragma unroll
  for (int j = 0; j < 8; ++j) {
    int k = ks * 32 + ((lane >> 4) << 3) + j;
    o[tau * 8 + j] = (col < OD) ? f2bf(W2[k * OD + col]) : (unsigned short)0;
  }
}

// ---- exclusive scan over cnt[i] = ideg[i]+1 ----
__global__ __launch_bounds__(256) void scan1_kernel(const int* __restrict__ ideg,
    int* __restrict__ off, int* __restrict__ bsum) {
  __shared__ int lds[256];
  int t = threadIdx.x;
  int i = blockIdx.x * 256 + t;
  int v = (i < N_NODES) ? ideg[i] + 1 : 0;
  lds[t] = v;
  __syncthreads();
  for (int s = 1; s < 256; s <<= 1) {
    int add = (t >= s) ? lds[t - s] : 0;
    __syncthreads();
    lds[t] += add;
    __syncthreads();
  }
  int inc = lds[t];
  if (i < N_NODES) off[i] = inc - v;
  if (t == 255) bsum[blockIdx.x] = inc;
}

__global__ __launch_bounds__(256) void scan2_kernel(int* __restrict__ bsum, int* __restrict__ bso, int nb) {
  __shared__ int lds[256];
  int t = threadIdx.x;
  int v = (t < nb) ? bsum[t] : 0;
  lds[t] = v;
  __syncthreads();
  for (int s = 1; s < 256; s <<= 1) {
    int add = (t >= s) ? lds[t - s] : 0;
    __syncthreads();
    lds[t] += add;
    __syncthreads();
  }
  if (t < nb) bso[t] = lds[t] - v;
}

__global__ __launch_bounds__(256) void scan3_kernel(int* __restrict__ off, const int* __restrict__ bso) {
  int i = blockIdx.x * 256 + threadIdx.x;
  if (i < N_NODES) off[i] += bso[blockIdx.x];
  if (i == 0) off[N_NODES] = N_TOT;
}

__global__ __launch_bounds__(256) void gstart_kernel(const int* __restrict__ batch, int* __restrict__ gstart) {
  int n = blockIdx.x * 256 + threadIdx.x;
  if (n >= N_NODES) return;
  if (n == 0) {
    for (int g = 0; g <= batch[0]; ++g) gstart[g] = 0;
  } else {
    int bp = batch[n - 1], bn = batch[n];
    for (int g = bp + 1; g <= bn; ++g) gstart[g] = n;
  }
  if (n == N_NODES - 1) {
    for (int g = batch[n] + 1; g <= NG; ++g) gstart[g] = N_NODES;
  }
}

// bucket edges by dst; record (xid, norm) and src
__global__ __launch_bounds__(256) void scatter_kernel(const int* __restrict__ ei,
    const int* __restrict__ x_ids, const float* __restrict__ dinv,
    const int* __restrict__ off, int* __restrict__ cur,
    int2* __restrict__ xn, int* __restrict__ ssrc) {
  int e = blockIdx.x * 256 + threadIdx.x;
  if (e >= N_TOT) return;
  int s, d; float nrm;
  if (e < N_EDGES) {
    s = ei[e]; d = ei[N_EDGES + e];
    nrm = dinv[s] * dinv[d];
  } else {
    s = d = e - N_EDGES;
    float di = dinv[s]; nrm = di * di;
  }
  int pos = off[d] + atomicAdd(&cur[d], 1);
  xn[pos] = make_int2(x_ids[s], __float_as_int(nrm));
  ssrc[pos] = s;
}

// agg1[d][f] = sum over CSR[d] of norm * embb[xid][f]
// wave-per-node: lane owns 2 features (4B packed), 4-edge unroll for ILP.
__global__ __launch_bounds__(256) void agg1w_kernel(const int* __restrict__ off,
    const int2* __restrict__ xn, const unsigned int* __restrict__ embw,
    unsigned int* __restrict__ agg1w) {
  int lane = threadIdx.x & 63;
  int node = __builtin_amdgcn_readfirstlane(blockIdx.x * 4 + (threadIdx.x >> 6));
  int beg = off[node], end = off[node + 1];
  float a0 = 0.f, a1 = 0.f;
  int i = beg;
  for (; i + 4 <= end; i += 4) {
    int2 r0 = xn[i], r1 = xn[i + 1], r2 = xn[i + 2], r3 = xn[i + 3];
    unsigned e0 = embw[r0.x * 64 + lane];
    unsigned e1 = embw[r1.x * 64 + lane];
    unsigned e2 = embw[r2.x * 64 + lane];
    unsigned e3 = embw[r3.x * 64 + lane];
    float n0 = __int_as_float(r0.y), n1 = __int_as_float(r1.y);
    float n2 = __int_as_float(r2.y), n3 = __int_as_float(r3.y);
    a0 += n0 * bflo(e0); a1 += n0 * bfhi(e0);
    a0 += n1 * bflo(e1); a1 += n1 * bfhi(e1);
    a0 += n2 * bflo(e2); a1 += n2 * bfhi(e2);
    a0 += n3 * bflo(e3); a1 += n3 * bfhi(e3);
  }
  for (; i < end; ++i) {
    int2 r = xn[i];
    unsigned e = embw[r.x * 64 + lane];
    float n = __int_as_float(r.y);
    a0 += n * bflo(e); a1 += n * bfhi(e);
  }
  unsigned packed = (unsigned)f2bf(a0) | ((unsigned)f2bf(a1) << 16);
  agg1w[node * 64 + lane] = packed;
}

// y1 = relu(agg1 @ W1 + b1)  via bf16 MFMA.  64x256 tile, 4 waves x (4 rf x 4 cf), K=128.
// y1 stored bf16 (numerically identical to fp32 store + later cvt).
__global__ __launch_bounds__(256) void gemm1_mfma(const unsigned short* __restrict__ agg1,
    const bh8* __restrict__ w1f, const float* __restrict__ b1, unsigned short* __restrict__ y1b) {
  __shared__ char raw[16384];   // 64 x 128 bf16, XOR-swizzled
  int t = threadIdx.x, lane = t & 63, wave = t >> 6;
  int row0 = blockIdx.x * 64;
  #pragma unroll
  for (int k = 0; k < 4; ++k) {
    int idx = k * 256 + t;            // 16B chunk id, tile = 1024 chunks
    int r = idx >> 4, c = idx & 15;
    int4 v = make_int4(0, 0, 0, 0);
    if (row0 + r < N_NODES)
      v = *(const int4*)((const char*)agg1 + (size_t)(row0 + r) * 256 + c * 16);
    *(int4*)(raw + ((r * 256 + c * 16) ^ ((r & 15) << 4))) = v;
  }
  bh8 bf[4][4];
  #pragma unroll
  for (int cf = 0; cf < 4; ++cf)
    #pragma unroll
    for (int ks = 0; ks < 4; ++ks)
      bf[cf][ks] = w1f[(ks * 16 + wave * 4 + cf) * 64 + lane];
  f4 acc[4][4];
  #pragma unroll
  for (int rf = 0; rf < 4; ++rf)
    #pragma unroll
    for (int cf = 0; cf < 4; ++cf)
      acc[rf][cf] = (f4){0.f, 0.f, 0.f, 0.f};
  __syncthreads();
  #pragma unroll
  for (int ks = 0; ks < 4; ++ks) {
    bh8 a[4];
    #pragma unroll
    for (int rf = 0; rf < 4; ++rf) {
      int r = rf * 16 + (lane & 15);
      int byte = (r * 256 + ks * 64 + ((lane >> 4) << 4)) ^ ((r & 15) << 4);
      a[rf] = *(const bh8*)(raw + byte);
    }
    #pragma unroll
    for (int rf = 0; rf < 4; ++rf)
      #pragma unroll
      for (int cf = 0; cf < 4; ++cf)
        acc[rf][cf] = __builtin_amdgcn_mfma_f32_16x16x32_bf16(a[rf], bf[cf][ks], acc[rf][cf], 0, 0, 0);
  }
  #pragma unroll
  for (int cf = 0; cf < 4; ++cf) {
    int col = wave * 64 + cf * 16 + (lane & 15);
    float bias = b1[col];
    #pragma unroll
    for (int rf = 0; rf < 4; ++rf)
      #pragma unroll
      for (int j = 0; j < 4; ++j) {
        int rg = row0 + rf * 16 + ((lane >> 4) << 2) + j;
        if (rg < N_NODES)
          y1b[(size_t)rg * HD + col] = f2bf(fmaxf(acc[rf][cf][j] + bias, 0.f));
      }
  }
}

// h2 = y1b(bf16) @ W2  via bf16 MFMA.  64-row tile, wave w owns rows w*16..., 3 cf, K=256.
__global__ __launch_bounds__(256) void gemm2_mfma(const unsigned short* __restrict__ y1b,
    const bh8* __restrict__ w2f, float* __restrict__ h2) {
  __shared__ char raw[32768];   // 64 x 256 bf16, XOR-swizzled
  int t = threadIdx.x, lane = t & 63, wave = t >> 6;
  int row0 = blockIdx.x * 64;
  #pragma unroll
  for (int k = 0; k < 16; ++k) {
    int idx = k * 256 + t;            // 8B chunk id, tile = 4096 chunks
    int r = idx >> 6, c8 = idx & 63;
    int2 v = make_int2(0, 0);
    if (row0 + r < N_NODES)
      v = *(const int2*)(y1b + (size_t)(row0 + r) * HD + c8 * 4);
    *(int2*)(raw + ((r * 512 + c8 * 8) ^ ((r & 15) << 4))) = v;
  }
  bh8 bf[3][8];
  #pragma unroll
  for (int cf = 0; cf < 3; ++cf)
    #pragma unroll
    for (int ks = 0; ks < 8; ++ks)
      bf[cf][ks] = w2f[(ks * 3 + cf) * 64 + lane];
  f4 acc[3];
  #pragma unroll
  for (int cf = 0; cf < 3; ++cf) acc[cf] = (f4){0.f, 0.f, 0.f, 0.f};
  __syncthreads();
  int r = wave * 16 + (lane & 15);
  #pragma unroll
  for (int ks = 0; ks < 8; ++ks) {
    int byte = (r * 512 + ks * 64 + ((lane >> 4) << 4)) ^ ((r & 15) << 4);
    bh8 a = *(const bh8*)(raw + byte);
    #pragma unroll
    for (int cf = 0; cf < 3; ++cf)
      acc[cf] = __builtin_amdgcn_mfma_f32_16x16x32_bf16(a, bf[cf][ks], acc[cf], 0, 0, 0);
  }
  #pragma unroll
  for (int cf = 0; cf < 3; ++cf) {
    int col = cf * 16 + (lane & 15);
    #pragma unroll
    for (int j = 0; j < 4; ++j) {
      int rg = row0 + wave * 16 + ((lane >> 4) << 2) + j;
      if (rg < N_NODES)
        h2[(size_t)rg * ODP + col] = acc[cf][j];
    }
  }
}

// fused layer-2 aggregation + graph pooling
__global__ __launch_bounds__(256) void pool2_kernel(const int* __restrict__ gstart,
    const int* __restrict__ off, const int* __restrict__ ssrc, const int2* __restrict__ xn,
    const float* __restrict__ h2, const float* __restrict__ b2, float* __restrict__ out) {
  __shared__ float red[6 * 41];
  int g = blockIdx.x >> 2, c = blockIdx.x & 3;
  int t = threadIdx.x;
  int r = t / 41, f = t - r * 41;
  int n0 = gstart[g], n1 = gstart[g + 1];
  int e0 = off[n0], e1 = off[n1];
  int len = e1 - e0;
  int q0 = e0 + ((len * c) >> 2);
  int q1 = e0 + ((len * (c + 1)) >> 2);
  if (r < 6) {
    float acc = 0.f;
    for (int i = q0 + r; i < q1; i += 6)
      acc += __int_as_float(xn[i].y) * h2[(size_t)ssrc[i] * ODP + f];
    red[r * 41 + f] = acc;
  }
  __syncthreads();
  if (r == 0) {
    float s = red[f] + red[41 + f] + red[82 + f] + red[123 + f] + red[164 + f] + red[205 + f];
    if (c == 0) s += (float)(n1 - n0) * b2[f];
    unsafeAtomicAdd(&out[g * OD + f], s);
  }
}

extern "C" void kernel_launch(void* const* d_in, const int* in_sizes, int n_in,
                              void* d_out, int out_size, void* d_ws, size_t ws_size,
                              hipStream_t stream) {
  const int*   x_ids = (const int*)d_in[0];
  const int*   ei    = (const int*)d_in[1];
  const int*   batch = (const int*)d_in[2];
  const float* emb   = (const float*)d_in[3];
  const float* W1    = (const float*)d_in[4];
  const float* b1    = (const float*)d_in[5];
  const float* W2    = (const float*)d_in[6];
  const float* b2    = (const float*)d_in[7];
  float* out = (float*)d_out;
  char* ws = (char*)d_ws;

  // workspace layout (bytes)
  int*            ideg   = (int*)           (ws + 0);          // 200 KB
  float*          dinv   = (float*)         (ws + 204800);     // 200 KB
  int*            off    = (int*)           (ws + 409600);     // 200 KB (+4)
  int*            cur    = (int*)           (ws + 614400);     // 200 KB
  int*            bsum   = (int*)           (ws + 819200);
  int*            bso    = (int*)           (ws + 820224);
  int*            gstart = (int*)           (ws + 821248);
  unsigned short* embb   = (unsigned short*)(ws + 1048576);    // 343 KB bf16 emb
  unsigned short* w1f    = (unsigned short*)(ws + 1441792);    // 64 KB frag-linear
  unsigned short* w2f    = (unsigned short*)(ws + 1507328);    // 24 KB frag-linear
  int2*           xn     = (int2*)          (ws + 2097152);    // 6.8 MB
  int*            ssrc   = (int*)           (ws + 9437184);    // 3.4 MB
  unsigned short* agg1   = (unsigned short*)(ws + 13631488);   // 12.8 MB bf16
  float*          h2     = (float*)         (ws + 13631488);   // 9.6 MB (reuses agg1 after gemm1)
  unsigned short* y1b    = (unsigned short*)(ws + 27262976);   // 25.6 MB bf16 (end ~52.9 MB)

  fill4_kernel<<<49, 256, 0, stream>>>((float4*)ideg, 0.f, 12500);
  fill4_kernel<<<49, 256, 0, stream>>>((float4*)cur,  0.f, 12500);
  fill4_kernel<<<21, 256, 0, stream>>>((float4*)out,  0.f, 5248);

  cvt_emb_kernel<<<670, 256, 0, stream>>>(emb, embb);
  cvt_w1_kernel <<<16,  256, 0, stream>>>(W1, w1f);
  cvt_w2_kernel <<<6,   256, 0, stream>>>(W2, w2f);

  deg_kernel  <<<3125, 256, 0, stream>>>(ei, ideg);
  dinv_kernel <<<196,  256, 0, stream>>>(ideg, dinv);

  scan1_kernel <<<196, 256, 0, stream>>>(ideg, off, bsum);
  scan2_kernel <<<1,   256, 0, stream>>>(bsum, bso, 196);
  scan3_kernel <<<196, 256, 0, stream>>>(off, bso);
  gstart_kernel<<<196, 256, 0, stream>>>(batch, gstart);

  scatter_kernel<<<3321, 256, 0, stream>>>(ei, x_ids, dinv, off, cur, xn, ssrc);

  agg1w_kernel<<<12500, 256, 0, stream>>>(off, xn, (const unsigned int*)embb, (unsigned int*)agg1);
  gemm1_mfma  <<<782,   256, 0, stream>>>(agg1, (const bh8*)w1f, b1, y1b);
  gemm2_mfma  <<<782,   256, 0, stream>>>(y1b, (const bh8*)w2f, h2);
  pool2_kernel<<<2048,  256, 0, stream>>>(gstart, off, ssrc, xn, h2, b2, out);
}

// Round 5
// 216.258 us; speedup vs baseline: 8.4822x; 1.0269x over previous
//
#include <hip/hip_runtime.h>

#define N_NODES 50000
#define N_EDGES 800000
#define N_TOT   850000   // edges + self-loops
#define SD 128
#define HD 256
#define OD 41
#define ODP 48
#define NG 512

typedef __attribute__((ext_vector_type(8))) short bh8;   // 8 bf16 = 4 VGPR (MFMA A/B frag)
typedef __attribute__((ext_vector_type(4))) float f4;    // MFMA C/D frag

__device__ inline unsigned short f2bf(float x) {         // RNE float->bf16
  unsigned u = __float_as_uint(x);
  unsigned r = u + 0x7fff + ((u >> 16) & 1);
  return (unsigned short)(r >> 16);
}
__device__ inline float bf2f(unsigned short s) {
  return __uint_as_float(((unsigned)s) << 16);
}
__device__ inline float bflo(unsigned e) { return __uint_as_float(e << 16); }
__device__ inline float bfhi(unsigned e) { return __uint_as_float(e & 0xffff0000u); }

__global__ __launch_bounds__(256) void fill4_kernel(float4* __restrict__ p, float v, int n4) {
  int i = blockIdx.x * 256 + threadIdx.x;
  if (i < n4) p[i] = make_float4(v, v, v, v);
}

__global__ __launch_bounds__(256) void deg_kernel(const int* __restrict__ ei, int* __restrict__ ideg) {
  int e = blockIdx.x * 256 + threadIdx.x;
  if (e < N_EDGES) atomicAdd(&ideg[ei[N_EDGES + e]], 1);
}

__global__ __launch_bounds__(256) void dinv_kernel(const int* __restrict__ ideg, float* __restrict__ dinv) {
  int i = blockIdx.x * 256 + threadIdx.x;
  if (i < N_NODES) dinv[i] = rsqrtf((float)(ideg[i] + 1));  // +1 = self-loop
}

// ---- dtype conversions / frag-linear weight layouts (tiny, once per launch) ----
__global__ __launch_bounds__(256) void cvt_emb_kernel(const float* __restrict__ emb,
    unsigned short* __restrict__ o) {
  int i = blockIdx.x * 256 + threadIdx.x;
  if (i < 1340 * SD) o[i] = f2bf(emb[i]);
}

// W1f[frag=ks*16+cf][lane][j] = bf16(W1[ks*32+(lane>>4)*8+j][cf*16+(lane&15)])
__global__ __launch_bounds__(256) void cvt_w1_kernel(const float* __restrict__ W1,
    unsigned short* __restrict__ o) {
  int tau = blockIdx.x * 256 + threadIdx.x;   // < 4096
  int lane = tau & 63, frag = tau >> 6;
  int ks = frag >> 4, cf = frag & 15;
  int col = cf * 16 + (lane & 15);
  #pragma unroll
  for (int j = 0; j < 8; ++j) {
    int k = ks * 32 + ((lane >> 4) << 3) + j;
    o[tau * 8 + j] = f2bf(W1[k * HD + col]);
  }
}

// W2f[frag=ks*3+cf][lane][j], zero-padded cols 41..47
__global__ __launch_bounds__(256) void cvt_w2_kernel(const float* __restrict__ W2,
    unsigned short* __restrict__ o) {
  int tau = blockIdx.x * 256 + threadIdx.x;   // < 1536
  if (tau >= 1536) return;
  int lane = tau & 63, frag = tau >> 6;
  int ks = frag / 3, cf = frag % 3;
  int col = cf * 16 + (lane & 15);
  #pragma unroll
  for (int j = 0; j < 8; ++j) {
    int k = ks * 32 + ((lane >> 4) << 3) + j;
    o[tau * 8 + j] = (col < OD) ? f2bf(W2[k * OD + col]) : (unsigned short)0;
  }
}

// ---- exclusive scan over cnt[i] = ideg[i]+1 ----
__global__ __launch_bounds__(256) void scan1_kernel(const int* __restrict__ ideg,
    int* __restrict__ off, int* __restrict__ bsum) {
  __shared__ int lds[256];
  int t = threadIdx.x;
  int i = blockIdx.x * 256 + t;
  int v = (i < N_NODES) ? ideg[i] + 1 : 0;
  lds[t] = v;
  __syncthreads();
  for (int s = 1; s < 256; s <<= 1) {
    int add = (t >= s) ? lds[t - s] : 0;
    __syncthreads();
    lds[t] += add;
    __syncthreads();
  }
  int inc = lds[t];
  if (i < N_NODES) off[i] = inc - v;
  if (t == 255) bsum[blockIdx.x] = inc;
}

__global__ __launch_bounds__(256) void scan2_kernel(int* __restrict__ bsum, int* __restrict__ bso, int nb) {
  __shared__ int lds[256];
  int t = threadIdx.x;
  int v = (t < nb) ? bsum[t] : 0;
  lds[t] = v;
  __syncthreads();
  for (int s = 1; s < 256; s <<= 1) {
    int add = (t >= s) ? lds[t - s] : 0;
    __syncthreads();
    lds[t] += add;
    __syncthreads();
  }
  if (t < nb) bso[t] = lds[t] - v;
}

__global__ __launch_bounds__(256) void scan3_kernel(int* __restrict__ off, const int* __restrict__ bso) {
  int i = blockIdx.x * 256 + threadIdx.x;
  if (i < N_NODES) off[i] += bso[blockIdx.x];
  if (i == 0) off[N_NODES] = N_TOT;
}

__global__ __launch_bounds__(256) void gstart_kernel(const int* __restrict__ batch, int* __restrict__ gstart) {
  int n = blockIdx.x * 256 + threadIdx.x;
  if (n >= N_NODES) return;
  if (n == 0) {
    for (int g = 0; g <= batch[0]; ++g) gstart[g] = 0;
  } else {
    int bp = batch[n - 1], bn = batch[n];
    for (int g = bp + 1; g <= bn; ++g) gstart[g] = n;
  }
  if (n == N_NODES - 1) {
    for (int g = batch[n] + 1; g <= NG; ++g) gstart[g] = N_NODES;
  }
}

// bucket edges by dst; one aligned 16B record (xid, norm, src, 0) per edge
__global__ __launch_bounds__(256) void scatter_kernel(const int* __restrict__ ei,
    const int* __restrict__ x_ids, const float* __restrict__ dinv,
    const int* __restrict__ off, int* __restrict__ cur, int4* __restrict__ rec) {
  int e = blockIdx.x * 256 + threadIdx.x;
  if (e >= N_TOT) return;
  int s, d; float nrm;
  if (e < N_EDGES) {
    s = ei[e]; d = ei[N_EDGES + e];
    nrm = dinv[s] * dinv[d];
  } else {
    s = d = e - N_EDGES;
    float di = dinv[s]; nrm = di * di;
  }
  int pos = off[d] + atomicAdd(&cur[d], 1);
  rec[pos] = make_int4(x_ids[s], __float_as_int(nrm), s, 0);
}

// agg1[d][f] = sum over CSR[d] of norm * embb[xid][f]
// wave-per-node: lane owns 2 features (4B packed), 4-edge unroll for ILP.
__global__ __launch_bounds__(256) void agg1w_kernel(const int* __restrict__ off,
    const int4* __restrict__ rec, const unsigned int* __restrict__ embw,
    unsigned int* __restrict__ agg1w) {
  int lane = threadIdx.x & 63;
  int node = __builtin_amdgcn_readfirstlane(blockIdx.x * 4 + (threadIdx.x >> 6));
  int beg = off[node], end = off[node + 1];
  float a0 = 0.f, a1 = 0.f;
  int i = beg;
  for (; i + 4 <= end; i += 4) {
    int4 r0 = rec[i], r1 = rec[i + 1], r2 = rec[i + 2], r3 = rec[i + 3];
    unsigned e0 = embw[r0.x * 64 + lane];
    unsigned e1 = embw[r1.x * 64 + lane];
    unsigned e2 = embw[r2.x * 64 + lane];
    unsigned e3 = embw[r3.x * 64 + lane];
    float n0 = __int_as_float(r0.y), n1 = __int_as_float(r1.y);
    float n2 = __int_as_float(r2.y), n3 = __int_as_float(r3.y);
    a0 += n0 * bflo(e0); a1 += n0 * bfhi(e0);
    a0 += n1 * bflo(e1); a1 += n1 * bfhi(e1);
    a0 += n2 * bflo(e2); a1 += n2 * bfhi(e2);
    a0 += n3 * bflo(e3); a1 += n3 * bfhi(e3);
  }
  for (; i < end; ++i) {
    int4 r = rec[i];
    unsigned e = embw[r.x * 64 + lane];
    float n = __int_as_float(r.y);
    a0 += n * bflo(e); a1 += n * bfhi(e);
  }
  unsigned packed = (unsigned)f2bf(a0) | ((unsigned)f2bf(a1) << 16);
  agg1w[node * 64 + lane] = packed;
}

// y1 = relu(agg1 @ W1 + b1)  via bf16 MFMA.  64x256 tile, 4 waves x (4 rf x 4 cf), K=128.
__global__ __launch_bounds__(256) void gemm1_mfma(const unsigned short* __restrict__ agg1,
    const bh8* __restrict__ w1f, const float* __restrict__ b1, unsigned short* __restrict__ y1b) {
  __shared__ char raw[16384];   // 64 x 128 bf16, XOR-swizzled
  int t = threadIdx.x, lane = t & 63, wave = t >> 6;
  int row0 = blockIdx.x * 64;
  #pragma unroll
  for (int k = 0; k < 4; ++k) {
    int idx = k * 256 + t;            // 16B chunk id, tile = 1024 chunks
    int r = idx >> 4, c = idx & 15;
    int4 v = make_int4(0, 0, 0, 0);
    if (row0 + r < N_NODES)
      v = *(const int4*)((const char*)agg1 + (size_t)(row0 + r) * 256 + c * 16);
    *(int4*)(raw + ((r * 256 + c * 16) ^ ((r & 15) << 4))) = v;
  }
  bh8 bf[4][4];
  #pragma unroll
  for (int cf = 0; cf < 4; ++cf)
    #pragma unroll
    for (int ks = 0; ks < 4; ++ks)
      bf[cf][ks] = w1f[(ks * 16 + wave * 4 + cf) * 64 + lane];
  f4 acc[4][4];
  #pragma unroll
  for (int rf = 0; rf < 4; ++rf)
    #pragma unroll
    for (int cf = 0; cf < 4; ++cf)
      acc[rf][cf] = (f4){0.f, 0.f, 0.f, 0.f};
  __syncthreads();
  #pragma unroll
  for (int ks = 0; ks < 4; ++ks) {
    bh8 a[4];
    #pragma unroll
    for (int rf = 0; rf < 4; ++rf) {
      int r = rf * 16 + (lane & 15);
      int byte = (r * 256 + ks * 64 + ((lane >> 4) << 4)) ^ ((r & 15) << 4);
      a[rf] = *(const bh8*)(raw + byte);
    }
    #pragma unroll
    for (int rf = 0; rf < 4; ++rf)
      #pragma unroll
      for (int cf = 0; cf < 4; ++cf)
        acc[rf][cf] = __builtin_amdgcn_mfma_f32_16x16x32_bf16(a[rf], bf[cf][ks], acc[rf][cf], 0, 0, 0);
  }
  #pragma unroll
  for (int cf = 0; cf < 4; ++cf) {
    int col = wave * 64 + cf * 16 + (lane & 15);
    float bias = b1[col];
    #pragma unroll
    for (int rf = 0; rf < 4; ++rf)
      #pragma unroll
      for (int j = 0; j < 4; ++j) {
        int rg = row0 + rf * 16 + ((lane >> 4) << 2) + j;
        if (rg < N_NODES)
          y1b[(size_t)rg * HD + col] = f2bf(fmaxf(acc[rf][cf][j] + bias, 0.f));
      }
  }
}

// h2b = bf16(y1b @ W2)  via bf16 MFMA.  64-row tile, wave w owns rows w*16.., 3 cf, K=256.
__global__ __launch_bounds__(256) void gemm2_mfma(const unsigned short* __restrict__ y1b,
    const bh8* __restrict__ w2f, unsigned short* __restrict__ h2b) {
  __shared__ char raw[32768];   // 64 x 256 bf16, XOR-swizzled
  int t = threadIdx.x, lane = t & 63, wave = t >> 6;
  int row0 = blockIdx.x * 64;
  #pragma unroll
  for (int k = 0; k < 16; ++k) {
    int idx = k * 256 + t;            // 8B chunk id, tile = 4096 chunks
    int r = idx >> 6, c8 = idx & 63;
    int2 v = make_int2(0, 0);
    if (row0 + r < N_NODES)
      v = *(const int2*)(y1b + (size_t)(row0 + r) * HD + c8 * 4);
    *(int2*)(raw + ((r * 512 + c8 * 8) ^ ((r & 15) << 4))) = v;
  }
  bh8 bf[3][8];
  #pragma unroll
  for (int cf = 0; cf < 3; ++cf)
    #pragma unroll
    for (int ks = 0; ks < 8; ++ks)
      bf[cf][ks] = w2f[(ks * 3 + cf) * 64 + lane];
  f4 acc[3];
  #pragma unroll
  for (int cf = 0; cf < 3; ++cf) acc[cf] = (f4){0.f, 0.f, 0.f, 0.f};
  __syncthreads();
  int r = wave * 16 + (lane & 15);
  #pragma unroll
  for (int ks = 0; ks < 8; ++ks) {
    int byte = (r * 512 + ks * 64 + ((lane >> 4) << 4)) ^ ((r & 15) << 4);
    bh8 a = *(const bh8*)(raw + byte);
    #pragma unroll
    for (int cf = 0; cf < 3; ++cf)
      acc[cf] = __builtin_amdgcn_mfma_f32_16x16x32_bf16(a, bf[cf][ks], acc[cf], 0, 0, 0);
  }
  #pragma unroll
  for (int cf = 0; cf < 3; ++cf) {
    int col = cf * 16 + (lane & 15);
    #pragma unroll
    for (int j = 0; j < 4; ++j) {
      int rg = row0 + wave * 16 + ((lane >> 4) << 2) + j;
      if (rg < N_NODES)
        h2b[(size_t)rg * ODP + col] = f2bf(acc[cf][j]);
    }
  }
}

// fused layer-2 aggregation + graph pooling (bf16 h2 gather, fp32 accumulate)
__global__ __launch_bounds__(256) void pool2_kernel(const int* __restrict__ gstart,
    const int* __restrict__ off, const int4* __restrict__ rec,
    const unsigned short* __restrict__ h2b, const float* __restrict__ b2,
    float* __restrict__ out) {
  __shared__ float red[6 * 41];
  int g = blockIdx.x >> 2, c = blockIdx.x & 3;
  int t = threadIdx.x;
  int r = t / 41, f = t - r * 41;
  int n0 = gstart[g], n1 = gstart[g + 1];
  int e0 = off[n0], e1 = off[n1];
  int len = e1 - e0;
  int q0 = e0 + ((len * c) >> 2);
  int q1 = e0 + ((len * (c + 1)) >> 2);
  if (r < 6) {
    float acc = 0.f;
    for (int i = q0 + r; i < q1; i += 6) {
      int4 rc = rec[i];
      acc += __int_as_float(rc.y) * bf2f(h2b[(size_t)rc.z * ODP + f]);
    }
    red[r * 41 + f] = acc;
  }
  __syncthreads();
  if (r == 0) {
    float s = red[f] + red[41 + f] + red[82 + f] + red[123 + f] + red[164 + f] + red[205 + f];
    if (c == 0) s += (float)(n1 - n0) * b2[f];
    unsafeAtomicAdd(&out[g * OD + f], s);
  }
}

extern "C" void kernel_launch(void* const* d_in, const int* in_sizes, int n_in,
                              void* d_out, int out_size, void* d_ws, size_t ws_size,
                              hipStream_t stream) {
  const int*   x_ids = (const int*)d_in[0];
  const int*   ei    = (const int*)d_in[1];
  const int*   batch = (const int*)d_in[2];
  const float* emb   = (const float*)d_in[3];
  const float* W1    = (const float*)d_in[4];
  const float* b1    = (const float*)d_in[5];
  const float* W2    = (const float*)d_in[6];
  const float* b2    = (const float*)d_in[7];
  float* out = (float*)d_out;
  char* ws = (char*)d_ws;

  // workspace layout (bytes)
  int*            ideg   = (int*)           (ws + 0);          // 200 KB
  float*          dinv   = (float*)         (ws + 204800);     // 200 KB
  int*            off    = (int*)           (ws + 409600);     // 200 KB (+4)
  int*            cur    = (int*)           (ws + 614400);     // 200 KB
  int*            bsum   = (int*)           (ws + 819200);
  int*            bso    = (int*)           (ws + 820224);
  int*            gstart = (int*)           (ws + 821248);
  unsigned short* embb   = (unsigned short*)(ws + 1048576);    // 343 KB bf16 emb
  unsigned short* w1f    = (unsigned short*)(ws + 1441792);    // 64 KB frag-linear
  unsigned short* w2f    = (unsigned short*)(ws + 1507328);    // 24 KB frag-linear
  int4*           rec    = (int4*)          (ws + 2097152);    // 13.6 MB packed edge records
  unsigned short* agg1   = (unsigned short*)(ws + 16777216);   // 12.8 MB bf16
  unsigned short* h2b    = (unsigned short*)(ws + 16777216);   // 4.8 MB (reuses agg1 after gemm1)
  unsigned short* y1b    = (unsigned short*)(ws + 33554432);   // 25.6 MB bf16 (end ~59.2 MB)

  fill4_kernel<<<49, 256, 0, stream>>>((float4*)ideg, 0.f, 12500);
  fill4_kernel<<<49, 256, 0, stream>>>((float4*)cur,  0.f, 12500);
  fill4_kernel<<<21, 256, 0, stream>>>((float4*)out,  0.f, 5248);

  cvt_emb_kernel<<<670, 256, 0, stream>>>(emb, embb);
  cvt_w1_kernel <<<16,  256, 0, stream>>>(W1, w1f);
  cvt_w2_kernel <<<6,   256, 0, stream>>>(W2, w2f);

  deg_kernel  <<<3125, 256, 0, stream>>>(ei, ideg);
  dinv_kernel <<<196,  256, 0, stream>>>(ideg, dinv);

  scan1_kernel <<<196, 256, 0, stream>>>(ideg, off, bsum);
  scan2_kernel <<<1,   256, 0, stream>>>(bsum, bso, 196);
  scan3_kernel <<<196, 256, 0, stream>>>(off, bso);
  gstart_kernel<<<196, 256, 0, stream>>>(batch, gstart);

  scatter_kernel<<<3321, 256, 0, stream>>>(ei, x_ids, dinv, off, cur, rec);

  agg1w_kernel<<<12500, 256, 0, stream>>>(off, rec, (const unsigned int*)embb, (unsigned int*)agg1);
  gemm1_mfma  <<<782,   256, 0, stream>>>(agg1, (const bh8*)w1f, b1, y1b);
  gemm2_mfma  <<<782,   256, 0, stream>>>(y1b, (const bh8*)w2f, h2b);
  pool2_kernel<<<2048,  256, 0, stream>>>(gstart, off, rec, h2b, b2, out);
}

// Round 6
// 195.806 us; speedup vs baseline: 9.3682x; 1.1045x over previous
//
#include <hip/hip_runtime.h>

#define N_NODES 50000
#define N_EDGES 800000
#define N_TOT   850000   // edges + self-loops
#define SD 128
#define HD 256
#define OD 41
#define ODP 48
#define NG 512

typedef __attribute__((ext_vector_type(8))) short bh8;   // 8 bf16 = 4 VGPR (MFMA A/B frag)
typedef __attribute__((ext_vector_type(4))) float f4;    // MFMA C/D frag

__device__ inline unsigned short f2bf(float x) {         // RNE float->bf16
  unsigned u = __float_as_uint(x);
  unsigned r = u + 0x7fff + ((u >> 16) & 1);
  return (unsigned short)(r >> 16);
}
__device__ inline float bf2f(unsigned short s) {
  return __uint_as_float(((unsigned)s) << 16);
}
__device__ inline float bflo(unsigned e) { return __uint_as_float(e << 16); }
__device__ inline float bfhi(unsigned e) { return __uint_as_float(e & 0xffff0000u); }

// zero two float4 regions in one launch (a = ideg+cur contiguous, b = out)
__global__ __launch_bounds__(256) void zero2_kernel(float4* __restrict__ a, int na,
                                                    float4* __restrict__ b, int nb) {
  int i = blockIdx.x * 256 + threadIdx.x;
  float4 z = make_float4(0.f, 0.f, 0.f, 0.f);
  if (i < na) { a[i] = z; return; }
  int j = i - na;
  if (j < nb) b[j] = z;
}

__global__ __launch_bounds__(256) void deg_kernel(const int* __restrict__ ei, int* __restrict__ ideg) {
  int e = blockIdx.x * 256 + threadIdx.x;
  if (e < N_EDGES) atomicAdd(&ideg[ei[N_EDGES + e]], 1);
}

// all dtype conversions / frag-linear weight layouts in one launch
__global__ __launch_bounds__(256) void cvt_all_kernel(const float* __restrict__ emb,
    const float* __restrict__ W1, const float* __restrict__ W2,
    unsigned short* __restrict__ embb, unsigned short* __restrict__ w1f,
    unsigned short* __restrict__ w2f) {
  int tid = blockIdx.x * 256 + threadIdx.x;
  if (tid < 1340 * SD) { embb[tid] = f2bf(emb[tid]); return; }
  int u = tid - 1340 * SD;
  if (u < 4096) {           // W1f[frag=ks*16+cf][lane][j]
    int lane = u & 63, frag = u >> 6;
    int ks = frag >> 4, cf = frag & 15;
    int col = cf * 16 + (lane & 15);
    #pragma unroll
    for (int j = 0; j < 8; ++j) {
      int k = ks * 32 + ((lane >> 4) << 3) + j;
      w1f[u * 8 + j] = f2bf(W1[k * HD + col]);
    }
    return;
  }
  u -= 4096;
  if (u < 1536) {           // W2f[frag=ks*3+cf][lane][j], zero-pad cols 41..47
    int lane = u & 63, frag = u >> 6;
    int ks = frag / 3, cf = frag % 3;
    int col = cf * 16 + (lane & 15);
    #pragma unroll
    for (int j = 0; j < 8; ++j) {
      int k = ks * 32 + ((lane >> 4) << 3) + j;
      w2f[u * 8 + j] = (col < OD) ? f2bf(W2[k * OD + col]) : (unsigned short)0;
    }
  }
}

// ---- exclusive scan over cnt[i] = ideg[i]+1 (dinv fused in) ----
__global__ __launch_bounds__(256) void scan1_kernel(const int* __restrict__ ideg,
    float* __restrict__ dinv, int* __restrict__ off, int* __restrict__ bsum) {
  __shared__ int lds[256];
  int t = threadIdx.x;
  int i = blockIdx.x * 256 + t;
  int v = (i < N_NODES) ? ideg[i] + 1 : 0;
  if (i < N_NODES) dinv[i] = rsqrtf((float)v);
  lds[t] = v;
  __syncthreads();
  for (int s = 1; s < 256; s <<= 1) {
    int add = (t >= s) ? lds[t - s] : 0;
    __syncthreads();
    lds[t] += add;
    __syncthreads();
  }
  int inc = lds[t];
  if (i < N_NODES) off[i] = inc - v;
  if (t == 255) bsum[blockIdx.x] = inc;
}

__global__ __launch_bounds__(256) void scan2_kernel(int* __restrict__ bsum, int* __restrict__ bso, int nb) {
  __shared__ int lds[256];
  int t = threadIdx.x;
  int v = (t < nb) ? bsum[t] : 0;
  lds[t] = v;
  __syncthreads();
  for (int s = 1; s < 256; s <<= 1) {
    int add = (t >= s) ? lds[t - s] : 0;
    __syncthreads();
    lds[t] += add;
    __syncthreads();
  }
  if (t < nb) bso[t] = lds[t] - v;
}

// scan finalize + graph-start boundaries in one launch
__global__ __launch_bounds__(256) void scan3g_kernel(int* __restrict__ off,
    const int* __restrict__ bso, const int* __restrict__ batch, int* __restrict__ gstart) {
  int i = blockIdx.x * 256 + threadIdx.x;
  if (i < N_NODES) off[i] += bso[blockIdx.x];
  if (i == 0) off[N_NODES] = N_TOT;
  if (i < N_NODES) {
    if (i == 0) {
      for (int g = 0; g <= batch[0]; ++g) gstart[g] = 0;
    } else {
      int bp = batch[i - 1], bn = batch[i];
      for (int g = bp + 1; g <= bn; ++g) gstart[g] = i;
    }
    if (i == N_NODES - 1) {
      for (int g = batch[i] + 1; g <= NG; ++g) gstart[g] = N_NODES;
    }
  }
}

// bucket edges by dst; one aligned 16B record (xid, norm, src, 0) per edge
__global__ __launch_bounds__(256) void scatter_kernel(const int* __restrict__ ei,
    const int* __restrict__ x_ids, const float* __restrict__ dinv,
    const int* __restrict__ off, int* __restrict__ cur, int4* __restrict__ rec) {
  int e = blockIdx.x * 256 + threadIdx.x;
  if (e >= N_TOT) return;
  int s, d; float nrm;
  if (e < N_EDGES) {
    s = ei[e]; d = ei[N_EDGES + e];
    nrm = dinv[s] * dinv[d];
  } else {
    s = d = e - N_EDGES;
    float di = dinv[s]; nrm = di * di;
  }
  int pos = off[d] + atomicAdd(&cur[d], 1);
  rec[pos] = make_int4(x_ids[s], __float_as_int(nrm), s, 0);
}

// agg1[d][f] = sum over CSR[d] of norm * embb[xid][f]
// wave-per-node: lane owns 2 features (4B packed), 4-edge unroll for ILP.
__global__ __launch_bounds__(256) void agg1w_kernel(const int* __restrict__ off,
    const int4* __restrict__ rec, const unsigned int* __restrict__ embw,
    unsigned int* __restrict__ agg1w) {
  int lane = threadIdx.x & 63;
  int node = __builtin_amdgcn_readfirstlane(blockIdx.x * 4 + (threadIdx.x >> 6));
  int beg = off[node], end = off[node + 1];
  float a0 = 0.f, a1 = 0.f;
  int i = beg;
  for (; i + 4 <= end; i += 4) {
    int4 r0 = rec[i], r1 = rec[i + 1], r2 = rec[i + 2], r3 = rec[i + 3];
    unsigned e0 = embw[r0.x * 64 + lane];
    unsigned e1 = embw[r1.x * 64 + lane];
    unsigned e2 = embw[r2.x * 64 + lane];
    unsigned e3 = embw[r3.x * 64 + lane];
    float n0 = __int_as_float(r0.y), n1 = __int_as_float(r1.y);
    float n2 = __int_as_float(r2.y), n3 = __int_as_float(r3.y);
    a0 += n0 * bflo(e0); a1 += n0 * bfhi(e0);
    a0 += n1 * bflo(e1); a1 += n1 * bfhi(e1);
    a0 += n2 * bflo(e2); a1 += n2 * bfhi(e2);
    a0 += n3 * bflo(e3); a1 += n3 * bfhi(e3);
  }
  for (; i < end; ++i) {
    int4 r = rec[i];
    unsigned e = embw[r.x * 64 + lane];
    float n = __int_as_float(r.y);
    a0 += n * bflo(e); a1 += n * bfhi(e);
  }
  unsigned packed = (unsigned)f2bf(a0) | ((unsigned)f2bf(a1) << 16);
  agg1w[node * 64 + lane] = packed;
}

// y1 = relu(agg1 @ W1 + b1)  via bf16 MFMA.  64x256 tile, 4 waves x (4 rf x 4 cf), K=128.
__global__ __launch_bounds__(256) void gemm1_mfma(const unsigned short* __restrict__ agg1,
    const bh8* __restrict__ w1f, const float* __restrict__ b1, unsigned short* __restrict__ y1b) {
  __shared__ char raw[16384];   // 64 x 128 bf16, XOR-swizzled
  int t = threadIdx.x, lane = t & 63, wave = t >> 6;
  int row0 = blockIdx.x * 64;
  #pragma unroll
  for (int k = 0; k < 4; ++k) {
    int idx = k * 256 + t;            // 16B chunk id, tile = 1024 chunks
    int r = idx >> 4, c = idx & 15;
    int4 v = make_int4(0, 0, 0, 0);
    if (row0 + r < N_NODES)
      v = *(const int4*)((const char*)agg1 + (size_t)(row0 + r) * 256 + c * 16);
    *(int4*)(raw + ((r * 256 + c * 16) ^ ((r & 15) << 4))) = v;
  }
  bh8 bf[4][4];
  #pragma unroll
  for (int cf = 0; cf < 4; ++cf)
    #pragma unroll
    for (int ks = 0; ks < 4; ++ks)
      bf[cf][ks] = w1f[(ks * 16 + wave * 4 + cf) * 64 + lane];
  f4 acc[4][4];
  #pragma unroll
  for (int rf = 0; rf < 4; ++rf)
    #pragma unroll
    for (int cf = 0; cf < 4; ++cf)
      acc[rf][cf] = (f4){0.f, 0.f, 0.f, 0.f};
  __syncthreads();
  #pragma unroll
  for (int ks = 0; ks < 4; ++ks) {
    bh8 a[4];
    #pragma unroll
    for (int rf = 0; rf < 4; ++rf) {
      int r = rf * 16 + (lane & 15);
      int byte = (r * 256 + ks * 64 + ((lane >> 4) << 4)) ^ ((r & 15) << 4);
      a[rf] = *(const bh8*)(raw + byte);
    }
    #pragma unroll
    for (int rf = 0; rf < 4; ++rf)
      #pragma unroll
      for (int cf = 0; cf < 4; ++cf)
        acc[rf][cf] = __builtin_amdgcn_mfma_f32_16x16x32_bf16(a[rf], bf[cf][ks], acc[rf][cf], 0, 0, 0);
  }
  #pragma unroll
  for (int cf = 0; cf < 4; ++cf) {
    int col = wave * 64 + cf * 16 + (lane & 15);
    float bias = b1[col];
    #pragma unroll
    for (int rf = 0; rf < 4; ++rf)
      #pragma unroll
      for (int j = 0; j < 4; ++j) {
        int rg = row0 + rf * 16 + ((lane >> 4) << 2) + j;
        if (rg < N_NODES)
          y1b[(size_t)rg * HD + col] = f2bf(fmaxf(acc[rf][cf][j] + bias, 0.f));
      }
  }
}

// h2b = bf16(y1b @ W2)  via bf16 MFMA.  64-row tile, wave w owns rows w*16.., 3 cf, K=256.
__global__ __launch_bounds__(256) void gemm2_mfma(const unsigned short* __restrict__ y1b,
    const bh8* __restrict__ w2f, unsigned short* __restrict__ h2b) {
  __shared__ char raw[32768];   // 64 x 256 bf16, XOR-swizzled
  int t = threadIdx.x, lane = t & 63, wave = t >> 6;
  int row0 = blockIdx.x * 64;
  #pragma unroll
  for (int k = 0; k < 16; ++k) {
    int idx = k * 256 + t;            // 8B chunk id, tile = 4096 chunks
    int r = idx >> 6, c8 = idx & 63;
    int2 v = make_int2(0, 0);
    if (row0 + r < N_NODES)
      v = *(const int2*)(y1b + (size_t)(row0 + r) * HD + c8 * 4);
    *(int2*)(raw + ((r * 512 + c8 * 8) ^ ((r & 15) << 4))) = v;
  }
  bh8 bf[3][8];
  #pragma unroll
  for (int cf = 0; cf < 3; ++cf)
    #pragma unroll
    for (int ks = 0; ks < 8; ++ks)
      bf[cf][ks] = w2f[(ks * 3 + cf) * 64 + lane];
  f4 acc[3];
  #pragma unroll
  for (int cf = 0; cf < 3; ++cf) acc[cf] = (f4){0.f, 0.f, 0.f, 0.f};
  __syncthreads();
  int r = wave * 16 + (lane & 15);
  #pragma unroll
  for (int ks = 0; ks < 8; ++ks) {
    int byte = (r * 512 + ks * 64 + ((lane >> 4) << 4)) ^ ((r & 15) << 4);
    bh8 a = *(const bh8*)(raw + byte);
    #pragma unroll
    for (int cf = 0; cf < 3; ++cf)
      acc[cf] = __builtin_amdgcn_mfma_f32_16x16x32_bf16(a, bf[cf][ks], acc[cf], 0, 0, 0);
  }
  #pragma unroll
  for (int cf = 0; cf < 3; ++cf) {
    int col = cf * 16 + (lane & 15);
    #pragma unroll
    for (int j = 0; j < 4; ++j) {
      int rg = row0 + wave * 16 + ((lane >> 4) << 2) + j;
      if (rg < N_NODES)
        h2b[(size_t)rg * ODP + col] = f2bf(acc[cf][j]);
    }
  }
}

// fused layer-2 aggregation + graph pooling.
// Wave-per-edge: all 64 lanes share one edge record (broadcast load), lane = feature
// (48-wide coalesced bf16 gather; cols 41..47 are zero), 4-edge unroll for ILP.
__global__ __launch_bounds__(256) void pool2_kernel(const int* __restrict__ gstart,
    const int* __restrict__ off, const int4* __restrict__ rec,
    const unsigned short* __restrict__ h2b, const float* __restrict__ b2,
    float* __restrict__ out) {
  __shared__ float red[4][48];
  int g = blockIdx.x >> 2, c = blockIdx.x & 3;
  int t = threadIdx.x, lane = t & 63, wv = t >> 6;
  int n0 = gstart[g], n1 = gstart[g + 1];
  int e0 = off[n0], e1 = off[n1];
  int len = e1 - e0;
  int q0 = e0 + ((len * c) >> 2);
  int q1 = e0 + ((len * (c + 1)) >> 2);
  int f = (lane < 48) ? lane : 0;
  float acc = 0.f;
  int i = q0 + wv;
  for (; i + 12 < q1; i += 16) {
    int4 r0 = rec[i], r1 = rec[i + 4], r2 = rec[i + 8], r3 = rec[i + 12];
    float h0 = bf2f(h2b[(size_t)r0.z * ODP + f]);
    float h1 = bf2f(h2b[(size_t)r1.z * ODP + f]);
    float h2 = bf2f(h2b[(size_t)r2.z * ODP + f]);
    float h3 = bf2f(h2b[(size_t)r3.z * ODP + f]);
    acc += __int_as_float(r0.y) * h0 + __int_as_float(r1.y) * h1
         + __int_as_float(r2.y) * h2 + __int_as_float(r3.y) * h3;
  }
  for (; i < q1; i += 4) {
    int4 r = rec[i];
    acc += __int_as_float(r.y) * bf2f(h2b[(size_t)r.z * ODP + f]);
  }
  if (lane < 48) red[wv][lane] = acc;
  __syncthreads();
  if (t < 48) {
    float s = red[0][t] + red[1][t] + red[2][t] + red[3][t];
    if (t < OD) {
      if (c == 0) s += (float)(n1 - n0) * b2[t];
      unsafeAtomicAdd(&out[g * OD + t], s);
    }
  }
}

extern "C" void kernel_launch(void* const* d_in, const int* in_sizes, int n_in,
                              void* d_out, int out_size, void* d_ws, size_t ws_size,
                              hipStream_t stream) {
  const int*   x_ids = (const int*)d_in[0];
  const int*   ei    = (const int*)d_in[1];
  const int*   batch = (const int*)d_in[2];
  const float* emb   = (const float*)d_in[3];
  const float* W1    = (const float*)d_in[4];
  const float* b1    = (const float*)d_in[5];
  const float* W2    = (const float*)d_in[6];
  const float* b2    = (const float*)d_in[7];
  float* out = (float*)d_out;
  char* ws = (char*)d_ws;

  // workspace layout (bytes); ideg+cur adjacent for single zero pass
  int*            ideg   = (int*)           (ws + 0);          // 200 KB
  int*            cur    = (int*)           (ws + 204800);     // 200 KB
  float*          dinv   = (float*)         (ws + 409600);     // 200 KB
  int*            off    = (int*)           (ws + 614400);     // 200 KB (+4)
  int*            bsum   = (int*)           (ws + 819200);
  int*            bso    = (int*)           (ws + 820224);
  int*            gstart = (int*)           (ws + 821248);
  unsigned short* embb   = (unsigned short*)(ws + 1048576);    // 343 KB bf16 emb
  unsigned short* w1f    = (unsigned short*)(ws + 1441792);    // 64 KB frag-linear
  unsigned short* w2f    = (unsigned short*)(ws + 1507328);    // 24 KB frag-linear
  int4*           rec    = (int4*)          (ws + 2097152);    // 13.6 MB packed edge records
  unsigned short* agg1   = (unsigned short*)(ws + 16777216);   // 12.8 MB bf16
  unsigned short* h2b    = (unsigned short*)(ws + 16777216);   // 4.8 MB (reuses agg1 after gemm1)
  unsigned short* y1b    = (unsigned short*)(ws + 33554432);   // 25.6 MB bf16 (end ~59.2 MB)

  // zero ideg+cur (contiguous 400KB = 25600 float4) and out (5248 float4)
  zero2_kernel<<<121, 256, 0, stream>>>((float4*)ws, 25600, (float4*)out, 5248);
  cvt_all_kernel<<<692, 256, 0, stream>>>(emb, W1, W2, embb, w1f, w2f);
  deg_kernel  <<<3125, 256, 0, stream>>>(ei, ideg);
  scan1_kernel<<<196, 256, 0, stream>>>(ideg, dinv, off, bsum);
  scan2_kernel<<<1,   256, 0, stream>>>(bsum, bso, 196);
  scan3g_kernel<<<196, 256, 0, stream>>>(off, bso, batch, gstart);

  scatter_kernel<<<3321, 256, 0, stream>>>(ei, x_ids, dinv, off, cur, rec);

  agg1w_kernel<<<12500, 256, 0, stream>>>(off, rec, (const unsigned int*)embb, (unsigned int*)agg1);
  gemm1_mfma  <<<782,   256, 0, stream>>>(agg1, (const bh8*)w1f, b1, y1b);
  gemm2_mfma  <<<782,   256, 0, stream>>>(y1b, (const bh8*)w2f, h2b);
  pool2_kernel<<<2048,  256, 0, stream>>>(gstart, off, rec, h2b, b2, out);
}

// Round 7
// 188.389 us; speedup vs baseline: 9.7370x; 1.0394x over previous
//
#include <hip/hip_runtime.h>

#define N_NODES 50000
#define N_EDGES 800000
#define N_TOT   850000   // edges + self-loops
#define SD 128
#define HD 256
#define OD 41
#define ODP 48
#define NG 512

typedef __attribute__((ext_vector_type(8))) short bh8;   // 8 bf16 = 4 VGPR (MFMA A/B frag)
typedef __attribute__((ext_vector_type(4))) float f4;    // MFMA C/D frag
typedef unsigned long long u64;

__device__ inline unsigned short f2bf(float x) {         // RNE float->bf16
  unsigned u = __float_as_uint(x);
  unsigned r = u + 0x7fff + ((u >> 16) & 1);
  return (unsigned short)(r >> 16);
}
__device__ inline float bf2f(unsigned short s) {
  return __uint_as_float(((unsigned)s) << 16);
}
__device__ inline float bflo(unsigned e) { return __uint_as_float(e << 16); }
__device__ inline float bfhi(unsigned e) { return __uint_as_float(e & 0xffff0000u); }

// 8B edge record: bits 48..63 norm(bf16), 16..26 xid, 0..15 src
__device__ inline u64 pack_rec(int xid, float nrm, int src) {
  unsigned nb = ((unsigned)f2bf(nrm)) << 16;
  return ((u64)nb << 32) | ((u64)(unsigned)xid << 16) | (u64)(unsigned)src;
}
__device__ inline unsigned rec_xid(u64 r)  { return ((unsigned)r) >> 16; }
__device__ inline unsigned rec_src(u64 r)  { return ((unsigned)r) & 0xFFFFu; }
__device__ inline float    rec_nrm(u64 r)  { return __uint_as_float((unsigned)(r >> 32)); }

// zero two float4 regions in one launch (a = ideg+cur contiguous, b = out)
__global__ __launch_bounds__(256) void zero2_kernel(float4* __restrict__ a, int na,
                                                    float4* __restrict__ b, int nb) {
  int i = blockIdx.x * 256 + threadIdx.x;
  float4 z = make_float4(0.f, 0.f, 0.f, 0.f);
  if (i < na) { a[i] = z; return; }
  int j = i - na;
  if (j < nb) b[j] = z;
}

__global__ __launch_bounds__(256) void deg_kernel(const int* __restrict__ ei, int* __restrict__ ideg) {
  int e = blockIdx.x * 256 + threadIdx.x;
  if (e < N_EDGES) atomicAdd(&ideg[ei[N_EDGES + e]], 1);
}

// all dtype conversions / frag-linear weight layouts in one launch
__global__ __launch_bounds__(256) void cvt_all_kernel(const float* __restrict__ emb,
    const float* __restrict__ W1, const float* __restrict__ W2,
    unsigned short* __restrict__ embb, unsigned short* __restrict__ w1f,
    unsigned short* __restrict__ w2f) {
  int tid = blockIdx.x * 256 + threadIdx.x;
  if (tid < 1340 * SD) { embb[tid] = f2bf(emb[tid]); return; }
  int u = tid - 1340 * SD;
  if (u < 4096) {           // W1f[frag=ks*16+cf][lane][j]
    int lane = u & 63, frag = u >> 6;
    int ks = frag >> 4, cf = frag & 15;
    int col = cf * 16 + (lane & 15);
    #pragma unroll
    for (int j = 0; j < 8; ++j) {
      int k = ks * 32 + ((lane >> 4) << 3) + j;
      w1f[u * 8 + j] = f2bf(W1[k * HD + col]);
    }
    return;
  }
  u -= 4096;
  if (u < 1536) {           // W2f[frag=ks*3+cf][lane][j], zero-pad cols 41..47
    int lane = u & 63, frag = u >> 6;
    int ks = frag / 3, cf = frag % 3;
    int col = cf * 16 + (lane & 15);
    #pragma unroll
    for (int j = 0; j < 8; ++j) {
      int k = ks * 32 + ((lane >> 4) << 3) + j;
      w2f[u * 8 + j] = (col < OD) ? f2bf(W2[k * OD + col]) : (unsigned short)0;
    }
  }
}

// ---- exclusive scan over cnt[i] = ideg[i]+1 (dinv fused in) ----
__global__ __launch_bounds__(256) void scan1_kernel(const int* __restrict__ ideg,
    float* __restrict__ dinv, int* __restrict__ off, int* __restrict__ bsum) {
  __shared__ int lds[256];
  int t = threadIdx.x;
  int i = blockIdx.x * 256 + t;
  int v = (i < N_NODES) ? ideg[i] + 1 : 0;
  if (i < N_NODES) dinv[i] = rsqrtf((float)v);
  lds[t] = v;
  __syncthreads();
  for (int s = 1; s < 256; s <<= 1) {
    int add = (t >= s) ? lds[t - s] : 0;
    __syncthreads();
    lds[t] += add;
    __syncthreads();
  }
  int inc = lds[t];
  if (i < N_NODES) off[i] = inc - v;
  if (t == 255) bsum[blockIdx.x] = inc;
}

__global__ __launch_bounds__(256) void scan2_kernel(int* __restrict__ bsum, int* __restrict__ bso, int nb) {
  __shared__ int lds[256];
  int t = threadIdx.x;
  int v = (t < nb) ? bsum[t] : 0;
  lds[t] = v;
  __syncthreads();
  for (int s = 1; s < 256; s <<= 1) {
    int add = (t >= s) ? lds[t - s] : 0;
    __syncthreads();
    lds[t] += add;
    __syncthreads();
  }
  if (t < nb) bso[t] = lds[t] - v;
}

// scan finalize + graph-start boundaries in one launch
__global__ __launch_bounds__(256) void scan3g_kernel(int* __restrict__ off,
    const int* __restrict__ bso, const int* __restrict__ batch, int* __restrict__ gstart) {
  int i = blockIdx.x * 256 + threadIdx.x;
  if (i < N_NODES) off[i] += bso[blockIdx.x];
  if (i == 0) off[N_NODES] = N_TOT;
  if (i < N_NODES) {
    if (i == 0) {
      for (int g = 0; g <= batch[0]; ++g) gstart[g] = 0;
    } else {
      int bp = batch[i - 1], bn = batch[i];
      for (int g = bp + 1; g <= bn; ++g) gstart[g] = i;
    }
    if (i == N_NODES - 1) {
      for (int g = batch[i] + 1; g <= NG; ++g) gstart[g] = N_NODES;
    }
  }
}

// bucket edges by dst; one 8B packed record per edge
__global__ __launch_bounds__(256) void scatter_kernel(const int* __restrict__ ei,
    const int* __restrict__ x_ids, const float* __restrict__ dinv,
    const int* __restrict__ off, int* __restrict__ cur, u64* __restrict__ rec) {
  int e = blockIdx.x * 256 + threadIdx.x;
  if (e >= N_TOT) return;
  int s, d; float nrm;
  if (e < N_EDGES) {
    s = ei[e]; d = ei[N_EDGES + e];
    nrm = dinv[s] * dinv[d];
  } else {
    s = d = e - N_EDGES;
    float di = dinv[s]; nrm = di * di;
  }
  int pos = off[d] + atomicAdd(&cur[d], 1);
  rec[pos] = pack_rec(x_ids[s], nrm, s);
}

// agg1[d][f] = sum over CSR[d] of norm * embb[xid][f]
// wave-per-node: lane owns 2 features (4B packed), 4-edge unroll for ILP.
__global__ __launch_bounds__(256) void agg1w_kernel(const int* __restrict__ off,
    const u64* __restrict__ rec, const unsigned int* __restrict__ embw,
    unsigned int* __restrict__ agg1w) {
  int lane = threadIdx.x & 63;
  int node = __builtin_amdgcn_readfirstlane(blockIdx.x * 4 + (threadIdx.x >> 6));
  int beg = off[node], end = off[node + 1];
  float a0 = 0.f, a1 = 0.f;
  int i = beg;
  for (; i + 4 <= end; i += 4) {
    u64 r0 = rec[i], r1 = rec[i + 1], r2 = rec[i + 2], r3 = rec[i + 3];
    unsigned e0 = embw[rec_xid(r0) * 64 + lane];
    unsigned e1 = embw[rec_xid(r1) * 64 + lane];
    unsigned e2 = embw[rec_xid(r2) * 64 + lane];
    unsigned e3 = embw[rec_xid(r3) * 64 + lane];
    float n0 = rec_nrm(r0), n1 = rec_nrm(r1), n2 = rec_nrm(r2), n3 = rec_nrm(r3);
    a0 += n0 * bflo(e0); a1 += n0 * bfhi(e0);
    a0 += n1 * bflo(e1); a1 += n1 * bfhi(e1);
    a0 += n2 * bflo(e2); a1 += n2 * bfhi(e2);
    a0 += n3 * bflo(e3); a1 += n3 * bfhi(e3);
  }
  for (; i < end; ++i) {
    u64 r = rec[i];
    unsigned e = embw[rec_xid(r) * 64 + lane];
    float n = rec_nrm(r);
    a0 += n * bflo(e); a1 += n * bfhi(e);
  }
  unsigned packed = (unsigned)f2bf(a0) | ((unsigned)f2bf(a1) << 16);
  agg1w[node * 64 + lane] = packed;
}

// y1 = relu(agg1 @ W1 + b1)  via bf16 MFMA.  64x256 tile, 4 waves x (4 rf x 4 cf), K=128.
__global__ __launch_bounds__(256) void gemm1_mfma(const unsigned short* __restrict__ agg1,
    const bh8* __restrict__ w1f, const float* __restrict__ b1, unsigned short* __restrict__ y1b) {
  __shared__ char raw[16384];   // 64 x 128 bf16, XOR-swizzled
  int t = threadIdx.x, lane = t & 63, wave = t >> 6;
  int row0 = blockIdx.x * 64;
  #pragma unroll
  for (int k = 0; k < 4; ++k) {
    int idx = k * 256 + t;            // 16B chunk id, tile = 1024 chunks
    int r = idx >> 4, c = idx & 15;
    int4 v = make_int4(0, 0, 0, 0);
    if (row0 + r < N_NODES)
      v = *(const int4*)((const char*)agg1 + (size_t)(row0 + r) * 256 + c * 16);
    *(int4*)(raw + ((r * 256 + c * 16) ^ ((r & 15) << 4))) = v;
  }
  bh8 bf[4][4];
  #pragma unroll
  for (int cf = 0; cf < 4; ++cf)
    #pragma unroll
    for (int ks = 0; ks < 4; ++ks)
      bf[cf][ks] = w1f[(ks * 16 + wave * 4 + cf) * 64 + lane];
  f4 acc[4][4];
  #pragma unroll
  for (int rf = 0; rf < 4; ++rf)
    #pragma unroll
    for (int cf = 0; cf < 4; ++cf)
      acc[rf][cf] = (f4){0.f, 0.f, 0.f, 0.f};
  __syncthreads();
  #pragma unroll
  for (int ks = 0; ks < 4; ++ks) {
    bh8 a[4];
    #pragma unroll
    for (int rf = 0; rf < 4; ++rf) {
      int r = rf * 16 + (lane & 15);
      int byte = (r * 256 + ks * 64 + ((lane >> 4) << 4)) ^ ((r & 15) << 4);
      a[rf] = *(const bh8*)(raw + byte);
    }
    #pragma unroll
    for (int rf = 0; rf < 4; ++rf)
      #pragma unroll
      for (int cf = 0; cf < 4; ++cf)
        acc[rf][cf] = __builtin_amdgcn_mfma_f32_16x16x32_bf16(a[rf], bf[cf][ks], acc[rf][cf], 0, 0, 0);
  }
  #pragma unroll
  for (int cf = 0; cf < 4; ++cf) {
    int col = wave * 64 + cf * 16 + (lane & 15);
    float bias = b1[col];
    #pragma unroll
    for (int rf = 0; rf < 4; ++rf)
      #pragma unroll
      for (int j = 0; j < 4; ++j) {
        int rg = row0 + rf * 16 + ((lane >> 4) << 2) + j;
        if (rg < N_NODES)
          y1b[(size_t)rg * HD + col] = f2bf(fmaxf(acc[rf][cf][j] + bias, 0.f));
      }
  }
}

// h2b = bf16(y1b @ W2)  via bf16 MFMA.  64-row tile, wave w owns rows w*16.., 3 cf, K=256.
__global__ __launch_bounds__(256) void gemm2_mfma(const unsigned short* __restrict__ y1b,
    const bh8* __restrict__ w2f, unsigned short* __restrict__ h2b) {
  __shared__ char raw[32768];   // 64 x 256 bf16, XOR-swizzled
  int t = threadIdx.x, lane = t & 63, wave = t >> 6;
  int row0 = blockIdx.x * 64;
  #pragma unroll
  for (int k = 0; k < 16; ++k) {
    int idx = k * 256 + t;            // 8B chunk id, tile = 4096 chunks
    int r = idx >> 6, c8 = idx & 63;
    int2 v = make_int2(0, 0);
    if (row0 + r < N_NODES)
      v = *(const int2*)(y1b + (size_t)(row0 + r) * HD + c8 * 4);
    *(int2*)(raw + ((r * 512 + c8 * 8) ^ ((r & 15) << 4))) = v;
  }
  bh8 bf[3][8];
  #pragma unroll
  for (int cf = 0; cf < 3; ++cf)
    #pragma unroll
    for (int ks = 0; ks < 8; ++ks)
      bf[cf][ks] = w2f[(ks * 3 + cf) * 64 + lane];
  f4 acc[3];
  #pragma unroll
  for (int cf = 0; cf < 3; ++cf) acc[cf] = (f4){0.f, 0.f, 0.f, 0.f};
  __syncthreads();
  int r = wave * 16 + (lane & 15);
  #pragma unroll
  for (int ks = 0; ks < 8; ++ks) {
    int byte = (r * 512 + ks * 64 + ((lane >> 4) << 4)) ^ ((r & 15) << 4);
    bh8 a = *(const bh8*)(raw + byte);
    #pragma unroll
    for (int cf = 0; cf < 3; ++cf)
      acc[cf] = __builtin_amdgcn_mfma_f32_16x16x32_bf16(a, bf[cf][ks], acc[cf], 0, 0, 0);
  }
  #pragma unroll
  for (int cf = 0; cf < 3; ++cf) {
    int col = cf * 16 + (lane & 15);
    #pragma unroll
    for (int j = 0; j < 4; ++j) {
      int rg = row0 + wave * 16 + ((lane >> 4) << 2) + j;
      if (rg < N_NODES)
        h2b[(size_t)rg * ODP + col] = f2bf(acc[cf][j]);
    }
  }
}

// fused layer-2 aggregation + graph pooling.
// Wave-per-edge (broadcast rec, lane = feature), 8-deep gather pipeline,
// 8 chunk-blocks per graph for balance.
__global__ __launch_bounds__(256) void pool2_kernel(const int* __restrict__ gstart,
    const int* __restrict__ off, const u64* __restrict__ rec,
    const unsigned short* __restrict__ h2b, const float* __restrict__ b2,
    float* __restrict__ out) {
  __shared__ float red[4][48];
  int g = blockIdx.x >> 3, c = blockIdx.x & 7;
  int t = threadIdx.x, lane = t & 63, wv = t >> 6;
  int n0 = gstart[g], n1 = gstart[g + 1];
  int e0 = off[n0], e1 = off[n1];
  int len = e1 - e0;
  int q0 = e0 + ((len * c) >> 3);
  int q1 = e0 + ((len * (c + 1)) >> 3);
  int f = (lane < 48) ? lane : 0;
  float acc = 0.f;
  int i = q0 + wv;
  for (; i + 28 < q1; i += 32) {     // 8 independent rec->gather chains in flight
    u64 r0 = rec[i],      r1 = rec[i + 4],  r2 = rec[i + 8],  r3 = rec[i + 12];
    u64 r4 = rec[i + 16], r5 = rec[i + 20], r6 = rec[i + 24], r7 = rec[i + 28];
    float h0 = bf2f(h2b[(size_t)rec_src(r0) * ODP + f]);
    float h1 = bf2f(h2b[(size_t)rec_src(r1) * ODP + f]);
    float h2 = bf2f(h2b[(size_t)rec_src(r2) * ODP + f]);
    float h3 = bf2f(h2b[(size_t)rec_src(r3) * ODP + f]);
    float h4 = bf2f(h2b[(size_t)rec_src(r4) * ODP + f]);
    float h5 = bf2f(h2b[(size_t)rec_src(r5) * ODP + f]);
    float h6 = bf2f(h2b[(size_t)rec_src(r6) * ODP + f]);
    float h7 = bf2f(h2b[(size_t)rec_src(r7) * ODP + f]);
    acc += rec_nrm(r0) * h0 + rec_nrm(r1) * h1 + rec_nrm(r2) * h2 + rec_nrm(r3) * h3
         + rec_nrm(r4) * h4 + rec_nrm(r5) * h5 + rec_nrm(r6) * h6 + rec_nrm(r7) * h7;
  }
  for (; i < q1; i += 4) {
    u64 r = rec[i];
    acc += rec_nrm(r) * bf2f(h2b[(size_t)rec_src(r) * ODP + f]);
  }
  if (lane < 48) red[wv][lane] = acc;
  __syncthreads();
  if (t < 48) {
    float s = red[0][t] + red[1][t] + red[2][t] + red[3][t];
    if (t < OD) {
      if (c == 0) s += (float)(n1 - n0) * b2[t];
      unsafeAtomicAdd(&out[g * OD + t], s);
    }
  }
}

extern "C" void kernel_launch(void* const* d_in, const int* in_sizes, int n_in,
                              void* d_out, int out_size, void* d_ws, size_t ws_size,
                              hipStream_t stream) {
  const int*   x_ids = (const int*)d_in[0];
  const int*   ei    = (const int*)d_in[1];
  const int*   batch = (const int*)d_in[2];
  const float* emb   = (const float*)d_in[3];
  const float* W1    = (const float*)d_in[4];
  const float* b1    = (const float*)d_in[5];
  const float* W2    = (const float*)d_in[6];
  const float* b2    = (const float*)d_in[7];
  float* out = (float*)d_out;
  char* ws = (char*)d_ws;

  // workspace layout (bytes); ideg+cur adjacent for single zero pass
  int*            ideg   = (int*)           (ws + 0);          // 200 KB
  int*            cur    = (int*)           (ws + 204800);     // 200 KB
  float*          dinv   = (float*)         (ws + 409600);     // 200 KB
  int*            off    = (int*)           (ws + 614400);     // 200 KB (+4)
  int*            bsum   = (int*)           (ws + 819200);
  int*            bso    = (int*)           (ws + 820224);
  int*            gstart = (int*)           (ws + 821248);
  unsigned short* embb   = (unsigned short*)(ws + 1048576);    // 343 KB bf16 emb
  unsigned short* w1f    = (unsigned short*)(ws + 1441792);    // 64 KB frag-linear
  unsigned short* w2f    = (unsigned short*)(ws + 1507328);    // 24 KB frag-linear
  u64*            rec    = (u64*)           (ws + 2097152);    // 6.8 MB packed edge records
  unsigned short* agg1   = (unsigned short*)(ws + 16777216);   // 12.8 MB bf16
  unsigned short* h2b    = (unsigned short*)(ws + 16777216);   // 4.8 MB (reuses agg1 after gemm1)
  unsigned short* y1b    = (unsigned short*)(ws + 33554432);   // 25.6 MB bf16 (end ~59.2 MB)

  // zero ideg+cur (contiguous 400KB = 25600 float4) and out (5248 float4)
  zero2_kernel<<<121, 256, 0, stream>>>((float4*)ws, 25600, (float4*)out, 5248);
  cvt_all_kernel<<<692, 256, 0, stream>>>(emb, W1, W2, embb, w1f, w2f);
  deg_kernel  <<<3125, 256, 0, stream>>>(ei, ideg);
  scan1_kernel<<<196, 256, 0, stream>>>(ideg, dinv, off, bsum);
  scan2_kernel<<<1,   256, 0, stream>>>(bsum, bso, 196);
  scan3g_kernel<<<196, 256, 0, stream>>>(off, bso, batch, gstart);

  scatter_kernel<<<3321, 256, 0, stream>>>(ei, x_ids, dinv, off, cur, rec);

  agg1w_kernel<<<12500, 256, 0, stream>>>(off, rec, (const unsigned int*)embb, (unsigned int*)agg1);
  gemm1_mfma  <<<782,   256, 0, stream>>>(agg1, (const bh8*)w1f, b1, y1b);
  gemm2_mfma  <<<782,   256, 0, stream>>>(y1b, (const bh8*)w2f, h2b);
  pool2_kernel<<<4096,  256, 0, stream>>>(gstart, off, rec, h2b, b2, out);
}

// Round 8
// 150.092 us; speedup vs baseline: 12.2215x; 1.2552x over previous
//
#include <hip/hip_runtime.h>

#define N_NODES 50000
#define N_EDGES 800000
#define N_TOT   850000   // edges + self-loops
#define SD 128
#define HD 256
#define OD 41
#define ODP 48
#define NG 512
#define NB 128           // dst-range buckets
#define NPB 391          // nodes per bucket (128*391 = 50048 >= 50000)
#define BCAP 8192        // records per bucket capacity (expected ~6640, +19 sigma)

typedef __attribute__((ext_vector_type(8))) short bh8;   // 8 bf16 = 4 VGPR (MFMA A/B frag)
typedef __attribute__((ext_vector_type(4))) float f4;    // MFMA C/D frag
typedef unsigned long long u64;

__device__ inline unsigned short f2bf(float x) {         // RNE float->bf16
  unsigned u = __float_as_uint(x);
  unsigned r = u + 0x7fff + ((u >> 16) & 1);
  return (unsigned short)(r >> 16);
}
__device__ inline float bf2f(unsigned short s) {
  return __uint_as_float(((unsigned)s) << 16);
}
__device__ inline float bflo(unsigned e) { return __uint_as_float(e << 16); }
__device__ inline float bfhi(unsigned e) { return __uint_as_float(e & 0xffff0000u); }

// final 8B edge record: [63:48] norm(bf16), [26:16] xid, [15:0] src
__device__ inline unsigned rec_xid(u64 r)  { return ((unsigned)r) >> 16; }
__device__ inline unsigned rec_src(u64 r)  { return ((unsigned)r) & 0xFFFFu; }
__device__ inline float    rec_nrm(u64 r)  { return __uint_as_float((unsigned)(r >> 32) & 0xFFFF0000u); }

// zero two float4 regions in one launch (a = bucket cursors, b = out)
__global__ __launch_bounds__(256) void zero2_kernel(float4* __restrict__ a, int na,
                                                    float4* __restrict__ b, int nb) {
  int i = blockIdx.x * 256 + threadIdx.x;
  float4 z = make_float4(0.f, 0.f, 0.f, 0.f);
  if (i < na) { a[i] = z; return; }
  int j = i - na;
  if (j < nb) b[j] = z;
}

// all dtype conversions / frag-linear weight layouts in one launch
__global__ __launch_bounds__(256) void cvt_all_kernel(const float* __restrict__ emb,
    const float* __restrict__ W1, const float* __restrict__ W2,
    unsigned short* __restrict__ embb, unsigned short* __restrict__ w1f,
    unsigned short* __restrict__ w2f) {
  int tid = blockIdx.x * 256 + threadIdx.x;
  if (tid < 1340 * SD) { embb[tid] = f2bf(emb[tid]); return; }
  int u = tid - 1340 * SD;
  if (u < 4096) {           // W1f[frag=ks*16+cf][lane][j]
    int lane = u & 63, frag = u >> 6;
    int ks = frag >> 4, cf = frag & 15;
    int col = cf * 16 + (lane & 15);
    #pragma unroll
    for (int j = 0; j < 8; ++j) {
      int k = ks * 32 + ((lane >> 4) << 3) + j;
      w1f[u * 8 + j] = f2bf(W1[k * HD + col]);
    }
    return;
  }
  u -= 4096;
  if (u < 1536) {           // W2f[frag=ks*3+cf][lane][j], zero-pad cols 41..47
    int lane = u & 63, frag = u >> 6;
    int ks = frag / 3, cf = frag % 3;
    int col = cf * 16 + (lane & 15);
    #pragma unroll
    for (int j = 0; j < 8; ++j) {
      int k = ks * 32 + ((lane >> 4) << 3) + j;
      w2f[u * 8 + j] = (col < OD) ? f2bf(W2[k * OD + col]) : (unsigned short)0;
    }
  }
}

// passA: bin edges (+self-loops) into NB dst-range buckets.
// staged record: [47:32] xid, [31:16] dst, [15:0] src
__global__ __launch_bounds__(256) void passA_kernel(const int* __restrict__ ei,
    const int* __restrict__ x_ids, int* __restrict__ curB, u64* __restrict__ stage) {
  __shared__ int lcur[NB];
  __shared__ int base[NB];
  int t = threadIdx.x;
  if (t < NB) lcur[t] = 0;
  __syncthreads();
  u64 pay[16];
  int loc[16];
  int e0 = blockIdx.x * 4096;
  #pragma unroll
  for (int j = 0; j < 16; ++j) {
    int e = e0 + j * 256 + t;
    loc[j] = -1;
    if (e < N_TOT) {
      int s, d;
      if (e < N_EDGES) { s = ei[e]; d = ei[N_EDGES + e]; }
      else             { s = d = e - N_EDGES; }
      int b = d / NPB;
      int lofs = atomicAdd(&lcur[b], 1);
      loc[j] = (b << 13) | lofs;
      pay[j] = ((u64)(unsigned)x_ids[s] << 32) | ((u64)(unsigned)d << 16) | (u64)(unsigned)s;
    }
  }
  __syncthreads();
  if (t < NB) base[t] = atomicAdd(&curB[t], lcur[t]);
  __syncthreads();
  #pragma unroll
  for (int j = 0; j < 16; ++j) {
    if (loc[j] >= 0) {
      int b = loc[j] >> 13, lofs = loc[j] & 8191;
      stage[(size_t)b * BCAP + base[b] + lofs] = pay[j];
    }
  }
}

// count: per bucket, count records per node (includes self-loop) -> vcnt, dinv
__global__ __launch_bounds__(256) void count_kernel(const int* __restrict__ curB,
    const u64* __restrict__ stage, int* __restrict__ vcnt, float* __restrict__ dinv) {
  __shared__ int cl[NPB];
  int t = threadIdx.x, k = blockIdx.x;
  for (int l = t; l < NPB; l += 256) cl[l] = 0;
  __syncthreads();
  int nbk = curB[k];
  const u64* st = stage + (size_t)k * BCAP;
  for (int i = t; i < nbk; i += 256) {
    int d = (int)((st[i] >> 16) & 0xFFFFu);
    atomicAdd(&cl[d - k * NPB], 1);
  }
  __syncthreads();
  int n0 = k * NPB;
  int nn = (n0 + NPB <= N_NODES) ? NPB : (N_NODES - n0);
  for (int l = t; l < nn; l += 256) {
    int v = cl[l];                       // = deg + 1 (self-loop staged)
    vcnt[n0 + l] = v;
    dinv[n0 + l] = rsqrtf((float)v);
  }
}

// ---- exclusive scan over vcnt ----
__global__ __launch_bounds__(256) void scan1_kernel(const int* __restrict__ vcnt,
    int* __restrict__ off, int* __restrict__ bsum) {
  __shared__ int lds[256];
  int t = threadIdx.x;
  int i = blockIdx.x * 256 + t;
  int v = (i < N_NODES) ? vcnt[i] : 0;
  lds[t] = v;
  __syncthreads();
  for (int s = 1; s < 256; s <<= 1) {
    int add = (t >= s) ? lds[t - s] : 0;
    __syncthreads();
    lds[t] += add;
    __syncthreads();
  }
  int inc = lds[t];
  if (i < N_NODES) off[i] = inc - v;
  if (t == 255) bsum[blockIdx.x] = inc;
}

__global__ __launch_bounds__(256) void scan2_kernel(int* __restrict__ bsum, int* __restrict__ bso, int nb) {
  __shared__ int lds[256];
  int t = threadIdx.x;
  int v = (t < nb) ? bsum[t] : 0;
  lds[t] = v;
  __syncthreads();
  for (int s = 1; s < 256; s <<= 1) {
    int add = (t >= s) ? lds[t - s] : 0;
    __syncthreads();
    lds[t] += add;
    __syncthreads();
  }
  if (t < nb) bso[t] = lds[t] - v;
}

// scan finalize + graph-start boundaries in one launch
__global__ __launch_bounds__(256) void scan3g_kernel(int* __restrict__ off,
    const int* __restrict__ bso, const int* __restrict__ batch, int* __restrict__ gstart) {
  int i = blockIdx.x * 256 + threadIdx.x;
  if (i < N_NODES) off[i] += bso[blockIdx.x];
  if (i == 0) off[N_NODES] = N_TOT;
  if (i < N_NODES) {
    if (i == 0) {
      for (int g = 0; g <= batch[0]; ++g) gstart[g] = 0;
    } else {
      int bp = batch[i - 1], bn = batch[i];
      for (int g = bp + 1; g <= bn; ++g) gstart[g] = i;
    }
    if (i == N_NODES - 1) {
      for (int g = batch[i] + 1; g <= NG; ++g) gstart[g] = N_NODES;
    }
  }
}

// passB: scatter bucket staging -> final CSR rec (writes confined to bucket window)
__global__ __launch_bounds__(256) void passB_kernel(const int* __restrict__ curB,
    const u64* __restrict__ stage, const int* __restrict__ off,
    const float* __restrict__ dinv, u64* __restrict__ rec) {
  __shared__ int lcur[NPB];
  __shared__ int loff[NPB];
  int t = threadIdx.x, k = blockIdx.x;
  int n0 = k * NPB;
  int nn = (n0 + NPB <= N_NODES) ? NPB : (N_NODES - n0);
  for (int l = t; l < nn; l += 256) { lcur[l] = 0; loff[l] = off[n0 + l]; }
  __syncthreads();
  int nbk = curB[k];
  const u64* st = stage + (size_t)k * BCAP;
  for (int i = t; i < nbk; i += 256) {
    u64 r = st[i];
    int s   = (int)(r & 0xFFFFu);
    int d   = (int)((r >> 16) & 0xFFFFu);
    int xid = (int)((r >> 32) & 0xFFFFu);
    float nrm = dinv[s] * dinv[d];          // self-loop s==d -> dinv^2, same formula
    int ld = d - n0;
    int p = loff[ld] + atomicAdd(&lcur[ld], 1);
    rec[p] = ((u64)f2bf(nrm) << 48) | ((u64)(unsigned)xid << 16) | (u64)(unsigned)s;
  }
}

// agg1[d][f] = sum over CSR[d] of norm * embb[xid][f]
// wave-per-node: lane owns 2 features (4B packed), 4-edge unroll for ILP.
__global__ __launch_bounds__(256) void agg1w_kernel(const int* __restrict__ off,
    const u64* __restrict__ rec, const unsigned int* __restrict__ embw,
    unsigned int* __restrict__ agg1w) {
  int lane = threadIdx.x & 63;
  int node = __builtin_amdgcn_readfirstlane(blockIdx.x * 4 + (threadIdx.x >> 6));
  int beg = off[node], end = off[node + 1];
  float a0 = 0.f, a1 = 0.f;
  int i = beg;
  for (; i + 4 <= end; i += 4) {
    u64 r0 = rec[i], r1 = rec[i + 1], r2 = rec[i + 2], r3 = rec[i + 3];
    unsigned e0 = embw[rec_xid(r0) * 64 + lane];
    unsigned e1 = embw[rec_xid(r1) * 64 + lane];
    unsigned e2 = embw[rec_xid(r2) * 64 + lane];
    unsigned e3 = embw[rec_xid(r3) * 64 + lane];
    float n0 = rec_nrm(r0), n1 = rec_nrm(r1), n2 = rec_nrm(r2), n3 = rec_nrm(r3);
    a0 += n0 * bflo(e0); a1 += n0 * bfhi(e0);
    a0 += n1 * bflo(e1); a1 += n1 * bfhi(e1);
    a0 += n2 * bflo(e2); a1 += n2 * bfhi(e2);
    a0 += n3 * bflo(e3); a1 += n3 * bfhi(e3);
  }
  for (; i < end; ++i) {
    u64 r = rec[i];
    unsigned e = embw[rec_xid(r) * 64 + lane];
    float n = rec_nrm(r);
    a0 += n * bflo(e); a1 += n * bfhi(e);
  }
  unsigned packed = (unsigned)f2bf(a0) | ((unsigned)f2bf(a1) << 16);
  agg1w[node * 64 + lane] = packed;
}

// y1 = relu(agg1 @ W1 + b1)  via bf16 MFMA.  64x256 tile, 4 waves x (4 rf x 4 cf), K=128.
__global__ __launch_bounds__(256) void gemm1_mfma(const unsigned short* __restrict__ agg1,
    const bh8* __restrict__ w1f, const float* __restrict__ b1, unsigned short* __restrict__ y1b) {
  __shared__ char raw[16384];   // 64 x 128 bf16, XOR-swizzled
  int t = threadIdx.x, lane = t & 63, wave = t >> 6;
  int row0 = blockIdx.x * 64;
  #pragma unroll
  for (int k = 0; k < 4; ++k) {
    int idx = k * 256 + t;            // 16B chunk id, tile = 1024 chunks
    int r = idx >> 4, c = idx & 15;
    int4 v = make_int4(0, 0, 0, 0);
    if (row0 + r < N_NODES)
      v = *(const int4*)((const char*)agg1 + (size_t)(row0 + r) * 256 + c * 16);
    *(int4*)(raw + ((r * 256 + c * 16) ^ ((r & 15) << 4))) = v;
  }
  bh8 bf[4][4];
  #pragma unroll
  for (int cf = 0; cf < 4; ++cf)
    #pragma unroll
    for (int ks = 0; ks < 4; ++ks)
      bf[cf][ks] = w1f[(ks * 16 + wave * 4 + cf) * 64 + lane];
  f4 acc[4][4];
  #pragma unroll
  for (int rf = 0; rf < 4; ++rf)
    #pragma unroll
    for (int cf = 0; cf < 4; ++cf)
      acc[rf][cf] = (f4){0.f, 0.f, 0.f, 0.f};
  __syncthreads();
  #pragma unroll
  for (int ks = 0; ks < 4; ++ks) {
    bh8 a[4];
    #pragma unroll
    for (int rf = 0; rf < 4; ++rf) {
      int r = rf * 16 + (lane & 15);
      int byte = (r * 256 + ks * 64 + ((lane >> 4) << 4)) ^ ((r & 15) << 4);
      a[rf] = *(const bh8*)(raw + byte);
    }
    #pragma unroll
    for (int rf = 0; rf < 4; ++rf)
      #pragma unroll
      for (int cf = 0; cf < 4; ++cf)
        acc[rf][cf] = __builtin_amdgcn_mfma_f32_16x16x32_bf16(a[rf], bf[cf][ks], acc[rf][cf], 0, 0, 0);
  }
  #pragma unroll
  for (int cf = 0; cf < 4; ++cf) {
    int col = wave * 64 + cf * 16 + (lane & 15);
    float bias = b1[col];
    #pragma unroll
    for (int rf = 0; rf < 4; ++rf)
      #pragma unroll
      for (int j = 0; j < 4; ++j) {
        int rg = row0 + rf * 16 + ((lane >> 4) << 2) + j;
        if (rg < N_NODES)
          y1b[(size_t)rg * HD + col] = f2bf(fmaxf(acc[rf][cf][j] + bias, 0.f));
      }
  }
}

// h2b = bf16(y1b @ W2)  via bf16 MFMA.  64-row tile, wave w owns rows w*16.., 3 cf, K=256.
__global__ __launch_bounds__(256) void gemm2_mfma(const unsigned short* __restrict__ y1b,
    const bh8* __restrict__ w2f, unsigned short* __restrict__ h2b) {
  __shared__ char raw[32768];   // 64 x 256 bf16, XOR-swizzled
  int t = threadIdx.x, lane = t & 63, wave = t >> 6;
  int row0 = blockIdx.x * 64;
  #pragma unroll
  for (int k = 0; k < 16; ++k) {
    int idx = k * 256 + t;            // 8B chunk id, tile = 4096 chunks
    int r = idx >> 6, c8 = idx & 63;
    int2 v = make_int2(0, 0);
    if (row0 + r < N_NODES)
      v = *(const int2*)(y1b + (size_t)(row0 + r) * HD + c8 * 4);
    *(int2*)(raw + ((r * 512 + c8 * 8) ^ ((r & 15) << 4))) = v;
  }
  bh8 bf[3][8];
  #pragma unroll
  for (int cf = 0; cf < 3; ++cf)
    #pragma unroll
    for (int ks = 0; ks < 8; ++ks)
      bf[cf][ks] = w2f[(ks * 3 + cf) * 64 + lane];
  f4 acc[3];
  #pragma unroll
  for (int cf = 0; cf < 3; ++cf) acc[cf] = (f4){0.f, 0.f, 0.f, 0.f};
  __syncthreads();
  int r = wave * 16 + (lane & 15);
  #pragma unroll
  for (int ks = 0; ks < 8; ++ks) {
    int byte = (r * 512 + ks * 64 + ((lane >> 4) << 4)) ^ ((r & 15) << 4);
    bh8 a = *(const bh8*)(raw + byte);
    #pragma unroll
    for (int cf = 0; cf < 3; ++cf)
      acc[cf] = __builtin_amdgcn_mfma_f32_16x16x32_bf16(a, bf[cf][ks], acc[cf], 0, 0, 0);
  }
  #pragma unroll
  for (int cf = 0; cf < 3; ++cf) {
    int col = cf * 16 + (lane & 15);
    #pragma unroll
    for (int j = 0; j < 4; ++j) {
      int rg = row0 + wave * 16 + ((lane >> 4) << 2) + j;
      if (rg < N_NODES)
        h2b[(size_t)rg * ODP + col] = f2bf(acc[cf][j]);
    }
  }
}

// fused layer-2 aggregation + graph pooling.
// Wave-per-edge (broadcast rec, lane = feature), 8-deep gather pipeline,
// 8 chunk-blocks per graph for balance.
__global__ __launch_bounds__(256) void pool2_kernel(const int* __restrict__ gstart,
    const int* __restrict__ off, const u64* __restrict__ rec,
    const unsigned short* __restrict__ h2b, const float* __restrict__ b2,
    float* __restrict__ out) {
  __shared__ float red[4][48];
  int g = blockIdx.x >> 3, c = blockIdx.x & 7;
  int t = threadIdx.x, lane = t & 63, wv = t >> 6;
  int n0 = gstart[g], n1 = gstart[g + 1];
  int e0 = off[n0], e1 = off[n1];
  int len = e1 - e0;
  int q0 = e0 + ((len * c) >> 3);
  int q1 = e0 + ((len * (c + 1)) >> 3);
  int f = (lane < 48) ? lane : 0;
  float acc = 0.f;
  int i = q0 + wv;
  for (; i + 28 < q1; i += 32) {     // 8 independent rec->gather chains in flight
    u64 r0 = rec[i],      r1 = rec[i + 4],  r2 = rec[i + 8],  r3 = rec[i + 12];
    u64 r4 = rec[i + 16], r5 = rec[i + 20], r6 = rec[i + 24], r7 = rec[i + 28];
    float h0 = bf2f(h2b[(size_t)rec_src(r0) * ODP + f]);
    float h1 = bf2f(h2b[(size_t)rec_src(r1) * ODP + f]);
    float h2 = bf2f(h2b[(size_t)rec_src(r2) * ODP + f]);
    float h3 = bf2f(h2b[(size_t)rec_src(r3) * ODP + f]);
    float h4 = bf2f(h2b[(size_t)rec_src(r4) * ODP + f]);
    float h5 = bf2f(h2b[(size_t)rec_src(r5) * ODP + f]);
    float h6 = bf2f(h2b[(size_t)rec_src(r6) * ODP + f]);
    float h7 = bf2f(h2b[(size_t)rec_src(r7) * ODP + f]);
    acc += rec_nrm(r0) * h0 + rec_nrm(r1) * h1 + rec_nrm(r2) * h2 + rec_nrm(r3) * h3
         + rec_nrm(r4) * h4 + rec_nrm(r5) * h5 + rec_nrm(r6) * h6 + rec_nrm(r7) * h7;
  }
  for (; i < q1; i += 4) {
    u64 r = rec[i];
    acc += rec_nrm(r) * bf2f(h2b[(size_t)rec_src(r) * ODP + f]);
  }
  if (lane < 48) red[wv][lane] = acc;
  __syncthreads();
  if (t < 48) {
    float s = red[0][t] + red[1][t] + red[2][t] + red[3][t];
    if (t < OD) {
      if (c == 0) s += (float)(n1 - n0) * b2[t];
      unsafeAtomicAdd(&out[g * OD + t], s);
    }
  }
}

extern "C" void kernel_launch(void* const* d_in, const int* in_sizes, int n_in,
                              void* d_out, int out_size, void* d_ws, size_t ws_size,
                              hipStream_t stream) {
  const int*   x_ids = (const int*)d_in[0];
  const int*   ei    = (const int*)d_in[1];
  const int*   batch = (const int*)d_in[2];
  const float* emb   = (const float*)d_in[3];
  const float* W1    = (const float*)d_in[4];
  const float* b1    = (const float*)d_in[5];
  const float* W2    = (const float*)d_in[6];
  const float* b2    = (const float*)d_in[7];
  float* out = (float*)d_out;
  char* ws = (char*)d_ws;

  // workspace layout (bytes)
  int*            vcnt   = (int*)           (ws + 0);          // 200 KB (deg+1 per node)
  int*            curB   = (int*)           (ws + 204800);     // 512 B bucket cursors
  float*          dinv   = (float*)         (ws + 208896);     // 200 KB
  int*            off    = (int*)           (ws + 413696);     // 200 KB (+4)
  int*            bsum   = (int*)           (ws + 618496);
  int*            bso    = (int*)           (ws + 619520);
  int*            gstart = (int*)           (ws + 620544);
  unsigned short* embb   = (unsigned short*)(ws + 1048576);    // 343 KB bf16 emb
  unsigned short* w1f    = (unsigned short*)(ws + 1441792);    // 64 KB frag-linear
  unsigned short* w2f    = (unsigned short*)(ws + 1507328);    // 24 KB frag-linear
  u64*            rec    = (u64*)           (ws + 2097152);    // 6.8 MB final CSR records
  u64*            stage  = (u64*)           (ws + 9437184);    // 8.4 MB bucket staging
  unsigned short* agg1   = (unsigned short*)(ws + 18874368);   // 12.8 MB bf16
  unsigned short* h2b    = (unsigned short*)(ws + 18874368);   // 4.8 MB (reuses agg1)
  unsigned short* y1b    = (unsigned short*)(ws + 35651584);   // 25.6 MB (end ~61.3 MB)

  // zero bucket cursors (32 float4) and out (5248 float4)
  zero2_kernel<<<21, 256, 0, stream>>>((float4*)curB, 32, (float4*)out, 5248);
  cvt_all_kernel<<<692, 256, 0, stream>>>(emb, W1, W2, embb, w1f, w2f);

  passA_kernel<<<208, 256, 0, stream>>>(ei, x_ids, curB, stage);
  count_kernel<<<NB,  256, 0, stream>>>(curB, stage, vcnt, dinv);
  scan1_kernel<<<196, 256, 0, stream>>>(vcnt, off, bsum);
  scan2_kernel<<<1,   256, 0, stream>>>(bsum, bso, 196);
  scan3g_kernel<<<196, 256, 0, stream>>>(off, bso, batch, gstart);
  passB_kernel<<<NB,  256, 0, stream>>>(curB, stage, off, dinv, rec);

  agg1w_kernel<<<12500, 256, 0, stream>>>(off, rec, (const unsigned int*)embb, (unsigned int*)agg1);
  gemm1_mfma  <<<782,   256, 0, stream>>>(agg1, (const bh8*)w1f, b1, y1b);
  gemm2_mfma  <<<782,   256, 0, stream>>>(y1b, (const bh8*)w2f, h2b);
  pool2_kernel<<<4096,  256, 0, stream>>>(gstart, off, rec, h2b, b2, out);
}

// Round 9
// 118.221 us; speedup vs baseline: 15.5162x; 1.2696x over previous
//
#include <hip/hip_runtime.h>

#define N_NODES 50000
#define N_EDGES 800000
#define N_TOT   850000   // edges + self-loops
#define SD 128
#define HD 256
#define OD 41
#define ODP 48
#define NG 512
#define NB 128           // dst-range buckets
#define NPB 391          // nodes per bucket (128*391 = 50048 >= 50000)
#define BCAP 8192        // records per bucket capacity

typedef __attribute__((ext_vector_type(8))) short bh8;   // 8 bf16 = 4 VGPR (MFMA A/B frag)
typedef __attribute__((ext_vector_type(4))) float f4;    // MFMA C/D frag
typedef unsigned long long u64;

__device__ inline unsigned short f2bf(float x) {         // RNE float->bf16
  unsigned u = __float_as_uint(x);
  unsigned r = u + 0x7fff + ((u >> 16) & 1);
  return (unsigned short)(r >> 16);
}
__device__ inline float bf2f(unsigned short s) {
  return __uint_as_float(((unsigned)s) << 16);
}
__device__ inline float bflo(unsigned e) { return __uint_as_float(e << 16); }
__device__ inline float bfhi(unsigned e) { return __uint_as_float(e & 0xffff0000u); }

// final 8B edge record: [63:48] norm(bf16), [26:16] xid, [15:0] src
__device__ inline unsigned rec_xid(u64 r)  { return ((unsigned)r) >> 16; }
__device__ inline unsigned rec_src(u64 r)  { return ((unsigned)r) & 0xFFFFu; }
__device__ inline float    rec_nrm(u64 r)  { return __uint_as_float((unsigned)(r >> 32) & 0xFFFF0000u); }

// zero two float4 regions in one launch (a = bucket cursors, b = out)
__global__ __launch_bounds__(256) void zero2_kernel(float4* __restrict__ a, int na,
                                                    float4* __restrict__ b, int nb) {
  int i = blockIdx.x * 256 + threadIdx.x;
  float4 z = make_float4(0.f, 0.f, 0.f, 0.f);
  if (i < na) { a[i] = z; return; }
  int j = i - na;
  if (j < nb) b[j] = z;
}

// all dtype conversions / frag-linear weight layouts in one launch
__global__ __launch_bounds__(256) void cvt_all_kernel(const float* __restrict__ emb,
    const float* __restrict__ W1, const float* __restrict__ W2,
    unsigned short* __restrict__ embb, unsigned short* __restrict__ w1f,
    unsigned short* __restrict__ w2f) {
  int tid = blockIdx.x * 256 + threadIdx.x;
  if (tid < 1340 * SD) { embb[tid] = f2bf(emb[tid]); return; }
  int u = tid - 1340 * SD;
  if (u < 4096) {           // W1f[frag=ks*16+cf][lane][j]
    int lane = u & 63, frag = u >> 6;
    int ks = frag >> 4, cf = frag & 15;
    int col = cf * 16 + (lane & 15);
    #pragma unroll
    for (int j = 0; j < 8; ++j) {
      int k = ks * 32 + ((lane >> 4) << 3) + j;
      w1f[u * 8 + j] = f2bf(W1[k * HD + col]);
    }
    return;
  }
  u -= 4096;
  if (u < 1536) {           // W2f[frag=ks*3+cf][lane][j], zero-pad cols 41..47
    int lane = u & 63, frag = u >> 6;
    int ks = frag / 3, cf = frag % 3;
    int col = cf * 16 + (lane & 15);
    #pragma unroll
    for (int j = 0; j < 8; ++j) {
      int k = ks * 32 + ((lane >> 4) << 3) + j;
      w2f[u * 8 + j] = (col < OD) ? f2bf(W2[k * OD + col]) : (unsigned short)0;
    }
  }
}

// passA: bin edges (+self-loops) into NB dst-range buckets.
// staged record: [47:32] xid, [31:16] dst, [15:0] src
__global__ __launch_bounds__(256) void passA_kernel(const int* __restrict__ ei,
    const int* __restrict__ x_ids, int* __restrict__ curB, u64* __restrict__ stage) {
  __shared__ int lcur[NB];
  __shared__ int base[NB];
  int t = threadIdx.x;
  if (t < NB) lcur[t] = 0;
  __syncthreads();
  u64 pay[16];
  int loc[16];
  int e0 = blockIdx.x * 4096;
  #pragma unroll
  for (int j = 0; j < 16; ++j) {
    int e = e0 + j * 256 + t;
    loc[j] = -1;
    if (e < N_TOT) {
      int s, d;
      if (e < N_EDGES) { s = ei[e]; d = ei[N_EDGES + e]; }
      else             { s = d = e - N_EDGES; }
      int b = d / NPB;
      int lofs = atomicAdd(&lcur[b], 1);
      loc[j] = (b << 13) | lofs;
      pay[j] = ((u64)(unsigned)x_ids[s] << 32) | ((u64)(unsigned)d << 16) | (u64)(unsigned)s;
    }
  }
  __syncthreads();
  if (t < NB) base[t] = atomicAdd(&curB[t], lcur[t]);
  __syncthreads();
  #pragma unroll
  for (int j = 0; j < 16; ++j) {
    if (loc[j] >= 0) {
      int b = loc[j] >> 13, lofs = loc[j] & 8191;
      stage[(size_t)b * BCAP + base[b] + lofs] = pay[j];
    }
  }
}

// count: per bucket, count records per node (includes self-loop) -> vcnt, dinv
__global__ __launch_bounds__(256) void count_kernel(const int* __restrict__ curB,
    const u64* __restrict__ stage, int* __restrict__ vcnt, float* __restrict__ dinv) {
  __shared__ int cl[NPB];
  int t = threadIdx.x, k = blockIdx.x;
  for (int l = t; l < NPB; l += 256) cl[l] = 0;
  __syncthreads();
  int nbk = curB[k];
  const u64* st = stage + (size_t)k * BCAP;
  for (int i = t; i < nbk; i += 256) {
    int d = (int)((st[i] >> 16) & 0xFFFFu);
    atomicAdd(&cl[d - k * NPB], 1);
  }
  __syncthreads();
  int n0 = k * NPB;
  int nn = (n0 + NPB <= N_NODES) ? NPB : (N_NODES - n0);
  for (int l = t; l < nn; l += 256) {
    int v = cl[l];                       // = deg + 1 (self-loop staged)
    vcnt[n0 + l] = v;
    dinv[n0 + l] = rsqrtf((float)v);
  }
}

// ---- exclusive scan over vcnt ----
__global__ __launch_bounds__(256) void scan1_kernel(const int* __restrict__ vcnt,
    int* __restrict__ off, int* __restrict__ bsum) {
  __shared__ int lds[256];
  int t = threadIdx.x;
  int i = blockIdx.x * 256 + t;
  int v = (i < N_NODES) ? vcnt[i] : 0;
  lds[t] = v;
  __syncthreads();
  for (int s = 1; s < 256; s <<= 1) {
    int add = (t >= s) ? lds[t - s] : 0;
    __syncthreads();
    lds[t] += add;
    __syncthreads();
  }
  int inc = lds[t];
  if (i < N_NODES) off[i] = inc - v;
  if (t == 255) bsum[blockIdx.x] = inc;
}

__global__ __launch_bounds__(256) void scan2_kernel(int* __restrict__ bsum, int* __restrict__ bso, int nb) {
  __shared__ int lds[256];
  int t = threadIdx.x;
  int v = (t < nb) ? bsum[t] : 0;
  lds[t] = v;
  __syncthreads();
  for (int s = 1; s < 256; s <<= 1) {
    int add = (t >= s) ? lds[t - s] : 0;
    __syncthreads();
    lds[t] += add;
    __syncthreads();
  }
  if (t < nb) bso[t] = lds[t] - v;
}

// scan finalize + graph-start boundaries in one launch
__global__ __launch_bounds__(256) void scan3g_kernel(int* __restrict__ off,
    const int* __restrict__ bso, const int* __restrict__ batch, int* __restrict__ gstart) {
  int i = blockIdx.x * 256 + threadIdx.x;
  if (i < N_NODES) off[i] += bso[blockIdx.x];
  if (i == 0) off[N_NODES] = N_TOT;
  if (i < N_NODES) {
    if (i == 0) {
      for (int g = 0; g <= batch[0]; ++g) gstart[g] = 0;
    } else {
      int bp = batch[i - 1], bn = batch[i];
      for (int g = bp + 1; g <= bn; ++g) gstart[g] = i;
    }
    if (i == N_NODES - 1) {
      for (int g = batch[i] + 1; g <= NG; ++g) gstart[g] = N_NODES;
    }
  }
}

// passB: scatter bucket staging -> final CSR rec (writes confined to bucket window)
__global__ __launch_bounds__(256) void passB_kernel(const int* __restrict__ curB,
    const u64* __restrict__ stage, const int* __restrict__ off,
    const float* __restrict__ dinv, u64* __restrict__ rec) {
  __shared__ int lcur[NPB];
  __shared__ int loff[NPB];
  int t = threadIdx.x, k = blockIdx.x;
  int n0 = k * NPB;
  int nn = (n0 + NPB <= N_NODES) ? NPB : (N_NODES - n0);
  for (int l = t; l < nn; l += 256) { lcur[l] = 0; loff[l] = off[n0 + l]; }
  __syncthreads();
  int nbk = curB[k];
  const u64* st = stage + (size_t)k * BCAP;
  for (int i = t; i < nbk; i += 256) {
    u64 r = st[i];
    int s   = (int)(r & 0xFFFFu);
    int d   = (int)((r >> 16) & 0xFFFFu);
    int xid = (int)((r >> 32) & 0xFFFFu);
    float nrm = dinv[s] * dinv[d];          // self-loop s==d -> dinv^2, same formula
    int ld = d - n0;
    int p = loff[ld] + atomicAdd(&lcur[ld], 1);
    rec[p] = ((u64)f2bf(nrm) << 48) | ((u64)(unsigned)xid << 16) | (u64)(unsigned)s;
  }
}

// agg1[d][f] = sum over CSR[d] of norm * embb[xid][f]
// wave-per-node: lane owns 2 features (4B packed), 8-edge unroll for ILP.
__global__ __launch_bounds__(256) void agg1w_kernel(const int* __restrict__ off,
    const u64* __restrict__ rec, const unsigned int* __restrict__ embw,
    unsigned int* __restrict__ agg1w) {
  int lane = threadIdx.x & 63;
  int node = __builtin_amdgcn_readfirstlane(blockIdx.x * 4 + (threadIdx.x >> 6));
  int beg = off[node], end = off[node + 1];
  float a0 = 0.f, a1 = 0.f;
  int i = beg;
  for (; i + 8 <= end; i += 8) {
    u64 r[8];
    unsigned e[8];
    #pragma unroll
    for (int p = 0; p < 8; ++p) r[p] = rec[i + p];
    #pragma unroll
    for (int p = 0; p < 8; ++p) e[p] = embw[rec_xid(r[p]) * 64 + lane];
    #pragma unroll
    for (int p = 0; p < 8; ++p) {
      float n = rec_nrm(r[p]);
      a0 += n * bflo(e[p]); a1 += n * bfhi(e[p]);
    }
  }
  for (; i + 4 <= end; i += 4) {
    u64 r0 = rec[i], r1 = rec[i + 1], r2 = rec[i + 2], r3 = rec[i + 3];
    unsigned e0 = embw[rec_xid(r0) * 64 + lane];
    unsigned e1 = embw[rec_xid(r1) * 64 + lane];
    unsigned e2 = embw[rec_xid(r2) * 64 + lane];
    unsigned e3 = embw[rec_xid(r3) * 64 + lane];
    float n0 = rec_nrm(r0), n1 = rec_nrm(r1), n2 = rec_nrm(r2), n3 = rec_nrm(r3);
    a0 += n0 * bflo(e0); a1 += n0 * bfhi(e0);
    a0 += n1 * bflo(e1); a1 += n1 * bfhi(e1);
    a0 += n2 * bflo(e2); a1 += n2 * bfhi(e2);
    a0 += n3 * bflo(e3); a1 += n3 * bfhi(e3);
  }
  for (; i < end; ++i) {
    u64 r = rec[i];
    unsigned e = embw[rec_xid(r) * 64 + lane];
    float n = rec_nrm(r);
    a0 += n * bflo(e); a1 += n * bfhi(e);
  }
  unsigned packed = (unsigned)f2bf(a0) | ((unsigned)f2bf(a1) << 16);
  agg1w[node * 64 + lane] = packed;
}

// FUSED: h2b = bf16( relu(agg1@W1+b1) @ W2 ).  64-row tile, y1 lives in LDS only.
__global__ __launch_bounds__(256) void gemm12_mfma(const unsigned short* __restrict__ agg1,
    const bh8* __restrict__ w1f, const float* __restrict__ b1,
    const bh8* __restrict__ w2f, unsigned short* __restrict__ h2b) {
  __shared__ char raw[32768];   // phase1: agg1 tile 64x128 bf16 in [0:16K]; phase2: y1 tile 64x256 bf16
  int t = threadIdx.x, lane = t & 63, wave = t >> 6;
  int row0 = blockIdx.x * 64;
  // stage agg1 tile (coalesced global, XOR-swizzled LDS)
  #pragma unroll
  for (int k = 0; k < 4; ++k) {
    int idx = k * 256 + t;            // 16B chunk id, tile = 1024 chunks
    int r = idx >> 4, cc = idx & 15;
    int4 v = make_int4(0, 0, 0, 0);
    if (row0 + r < N_NODES)
      v = *(const int4*)((const char*)agg1 + (size_t)(row0 + r) * 256 + cc * 16);
    *(int4*)(raw + ((r * 256 + cc * 16) ^ ((r & 15) << 4))) = v;
  }
  bh8 bf1[4][4];
  #pragma unroll
  for (int cf = 0; cf < 4; ++cf)
    #pragma unroll
    for (int ks = 0; ks < 4; ++ks)
      bf1[cf][ks] = w1f[(ks * 16 + wave * 4 + cf) * 64 + lane];
  f4 acc[4][4];
  #pragma unroll
  for (int rf = 0; rf < 4; ++rf)
    #pragma unroll
    for (int cf = 0; cf < 4; ++cf)
      acc[rf][cf] = (f4){0.f, 0.f, 0.f, 0.f};
  __syncthreads();
  #pragma unroll
  for (int ks = 0; ks < 4; ++ks) {
    bh8 a[4];
    #pragma unroll
    for (int rf = 0; rf < 4; ++rf) {
      int r = rf * 16 + (lane & 15);
      int byte = (r * 256 + ks * 64 + ((lane >> 4) << 4)) ^ ((r & 15) << 4);
      a[rf] = *(const bh8*)(raw + byte);
    }
    #pragma unroll
    for (int rf = 0; rf < 4; ++rf)
      #pragma unroll
      for (int cf = 0; cf < 4; ++cf)
        acc[rf][cf] = __builtin_amdgcn_mfma_f32_16x16x32_bf16(a[rf], bf1[cf][ks], acc[rf][cf], 0, 0, 0);
  }
  __syncthreads();    // all agg1-tile reads complete before overwrite
  // epilogue1: bias+relu, write bf16 y1 tile into LDS (row stride 512B, same swizzle as reader)
  #pragma unroll
  for (int cf = 0; cf < 4; ++cf) {
    int col = wave * 64 + cf * 16 + (lane & 15);
    float bias = b1[col];
    #pragma unroll
    for (int rf = 0; rf < 4; ++rf)
      #pragma unroll
      for (int j = 0; j < 4; ++j) {
        int r = rf * 16 + ((lane >> 4) << 2) + j;
        unsigned short v = f2bf(fmaxf(acc[rf][cf][j] + bias, 0.f));
        *(unsigned short*)(raw + ((r * 512 + col * 2) ^ ((r & 15) << 4))) = v;
      }
  }
  bh8 bf2[3][8];
  #pragma unroll
  for (int cf = 0; cf < 3; ++cf)
    #pragma unroll
    for (int ks = 0; ks < 8; ++ks)
      bf2[cf][ks] = w2f[(ks * 3 + cf) * 64 + lane];
  f4 acc2[3];
  #pragma unroll
  for (int cf = 0; cf < 3; ++cf) acc2[cf] = (f4){0.f, 0.f, 0.f, 0.f};
  __syncthreads();
  int r2 = wave * 16 + (lane & 15);
  #pragma unroll
  for (int ks = 0; ks < 8; ++ks) {
    int byte = (r2 * 512 + ks * 64 + ((lane >> 4) << 4)) ^ ((r2 & 15) << 4);
    bh8 a = *(const bh8*)(raw + byte);
    #pragma unroll
    for (int cf = 0; cf < 3; ++cf)
      acc2[cf] = __builtin_amdgcn_mfma_f32_16x16x32_bf16(a, bf2[cf][ks], acc2[cf], 0, 0, 0);
  }
  #pragma unroll
  for (int cf = 0; cf < 3; ++cf) {
    int col = cf * 16 + (lane & 15);
    #pragma unroll
    for (int j = 0; j < 4; ++j) {
      int rg = row0 + wave * 16 + ((lane >> 4) << 2) + j;
      if (rg < N_NODES)
        h2b[(size_t)rg * ODP + col] = f2bf(acc2[cf][j]);
    }
  }
}

// fused layer-2 aggregation + graph pooling.
// Paired edges per gather instr: lanes 0-23 = edge A dwords, 24-47 = edge B dwords
// (4B/lane), contiguous per-wave ranges, 8 pairs (16 edges) in flight.
__global__ __launch_bounds__(256) void pool2_kernel(const int* __restrict__ gstart,
    const int* __restrict__ off, const u64* __restrict__ rec,
    const unsigned short* __restrict__ h2b, const float* __restrict__ b2,
    float* __restrict__ out) {
  __shared__ float red[4][2][24][2];
  int g = blockIdx.x >> 3, c = blockIdx.x & 7;
  int t = threadIdx.x, lane = t & 63, wv = t >> 6;
  int n0 = gstart[g], n1 = gstart[g + 1];
  int e0 = off[n0], e1 = off[n1];
  int len = e1 - e0;
  int c0 = e0 + ((len * c) >> 3);
  int c1 = e0 + ((len * (c + 1)) >> 3);
  int clen = c1 - c0;
  int w0 = c0 + ((clen * wv) >> 2);
  int w1 = c0 + ((clen * (wv + 1)) >> 2);
  int half = (lane >= 24 && lane < 48) ? 1 : 0;
  int l24 = (lane < 24) ? lane : ((lane < 48) ? lane - 24 : lane - 48);
  float a0 = 0.f, a1 = 0.f;
  int i = w0;
  for (; i + 16 <= w1; i += 16) {
    u64 ra[8], rb[8];
    #pragma unroll
    for (int p = 0; p < 8; ++p) { ra[p] = rec[i + 2 * p]; rb[p] = rec[i + 2 * p + 1]; }
    #pragma unroll
    for (int p = 0; p < 8; ++p) {
      u64 r = half ? rb[p] : ra[p];
      unsigned hw = *(const unsigned*)(h2b + (size_t)rec_src(r) * ODP + l24 * 2);
      float n = rec_nrm(r);
      a0 += n * bflo(hw); a1 += n * bfhi(hw);
    }
  }
  for (; i < w1; ++i) {                   // tail: lanes 0-23 only accumulate
    u64 r = rec[i];
    unsigned hw = *(const unsigned*)(h2b + (size_t)rec_src(r) * ODP + l24 * 2);
    float n = rec_nrm(r);
    if (lane < 24) { a0 += n * bflo(hw); a1 += n * bfhi(hw); }
  }
  if (lane < 48) { red[wv][half][l24][0] = a0; red[wv][half][l24][1] = a1; }
  __syncthreads();
  if (t < 48) {                           // feature f = t = 2*m + b
    int m = t >> 1, b = t & 1;
    float s = red[0][0][m][b] + red[0][1][m][b] + red[1][0][m][b] + red[1][1][m][b]
            + red[2][0][m][b] + red[2][1][m][b] + red[3][0][m][b] + red[3][1][m][b];
    if (t < OD) {
      if (c == 0) s += (float)(n1 - n0) * b2[t];
      unsafeAtomicAdd(&out[g * OD + t], s);
    }
  }
}

extern "C" void kernel_launch(void* const* d_in, const int* in_sizes, int n_in,
                              void* d_out, int out_size, void* d_ws, size_t ws_size,
                              hipStream_t stream) {
  const int*   x_ids = (const int*)d_in[0];
  const int*   ei    = (const int*)d_in[1];
  const int*   batch = (const int*)d_in[2];
  const float* emb   = (const float*)d_in[3];
  const float* W1    = (const float*)d_in[4];
  const float* b1    = (const float*)d_in[5];
  const float* W2    = (const float*)d_in[6];
  const float* b2    = (const float*)d_in[7];
  float* out = (float*)d_out;
  char* ws = (char*)d_ws;

  // workspace layout (bytes)
  int*            vcnt   = (int*)           (ws + 0);          // 200 KB (deg+1 per node)
  int*            curB   = (int*)           (ws + 204800);     // 512 B bucket cursors
  float*          dinv   = (float*)         (ws + 208896);     // 200 KB
  int*            off    = (int*)           (ws + 413696);     // 200 KB (+4)
  int*            bsum   = (int*)           (ws + 618496);
  int*            bso    = (int*)           (ws + 619520);
  int*            gstart = (int*)           (ws + 620544);
  unsigned short* embb   = (unsigned short*)(ws + 1048576);    // 343 KB bf16 emb
  unsigned short* w1f    = (unsigned short*)(ws + 1441792);    // 64 KB frag-linear
  unsigned short* w2f    = (unsigned short*)(ws + 1507328);    // 24 KB frag-linear
  u64*            rec    = (u64*)           (ws + 2097152);    // 6.8 MB final CSR records
  u64*            stage  = (u64*)           (ws + 9437184);    // 8.4 MB bucket staging
  unsigned short* agg1   = (unsigned short*)(ws + 18874368);   // 12.8 MB bf16
  unsigned short* h2b    = (unsigned short*)(ws + 33554432);   // 4.8 MB (own buffer: fused
                                                               // kernel reads agg1 + writes h2b)

  // zero bucket cursors (32 float4) and out (5248 float4)
  zero2_kernel<<<21, 256, 0, stream>>>((float4*)curB, 32, (float4*)out, 5248);
  cvt_all_kernel<<<692, 256, 0, stream>>>(emb, W1, W2, embb, w1f, w2f);

  passA_kernel<<<208, 256, 0, stream>>>(ei, x_ids, curB, stage);
  count_kernel<<<NB,  256, 0, stream>>>(curB, stage, vcnt, dinv);
  scan1_kernel<<<196, 256, 0, stream>>>(vcnt, off, bsum);
  scan2_kernel<<<1,   256, 0, stream>>>(bsum, bso, 196);
  scan3g_kernel<<<196, 256, 0, stream>>>(off, bso, batch, gstart);
  passB_kernel<<<NB,  256, 0, stream>>>(curB, stage, off, dinv, rec);

  agg1w_kernel<<<12500, 256, 0, stream>>>(off, rec, (const unsigned int*)embb, (unsigned int*)agg1);
  gemm12_mfma <<<782,   256, 0, stream>>>(agg1, (const bh8*)w1f, b1, (const bh8*)w2f, h2b);
  pool2_kernel<<<4096,  256, 0, stream>>>(gstart, off, rec, h2b, b2, out);
}

// Round 10
// 105.975 us; speedup vs baseline: 17.3092x; 1.1156x over previous
//
#include <hip/hip_runtime.h>

#define N_NODES 50000
#define N_EDGES 800000
#define N_TOT   850000   // edges + self-loops
#define SD 128
#define HD 256
#define OD 41
#define ODP 48
#define NG 512
#define NB 128           // dst-range buckets
#define NPB 391          // nodes per bucket (128*391 = 50048 >= 50000)
#define BCAP 8192        // records per bucket capacity

typedef __attribute__((ext_vector_type(8))) short bh8;   // 8 bf16 = 4 VGPR (MFMA A/B frag)
typedef __attribute__((ext_vector_type(4))) float f4;    // MFMA C/D frag
typedef unsigned long long u64;

__device__ inline unsigned short f2bf(float x) {         // RNE float->bf16
  unsigned u = __float_as_uint(x);
  unsigned r = u + 0x7fff + ((u >> 16) & 1);
  return (unsigned short)(r >> 16);
}
__device__ inline float bf2f(unsigned short s) {
  return __uint_as_float(((unsigned)s) << 16);
}
__device__ inline float bflo(unsigned e) { return __uint_as_float(e << 16); }
__device__ inline float bfhi(unsigned e) { return __uint_as_float(e & 0xffff0000u); }
__device__ inline unsigned pk2(float lo, float hi) {
  return (unsigned)f2bf(lo) | ((unsigned)f2bf(hi) << 16);
}

// final 8B edge record: [63:48] norm(bf16), [26:16] xid, [15:0] src
__device__ inline unsigned rec_xid(u64 r)  { return ((unsigned)r) >> 16; }
__device__ inline unsigned rec_src(u64 r)  { return ((unsigned)r) & 0xFFFFu; }
__device__ inline float    rec_nrm(u64 r)  { return __uint_as_float((unsigned)(r >> 32) & 0xFFFF0000u); }

// init: emb/W1/W2 conversions + zero curB + zero out, one launch
__global__ __launch_bounds__(256) void init_kernel(const float* __restrict__ emb,
    const float* __restrict__ W1, const float* __restrict__ W2,
    unsigned short* __restrict__ embb, unsigned short* __restrict__ w1f,
    unsigned short* __restrict__ w2f, float4* __restrict__ curB4, float4* __restrict__ out4) {
  int tid = blockIdx.x * 256 + threadIdx.x;
  if (tid < 1340 * SD) { embb[tid] = f2bf(emb[tid]); return; }
  int u = tid - 1340 * SD;
  if (u < 4096) {           // W1f[frag=ks*16+cf][lane][j]
    int lane = u & 63, frag = u >> 6;
    int ks = frag >> 4, cf = frag & 15;
    int col = cf * 16 + (lane & 15);
    #pragma unroll
    for (int j = 0; j < 8; ++j) {
      int k = ks * 32 + ((lane >> 4) << 3) + j;
      w1f[u * 8 + j] = f2bf(W1[k * HD + col]);
    }
    return;
  }
  u -= 4096;
  if (u < 1536) {           // W2f[frag=ks*3+cf][lane][j], zero-pad cols 41..47
    int lane = u & 63, frag = u >> 6;
    int ks = frag / 3, cf = frag % 3;
    int col = cf * 16 + (lane & 15);
    #pragma unroll
    for (int j = 0; j < 8; ++j) {
      int k = ks * 32 + ((lane >> 4) << 3) + j;
      w2f[u * 8 + j] = (col < OD) ? f2bf(W2[k * OD + col]) : (unsigned short)0;
    }
    return;
  }
  u -= 1536;
  float4 z = make_float4(0.f, 0.f, 0.f, 0.f);
  if (u < 32) { curB4[u] = z; return; }
  u -= 32;
  if (u < 5248) out4[u] = z;
}

// passA: bin edges (+self-loops) into NB dst-range buckets.
// staged record: [47:32] xid, [31:16] dst, [15:0] src
__global__ __launch_bounds__(256) void passA_kernel(const int* __restrict__ ei,
    const int* __restrict__ x_ids, int* __restrict__ curB, u64* __restrict__ stage) {
  __shared__ int lcur[NB];
  __shared__ int base[NB];
  int t = threadIdx.x;
  if (t < NB) lcur[t] = 0;
  __syncthreads();
  u64 pay[16];
  int loc[16];
  int e0 = blockIdx.x * 4096;
  #pragma unroll
  for (int j = 0; j < 16; ++j) {
    int e = e0 + j * 256 + t;
    loc[j] = -1;
    if (e < N_TOT) {
      int s, d;
      if (e < N_EDGES) { s = ei[e]; d = ei[N_EDGES + e]; }
      else             { s = d = e - N_EDGES; }
      int b = d / NPB;
      int lofs = atomicAdd(&lcur[b], 1);
      loc[j] = (b << 13) | lofs;
      pay[j] = ((u64)(unsigned)x_ids[s] << 32) | ((u64)(unsigned)d << 16) | (u64)(unsigned)s;
    }
  }
  __syncthreads();
  if (t < NB) base[t] = atomicAdd(&curB[t], lcur[t]);
  __syncthreads();
  #pragma unroll
  for (int j = 0; j < 16; ++j) {
    if (loc[j] >= 0) {
      int b = loc[j] >> 13, lofs = loc[j] & 8191;
      stage[(size_t)b * BCAP + base[b] + lofs] = pay[j];
    }
  }
}

// count: per bucket, count records per node (includes self-loop) -> vcnt, dinv
__global__ __launch_bounds__(256) void count_kernel(const int* __restrict__ curB,
    const u64* __restrict__ stage, int* __restrict__ vcnt, float* __restrict__ dinv) {
  __shared__ int cl[NPB];
  int t = threadIdx.x, k = blockIdx.x;
  for (int l = t; l < NPB; l += 256) cl[l] = 0;
  __syncthreads();
  int nbk = curB[k];
  const u64* st = stage + (size_t)k * BCAP;
  for (int i = t; i < nbk; i += 256) {
    int d = (int)((st[i] >> 16) & 0xFFFFu);
    atomicAdd(&cl[d - k * NPB], 1);
  }
  __syncthreads();
  int n0 = k * NPB;
  int nn = (n0 + NPB <= N_NODES) ? NPB : (N_NODES - n0);
  for (int l = t; l < nn; l += 256) {
    int v = cl[l];                       // = deg + 1 (self-loop staged)
    vcnt[n0 + l] = v;
    dinv[n0 + l] = rsqrtf((float)v);
  }
}

// ---- exclusive scan over vcnt ----
__global__ __launch_bounds__(256) void scan1_kernel(const int* __restrict__ vcnt,
    int* __restrict__ off, int* __restrict__ bsum) {
  __shared__ int lds[256];
  int t = threadIdx.x;
  int i = blockIdx.x * 256 + t;
  int v = (i < N_NODES) ? vcnt[i] : 0;
  lds[t] = v;
  __syncthreads();
  for (int s = 1; s < 256; s <<= 1) {
    int add = (t >= s) ? lds[t - s] : 0;
    __syncthreads();
    lds[t] += add;
    __syncthreads();
  }
  int inc = lds[t];
  if (i < N_NODES) off[i] = inc - v;
  if (t == 255) bsum[blockIdx.x] = inc;
}

// scan finalize (block-sum scan redone per block) + graph-start boundaries
__global__ __launch_bounds__(256) void scan3g_kernel(int* __restrict__ off,
    const int* __restrict__ bsum, const int* __restrict__ batch, int* __restrict__ gstart) {
  __shared__ int lds[256];
  int t = threadIdx.x;
  int v = (t < 196) ? bsum[t] : 0;
  lds[t] = v;
  __syncthreads();
  for (int s = 1; s < 256; s <<= 1) {
    int add = (t >= s) ? lds[t - s] : 0;
    __syncthreads();
    lds[t] += add;
    __syncthreads();
  }
  int b = blockIdx.x;
  int bso = (b == 0) ? 0 : lds[b - 1];
  int i = b * 256 + t;
  if (i < N_NODES) off[i] += bso;
  if (i == 0) off[N_NODES] = N_TOT;
  if (i < N_NODES) {
    if (i == 0) {
      for (int g = 0; g <= batch[0]; ++g) gstart[g] = 0;
    } else {
      int bp = batch[i - 1], bn = batch[i];
      for (int g = bp + 1; g <= bn; ++g) gstart[g] = i;
    }
    if (i == N_NODES - 1) {
      for (int g = batch[i] + 1; g <= NG; ++g) gstart[g] = N_NODES;
    }
  }
}

// passB: scatter bucket staging -> final CSR rec (writes confined to bucket window)
__global__ __launch_bounds__(256) void passB_kernel(const int* __restrict__ curB,
    const u64* __restrict__ stage, const int* __restrict__ off,
    const float* __restrict__ dinv, u64* __restrict__ rec) {
  __shared__ int lcur[NPB];
  __shared__ int loff[NPB];
  int t = threadIdx.x, k = blockIdx.x;
  int n0 = k * NPB;
  int nn = (n0 + NPB <= N_NODES) ? NPB : (N_NODES - n0);
  for (int l = t; l < nn; l += 256) { lcur[l] = 0; loff[l] = off[n0 + l]; }
  __syncthreads();
  int nbk = curB[k];
  const u64* st = stage + (size_t)k * BCAP;
  for (int i = t; i < nbk; i += 256) {
    u64 r = st[i];
    int s   = (int)(r & 0xFFFFu);
    int d   = (int)((r >> 16) & 0xFFFFu);
    int xid = (int)((r >> 32) & 0xFFFFu);
    float nrm = dinv[s] * dinv[d];          // self-loop s==d -> dinv^2, same formula
    int ld = d - n0;
    int p = loff[ld] + atomicAdd(&lcur[ld], 1);
    rec[p] = ((u64)f2bf(nrm) << 48) | ((u64)(unsigned)xid << 16) | (u64)(unsigned)s;
  }
}

// agg1[d][f] = sum over CSR[d] of norm * embb[xid][f]
// wave-per-node, 4 edges per gather instruction: lane = (eslot 0..3, fgrp 0..15),
// dwordx4 (8 feats) per lane; cross-eslot shuffle reduce at node end.
__global__ __launch_bounds__(256) void agg1w_kernel(const int* __restrict__ off,
    const u64* __restrict__ rec, const uint4* __restrict__ emb16,
    uint4* __restrict__ agg16) {
  int lane = threadIdx.x & 63;
  int node = __builtin_amdgcn_readfirstlane(blockIdx.x * 4 + (threadIdx.x >> 6));
  int beg = off[node], end = off[node + 1];
  int eslot = lane >> 4, fgrp = lane & 15;
  float a[8];
  #pragma unroll
  for (int j = 0; j < 8; ++j) a[j] = 0.f;
  int i = beg;
  for (; i + 8 <= end; i += 8) {          // 2 groups of 4 edges in flight
    u64 rA = rec[i + eslot];
    u64 rB = rec[i + 4 + eslot];
    uint4 vA = emb16[rec_xid(rA) * 16 + fgrp];
    uint4 vB = emb16[rec_xid(rB) * 16 + fgrp];
    float nA = rec_nrm(rA), nB = rec_nrm(rB);
    a[0] += nA * bflo(vA.x); a[1] += nA * bfhi(vA.x);
    a[2] += nA * bflo(vA.y); a[3] += nA * bfhi(vA.y);
    a[4] += nA * bflo(vA.z); a[5] += nA * bfhi(vA.z);
    a[6] += nA * bflo(vA.w); a[7] += nA * bfhi(vA.w);
    a[0] += nB * bflo(vB.x); a[1] += nB * bfhi(vB.x);
    a[2] += nB * bflo(vB.y); a[3] += nB * bfhi(vB.y);
    a[4] += nB * bflo(vB.z); a[5] += nB * bfhi(vB.z);
    a[6] += nB * bflo(vB.w); a[7] += nB * bfhi(vB.w);
  }
  for (; i < end; i += 4) {               // tail groups (masked)
    int idx = i + eslot;
    bool val = idx < end;
    u64 r = rec[val ? idx : (end - 1)];
    uint4 v = emb16[rec_xid(r) * 16 + fgrp];
    float n = val ? rec_nrm(r) : 0.f;
    a[0] += n * bflo(v.x); a[1] += n * bfhi(v.x);
    a[2] += n * bflo(v.y); a[3] += n * bfhi(v.y);
    a[4] += n * bflo(v.z); a[5] += n * bfhi(v.z);
    a[6] += n * bflo(v.w); a[7] += n * bfhi(v.w);
  }
  #pragma unroll
  for (int j = 0; j < 8; ++j) {           // reduce across eslots (lanes ^16, ^32)
    a[j] += __shfl_xor(a[j], 16);
    a[j] += __shfl_xor(a[j], 32);
  }
  if (lane < 16) {
    uint4 o;
    o.x = pk2(a[0], a[1]); o.y = pk2(a[2], a[3]);
    o.z = pk2(a[4], a[5]); o.w = pk2(a[6], a[7]);
    agg16[(size_t)node * 16 + fgrp] = o;
  }
}

// FUSED: h2b = bf16( relu(agg1@W1+b1) @ W2 ).  64-row tile, y1 lives in LDS only.
__global__ __launch_bounds__(256) void gemm12_mfma(const unsigned short* __restrict__ agg1,
    const bh8* __restrict__ w1f, const float* __restrict__ b1,
    const bh8* __restrict__ w2f, unsigned short* __restrict__ h2b) {
  __shared__ char raw[32768];   // phase1: agg1 tile 64x128 bf16 in [0:16K]; phase2: y1 tile 64x256 bf16
  int t = threadIdx.x, lane = t & 63, wave = t >> 6;
  int row0 = blockIdx.x * 64;
  #pragma unroll
  for (int k = 0; k < 4; ++k) {
    int idx = k * 256 + t;            // 16B chunk id, tile = 1024 chunks
    int r = idx >> 4, cc = idx & 15;
    int4 v = make_int4(0, 0, 0, 0);
    if (row0 + r < N_NODES)
      v = *(const int4*)((const char*)agg1 + (size_t)(row0 + r) * 256 + cc * 16);
    *(int4*)(raw + ((r * 256 + cc * 16) ^ ((r & 15) << 4))) = v;
  }
  bh8 bf1[4][4];
  #pragma unroll
  for (int cf = 0; cf < 4; ++cf)
    #pragma unroll
    for (int ks = 0; ks < 4; ++ks)
      bf1[cf][ks] = w1f[(ks * 16 + wave * 4 + cf) * 64 + lane];
  f4 acc[4][4];
  #pragma unroll
  for (int rf = 0; rf < 4; ++rf)
    #pragma unroll
    for (int cf = 0; cf < 4; ++cf)
      acc[rf][cf] = (f4){0.f, 0.f, 0.f, 0.f};
  __syncthreads();
  #pragma unroll
  for (int ks = 0; ks < 4; ++ks) {
    bh8 a[4];
    #pragma unroll
    for (int rf = 0; rf < 4; ++rf) {
      int r = rf * 16 + (lane & 15);
      int byte = (r * 256 + ks * 64 + ((lane >> 4) << 4)) ^ ((r & 15) << 4);
      a[rf] = *(const bh8*)(raw + byte);
    }
    #pragma unroll
    for (int rf = 0; rf < 4; ++rf)
      #pragma unroll
      for (int cf = 0; cf < 4; ++cf)
        acc[rf][cf] = __builtin_amdgcn_mfma_f32_16x16x32_bf16(a[rf], bf1[cf][ks], acc[rf][cf], 0, 0, 0);
  }
  __syncthreads();    // all agg1-tile reads complete before overwrite
  #pragma unroll
  for (int cf = 0; cf < 4; ++cf) {
    int col = wave * 64 + cf * 16 + (lane & 15);
    float bias = b1[col];
    #pragma unroll
    for (int rf = 0; rf < 4; ++rf)
      #pragma unroll
      for (int j = 0; j < 4; ++j) {
        int r = rf * 16 + ((lane >> 4) << 2) + j;
        unsigned short v = f2bf(fmaxf(acc[rf][cf][j] + bias, 0.f));
        *(unsigned short*)(raw + ((r * 512 + col * 2) ^ ((r & 15) << 4))) = v;
      }
  }
  bh8 bf2[3][8];
  #pragma unroll
  for (int cf = 0; cf < 3; ++cf)
    #pragma unroll
    for (int ks = 0; ks < 8; ++ks)
      bf2[cf][ks] = w2f[(ks * 3 + cf) * 64 + lane];
  f4 acc2[3];
  #pragma unroll
  for (int cf = 0; cf < 3; ++cf) acc2[cf] = (f4){0.f, 0.f, 0.f, 0.f};
  __syncthreads();
  int r2 = wave * 16 + (lane & 15);
  #pragma unroll
  for (int ks = 0; ks < 8; ++ks) {
    int byte = (r2 * 512 + ks * 64 + ((lane >> 4) << 4)) ^ ((r2 & 15) << 4);
    bh8 a = *(const bh8*)(raw + byte);
    #pragma unroll
    for (int cf = 0; cf < 3; ++cf)
      acc2[cf] = __builtin_amdgcn_mfma_f32_16x16x32_bf16(a, bf2[cf][ks], acc2[cf], 0, 0, 0);
  }
  #pragma unroll
  for (int cf = 0; cf < 3; ++cf) {
    int col = cf * 16 + (lane & 15);
    #pragma unroll
    for (int j = 0; j < 4; ++j) {
      int rg = row0 + wave * 16 + ((lane >> 4) << 2) + j;
      if (rg < N_NODES)
        h2b[(size_t)rg * ODP + col] = f2bf(acc2[cf][j]);
    }
  }
}

// fused layer-2 aggregation + graph pooling.
// 10 edges per gather instruction: lane = (eslot 0..9, fgrp 0..5), dwordx4/lane,
// per-lane rec load rec[i+eslot]; LDS reduce across waves+eslots.
__global__ __launch_bounds__(256) void pool2_kernel(const int* __restrict__ gstart,
    const int* __restrict__ off, const u64* __restrict__ rec,
    const unsigned short* __restrict__ h2b, const float* __restrict__ b2,
    float* __restrict__ out) {
  __shared__ float red[4][60][8];   // 30.7 KB
  int g = blockIdx.x >> 3, c = blockIdx.x & 7;
  int t = threadIdx.x, lane = t & 63, wv = t >> 6;
  int n0 = gstart[g], n1 = gstart[g + 1];
  int e0 = off[n0], e1 = off[n1];
  int len = e1 - e0;
  int c0 = e0 + ((len * c) >> 3);
  int c1 = e0 + ((len * (c + 1)) >> 3);
  int clen = c1 - c0;
  int w0 = c0 + ((clen * wv) >> 2);
  int w1 = c0 + ((clen * (wv + 1)) >> 2);
  bool live = lane < 60;
  int eslot = live ? lane / 6 : 0;      // 0..9
  int fgrp  = live ? lane - (lane / 6) * 6 : 0;   // 0..5 (feats fgrp*8..+7)
  float a[8];
  #pragma unroll
  for (int j = 0; j < 8; ++j) a[j] = 0.f;
  int i = w0;
  for (; i + 10 <= w1; i += 10) {
    u64 r = rec[i + eslot];
    uint4 v = *(const uint4*)(h2b + (size_t)rec_src(r) * ODP + fgrp * 8);
    float n = live ? rec_nrm(r) : 0.f;
    a[0] += n * bflo(v.x); a[1] += n * bfhi(v.x);
    a[2] += n * bflo(v.y); a[3] += n * bfhi(v.y);
    a[4] += n * bflo(v.z); a[5] += n * bfhi(v.z);
    a[6] += n * bflo(v.w); a[7] += n * bfhi(v.w);
  }
  if (i < w1) {                         // one masked tail group
    int idx = i + eslot;
    bool val = live && idx < w1;
    u64 r = rec[val ? idx : w0];
    uint4 v = *(const uint4*)(h2b + (size_t)rec_src(r) * ODP + fgrp * 8);
    float n = val ? rec_nrm(r) : 0.f;
    a[0] += n * bflo(v.x); a[1] += n * bfhi(v.x);
    a[2] += n * bflo(v.y); a[3] += n * bfhi(v.y);
    a[4] += n * bflo(v.z); a[5] += n * bfhi(v.z);
    a[6] += n * bflo(v.w); a[7] += n * bfhi(v.w);
  }
  if (live) {
    #pragma unroll
    for (int j = 0; j < 8; ++j) red[wv][lane][j] = a[j];
  }
  __syncthreads();
  if (t < 48) {                         // feature f = t
    int fg = t >> 3, j = t & 7;
    float s = 0.f;
    #pragma unroll
    for (int w = 0; w < 4; ++w)
      #pragma unroll
      for (int e = 0; e < 10; ++e)
        s += red[w][e * 6 + fg][j];
    if (t < OD) {
      if (c == 0) s += (float)(n1 - n0) * b2[t];
      unsafeAtomicAdd(&out[g * OD + t], s);
    }
  }
}

extern "C" void kernel_launch(void* const* d_in, const int* in_sizes, int n_in,
                              void* d_out, int out_size, void* d_ws, size_t ws_size,
                              hipStream_t stream) {
  const int*   x_ids = (const int*)d_in[0];
  const int*   ei    = (const int*)d_in[1];
  const int*   batch = (const int*)d_in[2];
  const float* emb   = (const float*)d_in[3];
  const float* W1    = (const float*)d_in[4];
  const float* b1    = (const float*)d_in[5];
  const float* W2    = (const float*)d_in[6];
  const float* b2    = (const float*)d_in[7];
  float* out = (float*)d_out;
  char* ws = (char*)d_ws;

  // workspace layout (bytes)
  int*            vcnt   = (int*)           (ws + 0);          // 200 KB (deg+1 per node)
  int*            curB   = (int*)           (ws + 204800);     // 512 B bucket cursors
  float*          dinv   = (float*)         (ws + 208896);     // 200 KB
  int*            off    = (int*)           (ws + 413696);     // 200 KB (+4)
  int*            bsum   = (int*)           (ws + 618496);
  int*            gstart = (int*)           (ws + 620544);
  unsigned short* embb   = (unsigned short*)(ws + 1048576);    // 343 KB bf16 emb
  unsigned short* w1f    = (unsigned short*)(ws + 1441792);    // 64 KB frag-linear
  unsigned short* w2f    = (unsigned short*)(ws + 1507328);    // 24 KB frag-linear
  u64*            rec    = (u64*)           (ws + 2097152);    // 6.8 MB final CSR records
  u64*            stage  = (u64*)           (ws + 9437184);    // 8.4 MB bucket staging
  unsigned short* agg1   = (unsigned short*)(ws + 18874368);   // 12.8 MB bf16
  unsigned short* h2b    = (unsigned short*)(ws + 33554432);   // 4.8 MB

  init_kernel <<<713, 256, 0, stream>>>(emb, W1, W2, embb, w1f, w2f,
                                        (float4*)curB, (float4*)out);
  passA_kernel<<<208, 256, 0, stream>>>(ei, x_ids, curB, stage);
  count_kernel<<<NB,  256, 0, stream>>>(curB, stage, vcnt, dinv);
  scan1_kernel<<<196, 256, 0, stream>>>(vcnt, off, bsum);
  scan3g_kernel<<<196, 256, 0, stream>>>(off, bsum, batch, gstart);
  passB_kernel<<<NB,  256, 0, stream>>>(curB, stage, off, dinv, rec);

  agg1w_kernel<<<12500, 256, 0, stream>>>(off, rec, (const uint4*)embb, (uint4*)agg1);
  gemm12_mfma <<<782,   256, 0, stream>>>(agg1, (const bh8*)w1f, b1, (const bh8*)w2f, h2b);
  pool2_kernel<<<4096,  256, 0, stream>>>(gstart, off, rec, h2b, b2, out);
}

// Round 11
// 101.807 us; speedup vs baseline: 18.0178x; 1.0409x over previous
//
#include <hip/hip_runtime.h>

#define N_NODES 50000
#define N_EDGES 800000
#define N_TOT   850000   // edges + self-loops
#define SD 128
#define HD 256
#define OD 41
#define ODP 48
#define NG 512
#define NB 128           // dst-range buckets
#define NPB 391          // nodes per bucket (128*391 = 50048 >= 50000)
#define BCAP 8192        // records per bucket capacity

typedef __attribute__((ext_vector_type(8))) short bh8;   // 8 bf16 = 4 VGPR (MFMA A/B frag)
typedef __attribute__((ext_vector_type(4))) float f4;    // MFMA C/D frag
typedef unsigned long long u64;

__device__ inline unsigned short f2bf(float x) {         // RNE float->bf16
  unsigned u = __float_as_uint(x);
  unsigned r = u + 0x7fff + ((u >> 16) & 1);
  return (unsigned short)(r >> 16);
}
__device__ inline float bf2f(unsigned short s) {
  return __uint_as_float(((unsigned)s) << 16);
}
__device__ inline float bflo(unsigned e) { return __uint_as_float(e << 16); }
__device__ inline float bfhi(unsigned e) { return __uint_as_float(e & 0xffff0000u); }
__device__ inline unsigned pk2(float lo, float hi) {
  return (unsigned)f2bf(lo) | ((unsigned)f2bf(hi) << 16);
}

// final 8B edge record: [63:48] norm(bf16), [26:16] xid, [15:0] src
__device__ inline unsigned rec_xid(u64 r)  { return ((unsigned)r) >> 16; }
__device__ inline unsigned rec_src(u64 r)  { return ((unsigned)r) & 0xFFFFu; }
__device__ inline float    rec_nrm(u64 r)  { return __uint_as_float((unsigned)(r >> 32) & 0xFFFF0000u); }

// init: emb/W1/W2 conversions + zero curB + zero out + gstart, one launch
__global__ __launch_bounds__(256) void init_kernel(const float* __restrict__ emb,
    const float* __restrict__ W1, const float* __restrict__ W2,
    const int* __restrict__ batch,
    unsigned short* __restrict__ embb, unsigned short* __restrict__ w1f,
    unsigned short* __restrict__ w2f, float4* __restrict__ curB4,
    float4* __restrict__ out4, int* __restrict__ gstart) {
  int tid = blockIdx.x * 256 + threadIdx.x;
  if (tid < 1340 * SD) { embb[tid] = f2bf(emb[tid]); return; }
  int u = tid - 1340 * SD;
  if (u < 4096) {           // W1f[frag=ks*16+cf][lane][j]
    int lane = u & 63, frag = u >> 6;
    int ks = frag >> 4, cf = frag & 15;
    int col = cf * 16 + (lane & 15);
    #pragma unroll
    for (int j = 0; j < 8; ++j) {
      int k = ks * 32 + ((lane >> 4) << 3) + j;
      w1f[u * 8 + j] = f2bf(W1[k * HD + col]);
    }
    return;
  }
  u -= 4096;
  if (u < 1536) {           // W2f[frag=ks*3+cf][lane][j], zero-pad cols 41..47
    int lane = u & 63, frag = u >> 6;
    int ks = frag / 3, cf = frag % 3;
    int col = cf * 16 + (lane & 15);
    #pragma unroll
    for (int j = 0; j < 8; ++j) {
      int k = ks * 32 + ((lane >> 4) << 3) + j;
      w2f[u * 8 + j] = (col < OD) ? f2bf(W2[k * OD + col]) : (unsigned short)0;
    }
    return;
  }
  u -= 1536;
  float4 z = make_float4(0.f, 0.f, 0.f, 0.f);
  if (u < 32) { curB4[u] = z; return; }
  u -= 32;
  if (u < 5248) { out4[u] = z; return; }
  u -= 5248;
  if (u < N_NODES) {        // graph-start boundaries from sorted batch
    int i = u;
    if (i == 0) {
      for (int g = 0; g <= batch[0]; ++g) gstart[g] = 0;
    } else {
      int bp = batch[i - 1], bn = batch[i];
      for (int g = bp + 1; g <= bn; ++g) gstart[g] = i;
    }
    if (i == N_NODES - 1) {
      for (int g = batch[i] + 1; g <= NG; ++g) gstart[g] = N_NODES;
    }
  }
}

// passA: bin edges (+self-loops) into NB dst-range buckets.
// staged record: [47:32] xid, [31:16] dst, [15:0] src
__global__ __launch_bounds__(256) void passA_kernel(const int* __restrict__ ei,
    const int* __restrict__ x_ids, int* __restrict__ curB, u64* __restrict__ stage) {
  __shared__ int lcur[NB];
  __shared__ int base[NB];
  int t = threadIdx.x;
  if (t < NB) lcur[t] = 0;
  __syncthreads();
  u64 pay[16];
  int loc[16];
  int e0 = blockIdx.x * 4096;
  #pragma unroll
  for (int j = 0; j < 16; ++j) {
    int e = e0 + j * 256 + t;
    loc[j] = -1;
    if (e < N_TOT) {
      int s, d;
      if (e < N_EDGES) { s = ei[e]; d = ei[N_EDGES + e]; }
      else             { s = d = e - N_EDGES; }
      int b = d / NPB;
      int lofs = atomicAdd(&lcur[b], 1);
      loc[j] = (b << 13) | lofs;
      pay[j] = ((u64)(unsigned)x_ids[s] << 32) | ((u64)(unsigned)d << 16) | (u64)(unsigned)s;
    }
  }
  __syncthreads();
  if (t < NB) base[t] = atomicAdd(&curB[t], lcur[t]);
  __syncthreads();
  #pragma unroll
  for (int j = 0; j < 16; ++j) {
    if (loc[j] >= 0) {
      int b = loc[j] >> 13, lofs = loc[j] & 8191;
      stage[(size_t)b * BCAP + base[b] + lofs] = pay[j];
    }
  }
}

// countscan: per bucket, count per-node records, local exclusive scan,
// bucket base from in-block scan of curB -> off, dinv.  Replaces count+scan1+scan3g.
__global__ __launch_bounds__(256) void countscan_kernel(const int* __restrict__ curB,
    const u64* __restrict__ stage, int* __restrict__ off, float* __restrict__ dinv) {
  __shared__ int cl[NPB];
  __shared__ int sc[512];
  __shared__ int bs[NB];
  int t = threadIdx.x, k = blockIdx.x;
  for (int l = t; l < NPB; l += 256) cl[l] = 0;
  if (t < NB) bs[t] = curB[t];
  __syncthreads();
  // bucket-base scan over 128 totals (inclusive)
  for (int s = 1; s < NB; s <<= 1) {
    int a = (t < NB && t >= s) ? bs[t - s] : 0;
    __syncthreads();
    if (t < NB) bs[t] += a;
    __syncthreads();
  }
  int base = (k == 0) ? 0 : bs[k - 1];
  // count
  int nbk = curB[k];
  const u64* st = stage + (size_t)k * BCAP;
  for (int i = t; i < nbk; i += 256) {
    int d = (int)((st[i] >> 16) & 0xFFFFu);
    atomicAdd(&cl[d - k * NPB], 1);
  }
  __syncthreads();
  // local inclusive scan of 391 counts (padded to 512, 2 elems/thread)
  sc[t]       = (t < NPB)       ? cl[t]       : 0;
  sc[t + 256] = (t + 256 < NPB) ? cl[t + 256] : 0;
  __syncthreads();
  for (int s = 1; s < 512; s <<= 1) {
    int a0 = (t >= s) ? sc[t - s] : 0;
    int a1 = (t + 256 >= s) ? sc[t + 256 - s] : 0;
    __syncthreads();
    sc[t] += a0; sc[t + 256] += a1;
    __syncthreads();
  }
  int n0 = k * NPB;
  int nn = (n0 + NPB <= N_NODES) ? NPB : (N_NODES - n0);
  for (int l = t; l < nn; l += 256) {
    int v = cl[l];                        // = deg + 1 (self-loop staged)
    off[n0 + l] = base + sc[l] - v;       // global exclusive offset
    dinv[n0 + l] = rsqrtf((float)v);
  }
  if (k == 0 && t == 0) off[N_NODES] = N_TOT;
}

// passB: scatter bucket staging -> final CSR rec (writes confined to bucket window)
__global__ __launch_bounds__(256) void passB_kernel(const int* __restrict__ curB,
    const u64* __restrict__ stage, const int* __restrict__ off,
    const float* __restrict__ dinv, u64* __restrict__ rec) {
  __shared__ int lcur[NPB];
  __shared__ int loff[NPB];
  int t = threadIdx.x, k = blockIdx.x;
  int n0 = k * NPB;
  int nn = (n0 + NPB <= N_NODES) ? NPB : (N_NODES - n0);
  for (int l = t; l < nn; l += 256) { lcur[l] = 0; loff[l] = off[n0 + l]; }
  __syncthreads();
  int nbk = curB[k];
  const u64* st = stage + (size_t)k * BCAP;
  for (int i = t; i < nbk; i += 256) {
    u64 r = st[i];
    int s   = (int)(r & 0xFFFFu);
    int d   = (int)((r >> 16) & 0xFFFFu);
    int xid = (int)((r >> 32) & 0xFFFFu);
    float nrm = dinv[s] * dinv[d];          // self-loop s==d -> dinv^2, same formula
    int ld = d - n0;
    int p = loff[ld] + atomicAdd(&lcur[ld], 1);
    rec[p] = ((u64)f2bf(nrm) << 48) | ((u64)(unsigned)xid << 16) | (u64)(unsigned)s;
  }
}

// agg1[d][f] = sum over CSR[d] of norm * embb[xid][f]
// wave-per-node, 4 edges per gather instruction: lane = (eslot 0..3, fgrp 0..15),
// dwordx4 (8 feats) per lane; 16-edge leading loop for MLP depth;
// cross-eslot shuffle reduce at node end.
__global__ __launch_bounds__(256) void agg1w_kernel(const int* __restrict__ off,
    const u64* __restrict__ rec, const uint4* __restrict__ emb16,
    uint4* __restrict__ agg16) {
  int lane = threadIdx.x & 63;
  int node = __builtin_amdgcn_readfirstlane(blockIdx.x * 4 + (threadIdx.x >> 6));
  int beg = off[node], end = off[node + 1];
  int eslot = lane >> 4, fgrp = lane & 15;
  float a[8];
  #pragma unroll
  for (int j = 0; j < 8; ++j) a[j] = 0.f;
  int i = beg;
  for (; i + 16 <= end; i += 16) {        // 4 groups of 4 edges in flight
    u64 r0 = rec[i + eslot];
    u64 r1 = rec[i + 4 + eslot];
    u64 r2 = rec[i + 8 + eslot];
    u64 r3 = rec[i + 12 + eslot];
    uint4 v0 = emb16[rec_xid(r0) * 16 + fgrp];
    uint4 v1 = emb16[rec_xid(r1) * 16 + fgrp];
    uint4 v2 = emb16[rec_xid(r2) * 16 + fgrp];
    uint4 v3 = emb16[rec_xid(r3) * 16 + fgrp];
    float n0 = rec_nrm(r0), n1 = rec_nrm(r1), n2 = rec_nrm(r2), n3 = rec_nrm(r3);
    a[0] += n0 * bflo(v0.x); a[1] += n0 * bfhi(v0.x);
    a[2] += n0 * bflo(v0.y); a[3] += n0 * bfhi(v0.y);
    a[4] += n0 * bflo(v0.z); a[5] += n0 * bfhi(v0.z);
    a[6] += n0 * bflo(v0.w); a[7] += n0 * bfhi(v0.w);
    a[0] += n1 * bflo(v1.x); a[1] += n1 * bfhi(v1.x);
    a[2] += n1 * bflo(v1.y); a[3] += n1 * bfhi(v1.y);
    a[4] += n1 * bflo(v1.z); a[5] += n1 * bfhi(v1.z);
    a[6] += n1 * bflo(v1.w); a[7] += n1 * bfhi(v1.w);
    a[0] += n2 * bflo(v2.x); a[1] += n2 * bfhi(v2.x);
    a[2] += n2 * bflo(v2.y); a[3] += n2 * bfhi(v2.y);
    a[4] += n2 * bflo(v2.z); a[5] += n2 * bfhi(v2.z);
    a[6] += n2 * bflo(v2.w); a[7] += n2 * bfhi(v2.w);
    a[0] += n3 * bflo(v3.x); a[1] += n3 * bfhi(v3.x);
    a[2] += n3 * bflo(v3.y); a[3] += n3 * bfhi(v3.y);
    a[4] += n3 * bflo(v3.z); a[5] += n3 * bfhi(v3.z);
    a[6] += n3 * bflo(v3.w); a[7] += n3 * bfhi(v3.w);
  }
  for (; i + 8 <= end; i += 8) {          // 2 groups of 4 edges
    u64 rA = rec[i + eslot];
    u64 rB = rec[i + 4 + eslot];
    uint4 vA = emb16[rec_xid(rA) * 16 + fgrp];
    uint4 vB = emb16[rec_xid(rB) * 16 + fgrp];
    float nA = rec_nrm(rA), nB = rec_nrm(rB);
    a[0] += nA * bflo(vA.x); a[1] += nA * bfhi(vA.x);
    a[2] += nA * bflo(vA.y); a[3] += nA * bfhi(vA.y);
    a[4] += nA * bflo(vA.z); a[5] += nA * bfhi(vA.z);
    a[6] += nA * bflo(vA.w); a[7] += nA * bfhi(vA.w);
    a[0] += nB * bflo(vB.x); a[1] += nB * bfhi(vB.x);
    a[2] += nB * bflo(vB.y); a[3] += nB * bfhi(vB.y);
    a[4] += nB * bflo(vB.z); a[5] += nB * bfhi(vB.z);
    a[6] += nB * bflo(vB.w); a[7] += nB * bfhi(vB.w);
  }
  for (; i < end; i += 4) {               // tail groups (masked)
    int idx = i + eslot;
    bool val = idx < end;
    u64 r = rec[val ? idx : (end - 1)];
    uint4 v = emb16[rec_xid(r) * 16 + fgrp];
    float n = val ? rec_nrm(r) : 0.f;
    a[0] += n * bflo(v.x); a[1] += n * bfhi(v.x);
    a[2] += n * bflo(v.y); a[3] += n * bfhi(v.y);
    a[4] += n * bflo(v.z); a[5] += n * bfhi(v.z);
    a[6] += n * bflo(v.w); a[7] += n * bfhi(v.w);
  }
  #pragma unroll
  for (int j = 0; j < 8; ++j) {           // reduce across eslots (lanes ^16, ^32)
    a[j] += __shfl_xor(a[j], 16);
    a[j] += __shfl_xor(a[j], 32);
  }
  if (lane < 16) {
    uint4 o;
    o.x = pk2(a[0], a[1]); o.y = pk2(a[2], a[3]);
    o.z = pk2(a[4], a[5]); o.w = pk2(a[6], a[7]);
    agg16[(size_t)node * 16 + fgrp] = o;
  }
}

// FUSED: h2b = bf16( relu(agg1@W1+b1) @ W2 ).  64-row tile, y1 lives in LDS only.
__global__ __launch_bounds__(256) void gemm12_mfma(const unsigned short* __restrict__ agg1,
    const bh8* __restrict__ w1f, const float* __restrict__ b1,
    const bh8* __restrict__ w2f, unsigned short* __restrict__ h2b) {
  __shared__ char raw[32768];   // phase1: agg1 tile 64x128 bf16 in [0:16K]; phase2: y1 tile 64x256 bf16
  int t = threadIdx.x, lane = t & 63, wave = t >> 6;
  int row0 = blockIdx.x * 64;
  #pragma unroll
  for (int k = 0; k < 4; ++k) {
    int idx = k * 256 + t;            // 16B chunk id, tile = 1024 chunks
    int r = idx >> 4, cc = idx & 15;
    int4 v = make_int4(0, 0, 0, 0);
    if (row0 + r < N_NODES)
      v = *(const int4*)((const char*)agg1 + (size_t)(row0 + r) * 256 + cc * 16);
    *(int4*)(raw + ((r * 256 + cc * 16) ^ ((r & 15) << 4))) = v;
  }
  bh8 bf1[4][4];
  #pragma unroll
  for (int cf = 0; cf < 4; ++cf)
    #pragma unroll
    for (int ks = 0; ks < 4; ++ks)
      bf1[cf][ks] = w1f[(ks * 16 + wave * 4 + cf) * 64 + lane];
  f4 acc[4][4];
  #pragma unroll
  for (int rf = 0; rf < 4; ++rf)
    #pragma unroll
    for (int cf = 0; cf < 4; ++cf)
      acc[rf][cf] = (f4){0.f, 0.f, 0.f, 0.f};
  __syncthreads();
  #pragma unroll
  for (int ks = 0; ks < 4; ++ks) {
    bh8 a[4];
    #pragma unroll
    for (int rf = 0; rf < 4; ++rf) {
      int r = rf * 16 + (lane & 15);
      int byte = (r * 256 + ks * 64 + ((lane >> 4) << 4)) ^ ((r & 15) << 4);
      a[rf] = *(const bh8*)(raw + byte);
    }
    #pragma unroll
    for (int rf = 0; rf < 4; ++rf)
      #pragma unroll
      for (int cf = 0; cf < 4; ++cf)
        acc[rf][cf] = __builtin_amdgcn_mfma_f32_16x16x32_bf16(a[rf], bf1[cf][ks], acc[rf][cf], 0, 0, 0);
  }
  __syncthreads();    // all agg1-tile reads complete before overwrite
  #pragma unroll
  for (int cf = 0; cf < 4; ++cf) {
    int col = wave * 64 + cf * 16 + (lane & 15);
    float bias = b1[col];
    #pragma unroll
    for (int rf = 0; rf < 4; ++rf)
      #pragma unroll
      for (int j = 0; j < 4; ++j) {
        int r = rf * 16 + ((lane >> 4) << 2) + j;
        unsigned short v = f2bf(fmaxf(acc[rf][cf][j] + bias, 0.f));
        *(unsigned short*)(raw + ((r * 512 + col * 2) ^ ((r & 15) << 4))) = v;
      }
  }
  bh8 bf2[3][8];
  #pragma unroll
  for (int cf = 0; cf < 3; ++cf)
    #pragma unroll
    for (int ks = 0; ks < 8; ++ks)
      bf2[cf][ks] = w2f[(ks * 3 + cf) * 64 + lane];
  f4 acc2[3];
  #pragma unroll
  for (int cf = 0; cf < 3; ++cf) acc2[cf] = (f4){0.f, 0.f, 0.f, 0.f};
  __syncthreads();
  int r2 = wave * 16 + (lane & 15);
  #pragma unroll
  for (int ks = 0; ks < 8; ++ks) {
    int byte = (r2 * 512 + ks * 64 + ((lane >> 4) << 4)) ^ ((r2 & 15) << 4);
    bh8 a = *(const bh8*)(raw + byte);
    #pragma unroll
    for (int cf = 0; cf < 3; ++cf)
      acc2[cf] = __builtin_amdgcn_mfma_f32_16x16x32_bf16(a, bf2[cf][ks], acc2[cf], 0, 0, 0);
  }
  #pragma unroll
  for (int cf = 0; cf < 3; ++cf) {
    int col = cf * 16 + (lane & 15);
    #pragma unroll
    for (int j = 0; j < 4; ++j) {
      int rg = row0 + wave * 16 + ((lane >> 4) << 2) + j;
      if (rg < N_NODES)
        h2b[(size_t)rg * ODP + col] = f2bf(acc2[cf][j]);
    }
  }
}

// fused layer-2 aggregation + graph pooling.
// 10 edges per gather instruction: lane = (eslot 0..9, fgrp 0..5), dwordx4/lane;
// 20-edge (2-group) leading loop; LDS reduce across waves+eslots.
__global__ __launch_bounds__(256) void pool2_kernel(const int* __restrict__ gstart,
    const int* __restrict__ off, const u64* __restrict__ rec,
    const unsigned short* __restrict__ h2b, const float* __restrict__ b2,
    float* __restrict__ out) {
  __shared__ float red[4][60][8];   // 30.7 KB
  int g = blockIdx.x >> 3, c = blockIdx.x & 7;
  int t = threadIdx.x, lane = t & 63, wv = t >> 6;
  int n0 = gstart[g], n1 = gstart[g + 1];
  int e0 = off[n0], e1 = off[n1];
  int len = e1 - e0;
  int c0 = e0 + ((len * c) >> 3);
  int c1 = e0 + ((len * (c + 1)) >> 3);
  int clen = c1 - c0;
  int w0 = c0 + ((clen * wv) >> 2);
  int w1 = c0 + ((clen * (wv + 1)) >> 2);
  bool live = lane < 60;
  int eslot = live ? lane / 6 : 0;      // 0..9
  int fgrp  = live ? lane - (lane / 6) * 6 : 0;   // 0..5 (feats fgrp*8..+7)
  float a[8];
  #pragma unroll
  for (int j = 0; j < 8; ++j) a[j] = 0.f;
  int i = w0;
  for (; i + 20 <= w1; i += 20) {       // 20 edges (2 groups) in flight
    u64 rA = rec[i + eslot];
    u64 rB = rec[i + 10 + eslot];
    uint4 vA = *(const uint4*)(h2b + (size_t)rec_src(rA) * ODP + fgrp * 8);
    uint4 vB = *(const uint4*)(h2b + (size_t)rec_src(rB) * ODP + fgrp * 8);
    float nA = live ? rec_nrm(rA) : 0.f;
    float nB = live ? rec_nrm(rB) : 0.f;
    a[0] += nA * bflo(vA.x); a[1] += nA * bfhi(vA.x);
    a[2] += nA * bflo(vA.y); a[3] += nA * bfhi(vA.y);
    a[4] += nA * bflo(vA.z); a[5] += nA * bfhi(vA.z);
    a[6] += nA * bflo(vA.w); a[7] += nA * bfhi(vA.w);
    a[0] += nB * bflo(vB.x); a[1] += nB * bfhi(vB.x);
    a[2] += nB * bflo(vB.y); a[3] += nB * bfhi(vB.y);
    a[4] += nB * bflo(vB.z); a[5] += nB * bfhi(vB.z);
    a[6] += nB * bflo(vB.w); a[7] += nB * bfhi(vB.w);
  }
  for (; i + 10 <= w1; i += 10) {
    u64 r = rec[i + eslot];
    uint4 v = *(const uint4*)(h2b + (size_t)rec_src(r) * ODP + fgrp * 8);
    float n = live ? rec_nrm(r) : 0.f;
    a[0] += n * bflo(v.x); a[1] += n * bfhi(v.x);
    a[2] += n * bflo(v.y); a[3] += n * bfhi(v.y);
    a[4] += n * bflo(v.z); a[5] += n * bfhi(v.z);
    a[6] += n * bflo(v.w); a[7] += n * bfhi(v.w);
  }
  if (i < w1) {                         // one masked tail group
    int idx = i + eslot;
    bool val = live && idx < w1;
    u64 r = rec[val ? idx : w0];
    uint4 v = *(const uint4*)(h2b + (size_t)rec_src(r) * ODP + fgrp * 8);
    float n = val ? rec_nrm(r) : 0.f;
    a[0] += n * bflo(v.x); a[1] += n * bfhi(v.x);
    a[2] += n * bflo(v.y); a[3] += n * bfhi(v.y);
    a[4] += n * bflo(v.z); a[5] += n * bfhi(v.z);
    a[6] += n * bflo(v.w); a[7] += n * bfhi(v.w);
  }
  if (live) {
    #pragma unroll
    for (int j = 0; j < 8; ++j) red[wv][lane][j] = a[j];
  }
  __syncthreads();
  if (t < 48) {                         // feature f = t
    int fg = t >> 3, j = t & 7;
    float s = 0.f;
    #pragma unroll
    for (int w = 0; w < 4; ++w)
      #pragma unroll
      for (int e = 0; e < 10; ++e)
        s += red[w][e * 6 + fg][j];
    if (t < OD) {
      if (c == 0) s += (float)(n1 - n0) * b2[t];
      unsafeAtomicAdd(&out[g * OD + t], s);
    }
  }
}

extern "C" void kernel_launch(void* const* d_in, const int* in_sizes, int n_in,
                              void* d_out, int out_size, void* d_ws, size_t ws_size,
                              hipStream_t stream) {
  const int*   x_ids = (const int*)d_in[0];
  const int*   ei    = (const int*)d_in[1];
  const int*   batch = (const int*)d_in[2];
  const float* emb   = (const float*)d_in[3];
  const float* W1    = (const float*)d_in[4];
  const float* b1    = (const float*)d_in[5];
  const float* W2    = (const float*)d_in[6];
  const float* b2    = (const float*)d_in[7];
  float* out = (float*)d_out;
  char* ws = (char*)d_ws;

  // workspace layout (bytes)
  int*            curB   = (int*)           (ws + 0);          // 512 B bucket cursors
  float*          dinv   = (float*)         (ws + 4096);       // 200 KB
  int*            off    = (int*)           (ws + 208896);     // 200 KB (+4)
  int*            gstart = (int*)           (ws + 413696);     // 2052 B
  unsigned short* embb   = (unsigned short*)(ws + 1048576);    // 343 KB bf16 emb
  unsigned short* w1f    = (unsigned short*)(ws + 1441792);    // 64 KB frag-linear
  unsigned short* w2f    = (unsigned short*)(ws + 1507328);    // 24 KB frag-linear
  u64*            rec    = (u64*)           (ws + 2097152);    // 6.8 MB final CSR records
  u64*            stage  = (u64*)           (ws + 9437184);    // 8.4 MB bucket staging
  unsigned short* agg1   = (unsigned short*)(ws + 18874368);   // 12.8 MB bf16
  unsigned short* h2b    = (unsigned short*)(ws + 33554432);   // 4.8 MB

  init_kernel <<<908, 256, 0, stream>>>(emb, W1, W2, batch, embb, w1f, w2f,
                                        (float4*)curB, (float4*)out, gstart);
  passA_kernel<<<208, 256, 0, stream>>>(ei, x_ids, curB, stage);
  countscan_kernel<<<NB, 256, 0, stream>>>(curB, stage, off, dinv);
  passB_kernel<<<NB,  256, 0, stream>>>(curB, stage, off, dinv, rec);

  agg1w_kernel<<<12500, 256, 0, stream>>>(off, rec, (const uint4*)embb, (uint4*)agg1);
  gemm12_mfma <<<782,   256, 0, stream>>>(agg1, (const bh8*)w1f, b1, (const bh8*)w2f, h2b);
  pool2_kernel<<<4096,  256, 0, stream>>>(gstart, off, rec, h2b, b2, out);
}